// Round 4
// baseline (383.923 us; speedup 1.0000x reference)
//
#include <hip/hip_runtime.h>
#include <math.h>
#include <float.h>

// Problem constants
constexpr int CB = 16;        // batch
constexpr int CC = 256;       // channels
constexpr int PH = 96, PW = 96, PHW = 9216;
constexpr int MH = 48, MW = 48, MHW = 2304;
constexpr int KSPLIT = 2;
constexpr int KHALF = 1152;   // MHW / KSPLIT
constexpr int GM = 64;        // GEMM i-tile (A rows)
constexpr int GN = 128;       // GEMM j-tile (B rows)
constexpr int GKT = 32;       // GEMM k-tile
constexpr int GSTEPS = KHALF / GKT;  // 36

__device__ __forceinline__ float sigmoidf_(float x) { return 1.f / (1.f + __expf(-x)); }

__device__ __forceinline__ unsigned f2ord(float f) {
  unsigned u = __float_as_uint(f);
  return (u & 0x80000000u) ? ~u : (u | 0x80000000u);
}

// ---------------- Kernel A: f_p stats + bilinear-adjoint downsample ----------------
__global__ __launch_bounds__(256) void k_pstats(const float* __restrict__ fp,
                                                float* __restrict__ padj,
                                                float* __restrict__ meanp,
                                                float* __restrict__ pn) {
  __shared__ __align__(16) float sm[PHW];       // 36 KB
  __shared__ __align__(16) float tmp[MH * PW];  // 18 KB
  __shared__ float rs[4], rss[4];
  const int bc = blockIdx.x;
  const int tid = threadIdx.x;
  const float* img = fp + (size_t)bc * PHW;
  float s = 0.f, ss = 0.f;
  for (int q = tid; q < PHW / 4; q += 256) {
    float4 v = ((const float4*)img)[q];
    ((float4*)sm)[q] = v;
    s += v.x + v.y + v.z + v.w;
    ss += v.x * v.x + v.y * v.y + v.z * v.z + v.w * v.w;
  }
  for (int off = 32; off; off >>= 1) { s += __shfl_down(s, off); ss += __shfl_down(ss, off); }
  if ((tid & 63) == 0) { rs[tid >> 6] = s; rss[tid >> 6] = ss; }
  __syncthreads();
  if (tid == 0) {
    float S = rs[0] + rs[1] + rs[2] + rs[3];
    float SS = rss[0] + rss[1] + rss[2] + rss[3];
    meanp[bc] = S / (float)PHW;
    pn[bc] = sqrtf(fmaxf(SS - S * S / (float)PHW, 0.f));
  }
  // row adjoint: tmp[u][w] = sum_h Wrow[h,u] * p[h,w]
  for (int i = tid; i < MH * PW; i += 256) {
    int u = i / PW, w = i - u * PW;
    float v;
    if (u == 0)
      v = sm[w] + 0.75f * sm[PW + w] + 0.25f * sm[2 * PW + w];
    else if (u == MH - 1)
      v = 0.25f * sm[(PH - 3) * PW + w] + 0.75f * sm[(PH - 2) * PW + w] + sm[(PH - 1) * PW + w];
    else
      v = 0.25f * (sm[(2 * u - 1) * PW + w] + sm[(2 * u + 2) * PW + w]) +
          0.75f * (sm[2 * u * PW + w] + sm[(2 * u + 1) * PW + w]);
    tmp[i] = v;
  }
  __syncthreads();
  float* outp = padj + (size_t)bc * MHW;
  for (int i = tid; i < MHW; i += 256) {
    int u = i / MW, v = i - u * MW;
    const float* r = tmp + u * PW;
    float val;
    if (v == 0)
      val = r[0] + 0.75f * r[1] + 0.25f * r[2];
    else if (v == MW - 1)
      val = 0.25f * r[PW - 3] + 0.75f * r[PW - 2] + r[PW - 1];
    else
      val = 0.25f * (r[2 * v - 1] + r[2 * v + 2]) + 0.75f * (r[2 * v] + r[2 * v + 1]);
    outp[i] = val;
  }
}

// ---------------- Kernel B: f_ms stats (mean + norm of centered upsampled) ----------------
__device__ __forceinline__ void taps96(int h, int& i0, int& i1, float& w0, float& w1) {
  if (h == 0) { i0 = 0; i1 = 0; w0 = 1.f; w1 = 0.f; }
  else if (h == 95) { i0 = 47; i1 = 47; w0 = 1.f; w1 = 0.f; }
  else if (h & 1) { int k = h >> 1; i0 = k; i1 = k + 1; w0 = 0.75f; w1 = 0.25f; }
  else { int k = h >> 1; i0 = k - 1; i1 = k; w0 = 0.25f; w1 = 0.75f; }
}

__global__ __launch_bounds__(256) void k_msstats(const float* __restrict__ fms,
                                                 float* __restrict__ meanms,
                                                 float* __restrict__ msn) {
  __shared__ __align__(16) float sm[MHW];  // 9 KB
  __shared__ float rs[4], rss[4];
  const int bc = blockIdx.x, tid = threadIdx.x;
  const float* img = fms + (size_t)bc * MHW;
  float s = 0.f;
  for (int q = tid; q < MHW / 4; q += 256) {
    float4 v = ((const float4*)img)[q];
    ((float4*)sm)[q] = v;
    s += v.x + v.y + v.z + v.w;
  }
  for (int off = 32; off; off >>= 1) s += __shfl_down(s, off);
  if ((tid & 63) == 0) rs[tid >> 6] = s;
  __syncthreads();
  const float mean = (rs[0] + rs[1] + rs[2] + rs[3]) / (float)MHW;  // == mean of upsampled
  float ss = 0.f;
  for (int i = tid; i < PHW; i += 256) {
    int h = i / PW, w = i - h * PW;
    int r0, r1, c0, c1; float wr0, wr1, wc0, wc1;
    taps96(h, r0, r1, wr0, wr1);
    taps96(w, c0, c1, wc0, wc1);
    float v = wr0 * (wc0 * sm[r0 * MW + c0] + wc1 * sm[r0 * MW + c1]) +
              wr1 * (wc0 * sm[r1 * MW + c0] + wc1 * sm[r1 * MW + c1]);
    ss += v * v;
  }
  for (int off = 32; off; off >>= 1) ss += __shfl_down(ss, off);
  if ((tid & 63) == 0) rss[tid >> 6] = ss;
  __syncthreads();
  if (tid == 0) {
    float SS = rss[0] + rss[1] + rss[2] + rss[3];
    meanms[bc] = mean;
    msn[bc] = sqrtf(fmaxf(SS - (float)PHW * mean * mean, 0.f));
  }
}

// ---------------- Kernel C: batched fp32 GEMM  dot[ks][b][i][j] = sum_k ms[b,i,k]*padj[b,j,k]
// Row-major swizzled LDS (no transpose scatter), 64x128 tile, 4x8 acc, 1 barrier/step,
// XCD-aware block swizzle. Per-output accumulation = sequential k ascending -> bitwise
// identical scores to previous rounds.
__device__ __forceinline__ int lds_at(int row, int k4) {
  return row * GKT + (k4 ^ (((row >> 3) & 7) << 2));
}

__global__ __launch_bounds__(256) void k_gemm(const float* __restrict__ A,
                                              const float* __restrict__ Bm,
                                              float* __restrict__ Cp) {
  __shared__ __align__(16) float Asm[2][GM * GKT];   // 2 * 8 KB
  __shared__ __align__(16) float Bsm[2][GN * GKT];   // 2 * 16 KB
  // XCD-aware swizzle: block n -> XCD n%8 (dispatch round-robin). Give each XCD all
  // 8 xy-tiles of 4 consecutive z=(b,ks) slices so A/B panels are L2-shared.
  const int n = blockIdx.x;              // 0..255
  const int xcd = n & 7, slot = n >> 3;  // slot 0..31
  const int z = xcd * 4 + (slot >> 3);   // 0..31
  const int xy = slot & 7;               // 0..7
  const int bx = xy & 3, by = xy >> 2;   // bx 0..3 (i), by 0..1 (j)
  const int b = z >> 1, ks = z & 1;
  const int i0 = bx * GM, j0 = by * GN;
  const int tid = threadIdx.x;
  const int ty = tid >> 4, tx = tid & 15;  // 16 x 16 -> rows ty*4+[0,4), cols tx*8+[0,8)
  const float* Ab = A + ((size_t)b * CC + i0) * MHW + ks * KHALF;
  const float* Bb = Bm + ((size_t)b * CC + j0) * MHW + ks * KHALF;
  float acc[4][8] = {};
  float4 ra[2], rb[4];

  auto load_regs = [&](int kt) {
#pragma unroll
    for (int qq = 0; qq < 2; ++qq) {
      int f = tid + qq * 256;             // 512: 64 rows x 8 float4
      int row = f >> 3, k4 = (f & 7) << 2;
      ra[qq] = *(const float4*)(Ab + (size_t)row * MHW + kt + k4);
    }
#pragma unroll
    for (int qq = 0; qq < 4; ++qq) {
      int f = tid + qq * 256;             // 1024: 128 rows x 8 float4
      int row = f >> 3, k4 = (f & 7) << 2;
      rb[qq] = *(const float4*)(Bb + (size_t)row * MHW + kt + k4);
    }
  };
  auto store_lds = [&](int buf) {
#pragma unroll
    for (int qq = 0; qq < 2; ++qq) {
      int f = tid + qq * 256;
      int row = f >> 3, k4 = (f & 7) << 2;
      *(float4*)&Asm[buf][lds_at(row, k4)] = ra[qq];
    }
#pragma unroll
    for (int qq = 0; qq < 4; ++qq) {
      int f = tid + qq * 256;
      int row = f >> 3, k4 = (f & 7) << 2;
      *(float4*)&Bsm[buf][lds_at(row, k4)] = rb[qq];
    }
  };

  load_regs(0);
  store_lds(0);
  __syncthreads();
  int cur = 0;
  for (int step = 0; step < GSTEPS; ++step) {
    if (step + 1 < GSTEPS) load_regs((step + 1) * GKT);
#pragma unroll
    for (int k4c = 0; k4c < GKT / 4; ++k4c) {
      const int k4 = k4c * 4;
      float4 a4[4], b4[8];
#pragma unroll
      for (int u = 0; u < 4; ++u)
        a4[u] = *(const float4*)&Asm[cur][lds_at(ty * 4 + u, k4)];
#pragma unroll
      for (int v = 0; v < 8; ++v)
        b4[v] = *(const float4*)&Bsm[cur][lds_at(tx * 8 + v, k4)];
#pragma unroll
      for (int kk = 0; kk < 4; ++kk)
#pragma unroll
        for (int u = 0; u < 4; ++u)
#pragma unroll
          for (int v = 0; v < 8; ++v)
            acc[u][v] = fmaf(((const float*)&a4[u])[kk], ((const float*)&b4[v])[kk], acc[u][v]);
    }
    if (step + 1 < GSTEPS) {
      store_lds(cur ^ 1);   // other buffer: no barrier needed before store
      __syncthreads();      // single barrier per step
      cur ^= 1;
    }
  }
  float* outp = Cp + (((size_t)ks * CB + b) * CC + (i0 + ty * 4)) * CC + j0 + tx * 8;
#pragma unroll
  for (int u = 0; u < 4; ++u) {
    *(float4*)(outp + (size_t)u * CC + 0) = make_float4(acc[u][0], acc[u][1], acc[u][2], acc[u][3]);
    *(float4*)(outp + (size_t)u * CC + 4) = make_float4(acc[u][4], acc[u][5], acc[u][6], acc[u][7]);
  }
}

// ---------------- Kernel C2: per-row max/argmax of similarity ----------------
__global__ __launch_bounds__(256) void k_rowmax(const float* __restrict__ dotp,
                                                const float* __restrict__ meanp,
                                                const float* __restrict__ pn,
                                                const float* __restrict__ meanms,
                                                const float* __restrict__ msn,
                                                float* __restrict__ maxv,
                                                int* __restrict__ amax) {
  const int tid = threadIdx.x;
  const int r = blockIdx.x * 4 + (tid >> 6);  // row in [0, CB*CC)
  const int lane = tid & 63;
  const int b = r >> 8;
  const float* d0 = dotp + (size_t)r * CC;
  const float* d1 = d0 + (size_t)CB * CC * CC;
  const float mm = meanms[r];
  const float inv = 100.f / msn[r];
  const int j = lane * 4;
  float4 v0 = *(const float4*)(d0 + j);
  float4 v1 = *(const float4*)(d1 + j);
  float4 mp4 = *(const float4*)(meanp + b * CC + j);
  float4 pn4 = *(const float4*)(pn + b * CC + j);
  float sv[4];
  sv[0] = (v0.x + v1.x - (float)PHW * mm * mp4.x) * inv / pn4.x;
  sv[1] = (v0.y + v1.y - (float)PHW * mm * mp4.y) * inv / pn4.y;
  sv[2] = (v0.z + v1.z - (float)PHW * mm * mp4.z) * inv / pn4.z;
  sv[3] = (v0.w + v1.w - (float)PHW * mm * mp4.w) * inv / pn4.w;
  float best = sv[0]; int bj = j;
#pragma unroll
  for (int t = 1; t < 4; ++t)
    if (sv[t] > best) { best = sv[t]; bj = j + t; }
  for (int off = 32; off; off >>= 1) {
    float ov = __shfl_down(best, off);
    int oi = __shfl_down(bj, off);
    if (ov > best || (ov == best && oi < bj)) { best = ov; bj = oi; }
  }
  if (lane == 0) { maxv[r] = best; amax[r] = bj; }
}

// ---------------- Kernel D: group select + deterministic bitonic sort (per batch) ----------------
__global__ __launch_bounds__(256) void k_group(const float* __restrict__ maxv,
                                               const int* __restrict__ amax,
                                               float* __restrict__ sscore,
                                               int* __restrict__ svals,
                                               int* __restrict__ cnt) {
  const int b = blockIdx.x, tid = threadIdx.x;
  __shared__ float mv[CC];
  __shared__ int sidx[CC];
  __shared__ float gsc[CC];
  __shared__ int pres[CC];
  __shared__ unsigned long long keys[CC];
  __shared__ float r1[4], r2[4];
  __shared__ int r3[4];
  float v = maxv[b * CC + tid];
  sidx[tid] = amax[b * CC + tid];
  float m = v;
  for (int off = 32; off; off >>= 1) m = fmaxf(m, __shfl_down(m, off));
  if ((tid & 63) == 0) r1[tid >> 6] = m;
  __syncthreads();
  float mt = fmaxf(fmaxf(r1[0], r1[1]), fmaxf(r1[2], r1[3]));
  float e = __expf(v - mt);
  float s = e;
  for (int off = 32; off; off >>= 1) s += __shfl_down(s, off);
  if ((tid & 63) == 0) r2[tid >> 6] = s;
  __syncthreads();
  float st = r2[0] + r2[1] + r2[2] + r2[3];
  mv[tid] = e / st;
  __syncthreads();
  // group score for channel j = tid (sequential over i -> deterministic)
  float g = 0.f; int p = 0;
  for (int i2 = 0; i2 < CC; ++i2)
    if (sidx[i2] == tid) { g += mv[i2]; p = 1; }
  gsc[tid] = g; pres[tid] = p;
  int pc = p;
  for (int off = 32; off; off >>= 1) pc += __shfl_down(pc, off);
  if ((tid & 63) == 0) r3[tid >> 6] = pc;
  __syncthreads();
  if (tid == 0) cnt[b] = r3[0] + r3[1] + r3[2] + r3[3];
  // key: (ordered score << 32) | channel; descending sort => ties -> larger channel first
  int c = 255 - tid;
  float val = pres[c] ? gsc[c] : -INFINITY;
  keys[tid] = ((unsigned long long)f2ord(val) << 32) | (unsigned)c;
  __syncthreads();
  for (int ksz = 2; ksz <= 256; ksz <<= 1) {
    for (int jj = ksz >> 1; jj > 0; jj >>= 1) {
      int ixj = tid ^ jj;
      if (ixj > tid) {
        unsigned long long a = keys[tid], o = keys[ixj];
        bool descBlock = ((tid & ksz) == 0);
        bool sw = descBlock ? (a < o) : (a > o);
        if (sw) { keys[tid] = o; keys[ixj] = a; }
      }
      __syncthreads();
    }
  }
  unsigned long long kk = keys[tid];
  int cc2 = (int)(kk & 0xFFFFFFFFull);
  float vv = pres[cc2] ? gsc[cc2] : -INFINITY;
  sscore[b * CC + tid] = vv;
  svals[b * CC + tid] = cc2;
}

// ---------------- Kernel E: min_k + softmax weights ----------------
__global__ __launch_bounds__(128) void k_wsel(const float* __restrict__ sscore,
                                              const int* __restrict__ cnt,
                                              float* __restrict__ wgt,
                                              int* __restrict__ minkp) {
  const int b = blockIdx.x, tid = threadIdx.x;
  int mn = 0x7fffffff;
#pragma unroll
  for (int t = 0; t < CB; ++t) mn = min(mn, cnt[t]);
  const int mink = (mn + 1) >> 1;
  if (b == 0 && tid == 0) *minkp = mink;
  __shared__ float sh1[2], sh2[2];
  float v = (tid < mink) ? sscore[b * CC + tid] : -INFINITY;
  float m = v;
  for (int off = 32; off; off >>= 1) m = fmaxf(m, __shfl_down(m, off));
  if ((tid & 63) == 0) sh1[tid >> 6] = m;
  __syncthreads();
  float mt = fmaxf(sh1[0], sh1[1]);
  float e = (tid < mink) ? __expf(v - mt) : 0.f;
  float s = e;
  for (int off = 32; off; off >>= 1) s += __shfl_down(s, off);
  if ((tid & 63) == 0) sh2[tid >> 6] = s;
  __syncthreads();
  float st = sh2[0] + sh2[1];
  if (tid < mink) wgt[b * 128 + tid] = e / st;
}

// ---------------- Kernel F1: mask[b,hw] = sum_k w[b,k]*sigmoid(fp[b,sel[k],hw]) ----------------
__global__ __launch_bounds__(256) void k_mask(const float* __restrict__ fp,
                                              const float* __restrict__ wgt,
                                              const int* __restrict__ svals,
                                              const int* __restrict__ minkp,
                                              float* __restrict__ mask) {
  const int b = blockIdx.y;
  const int hw4 = blockIdx.x * 256 + threadIdx.x;  // float4 index < 2304
  const int mink = *minkp;
  const float* base = fp + (size_t)b * CC * PHW;
  float4 acc = make_float4(0.f, 0.f, 0.f, 0.f);
  for (int k = 0; k < mink; ++k) {
    int c = svals[b * CC + k];
    float wk = wgt[b * 128 + k];
    float4 v = ((const float4*)(base + (size_t)c * PHW))[hw4];
    acc.x += wk * sigmoidf_(v.x);
    acc.y += wk * sigmoidf_(v.y);
    acc.z += wk * sigmoidf_(v.z);
    acc.w += wk * sigmoidf_(v.w);
  }
  ((float4*)(mask + (size_t)b * PHW))[hw4] = acc;
}

// ---------------- Kernel F2: out = fp * (1 + mask) ----------------
__global__ __launch_bounds__(256) void k_out(const float* __restrict__ fp,
                                             const float* __restrict__ mask,
                                             float* __restrict__ out) {
  const int idx = blockIdx.x * 256 + threadIdx.x;  // float4 index
  const int img = idx / (PHW / 4);
  const int hw4 = idx - img * (PHW / 4);
  const int b = img >> 8;
  float4 mk = ((const float4*)mask)[b * (PHW / 4) + hw4];
  float4 v = ((const float4*)fp)[idx];
  float4 o;
  o.x = v.x * (1.f + mk.x);
  o.y = v.y * (1.f + mk.y);
  o.z = v.z * (1.f + mk.z);
  o.w = v.w * (1.f + mk.w);
  ((float4*)out)[idx] = o;
}

extern "C" void kernel_launch(void* const* d_in, const int* in_sizes, int n_in,
                              void* d_out, int out_size, void* d_ws, size_t ws_size,
                              hipStream_t stream) {
  (void)in_sizes; (void)n_in; (void)out_size;
  const float* fp = (const float*)d_in[0];
  const float* fms = (const float*)d_in[1];
  float* out = (float*)d_out;

  // Big scratch lives in d_out (dead before k_out overwrites it):
  //   padj: 16*256*2304 = 9,437,184 floats
  //   dot : 2*16*256*256 = 2,097,152 floats
  float* padj = out;
  float* dotp = out + (size_t)CB * CC * MHW;

  // Small scratch in d_ws (~730 KB)
  if (ws_size < (size_t)183000 * 4) return;
  float* wsf = (float*)d_ws;
  float* meanp = wsf;               // 4096
  float* pnv = wsf + 4096;          // 4096
  float* meanms = wsf + 8192;       // 4096
  float* msn = wsf + 12288;         // 4096
  float* maxv = wsf + 16384;        // 4096
  float* ssc = wsf + 20480;         // 4096
  float* wgt = wsf + 24576;         // 2048
  float* maskp = wsf + 26624;       // 147456 -> ends at 174080
  int* amax = (int*)(wsf + 174080); // 4096
  int* sv = (int*)(wsf + 178176);   // 4096
  int* cntp = (int*)(wsf + 182272); // 16
  int* minkp = (int*)(wsf + 182288);// 1

  k_pstats<<<CB * CC, 256, 0, stream>>>(fp, padj, meanp, pnv);
  k_msstats<<<CB * CC, 256, 0, stream>>>(fms, meanms, msn);
  k_gemm<<<256, 256, 0, stream>>>(fms, padj, dotp);
  k_rowmax<<<(CB * CC) / 4, 256, 0, stream>>>(dotp, meanp, pnv, meanms, msn, maxv, amax);
  k_group<<<CB, 256, 0, stream>>>(maxv, amax, ssc, sv, cntp);
  k_wsel<<<CB, 128, 0, stream>>>(ssc, cntp, wgt, minkp);
  k_mask<<<dim3(PHW / 4 / 256, CB), 256, 0, stream>>>(fp, wgt, sv, minkp, maskp);
  k_out<<<(CB * CC * PHW / 4) / 256, 256, 0, stream>>>(fp, maskp, out);
}

// Round 5
// 341.768 us; speedup vs baseline: 1.1233x; 1.1233x over previous
//
#include <hip/hip_runtime.h>
#include <math.h>
#include <float.h>

// Problem constants
constexpr int CB = 16;        // batch
constexpr int CC = 256;       // channels
constexpr int PH = 96, PW = 96, PHW = 9216;
constexpr int MH = 48, MW = 48, MHW = 2304;
constexpr int KSPLIT = 2;
constexpr int KHALF = 1152;   // MHW / KSPLIT
constexpr int GKT = 32;       // GEMM k-tile
constexpr int GSTEPS = KHALF / GKT;  // 36
constexpr int GTM = 32;       // GEMM i-tile
constexpr int GTN = 64;       // GEMM j-tile

__device__ __forceinline__ float sigmoidf_(float x) { return 1.f / (1.f + __expf(-x)); }

__device__ __forceinline__ unsigned f2ord(float f) {
  unsigned u = __float_as_uint(f);
  return (u & 0x80000000u) ? ~u : (u | 0x80000000u);
}

// ---------------- Kernel A: f_p stats + fused bilinear-adjoint downsample ----------------
// Row+col adjoint fused via lane-local registers + shuffles; per-element expressions are
// verbatim from the two-pass version -> bitwise-identical padj. LDS = image only (36.9 KB)
// -> 4 blocks/CU.
__global__ __launch_bounds__(256) void k_pstats(const float* __restrict__ fp,
                                                float* __restrict__ padj,
                                                float* __restrict__ meanp,
                                                float* __restrict__ pn) {
  __shared__ __align__(16) float sm[PHW];       // 36 KB
  __shared__ float rs[4], rss[4];
  const int bc = blockIdx.x;
  const int tid = threadIdx.x;
  const float* img = fp + (size_t)bc * PHW;
  float s = 0.f, ss = 0.f;
  for (int q = tid; q < PHW / 4; q += 256) {
    float4 v = ((const float4*)img)[q];
    ((float4*)sm)[q] = v;
    s += v.x + v.y + v.z + v.w;
    ss += v.x * v.x + v.y * v.y + v.z * v.z + v.w * v.w;
  }
  for (int off = 32; off; off >>= 1) { s += __shfl_down(s, off); ss += __shfl_down(ss, off); }
  if ((tid & 63) == 0) { rs[tid >> 6] = s; rss[tid >> 6] = ss; }
  __syncthreads();
  if (tid == 0) {
    float S = rs[0] + rs[1] + rs[2] + rs[3];
    float SS = rss[0] + rss[1] + rss[2] + rss[3];
    meanp[bc] = S / (float)PHW;
    pn[bc] = sqrtf(fmaxf(SS - S * S / (float)PHW, 0.f));
  }
  // Fused adjoint: wave handles row u = g*4 + waveid; lane l<48 computes
  // tmp[u][2l],tmp[u][2l+1] in regs, shuffles neighbors, emits padj[u][l].
  const int wid = tid >> 6, lane = tid & 63;
  float* outp = padj + (size_t)bc * MHW;
  for (int g = 0; g < 12; ++g) {
    const int u = g * 4 + wid;
    if (lane < 48) {
      const int w0 = 2 * lane;
      float t0, t1;
      if (u == 0) {
        float2 r0 = *(const float2*)&sm[w0];
        float2 r1 = *(const float2*)&sm[PW + w0];
        float2 r2 = *(const float2*)&sm[2 * PW + w0];
        t0 = r0.x + 0.75f * r1.x + 0.25f * r2.x;
        t1 = r0.y + 0.75f * r1.y + 0.25f * r2.y;
      } else if (u == MH - 1) {
        float2 ra = *(const float2*)&sm[(PH - 3) * PW + w0];
        float2 rb = *(const float2*)&sm[(PH - 2) * PW + w0];
        float2 rc = *(const float2*)&sm[(PH - 1) * PW + w0];
        t0 = 0.25f * ra.x + 0.75f * rb.x + rc.x;
        t1 = 0.25f * ra.y + 0.75f * rb.y + rc.y;
      } else {
        float2 r0 = *(const float2*)&sm[(2 * u - 1) * PW + w0];
        float2 r1 = *(const float2*)&sm[2 * u * PW + w0];
        float2 r2 = *(const float2*)&sm[(2 * u + 1) * PW + w0];
        float2 r3 = *(const float2*)&sm[(2 * u + 2) * PW + w0];
        t0 = 0.25f * (r0.x + r3.x) + 0.75f * (r1.x + r2.x);
        t1 = 0.25f * (r0.y + r3.y) + 0.75f * (r1.y + r2.y);
      }
      const float t1m = __shfl_up(t1, 1);    // tmp[u][2l-1] (from lane l-1)
      const float t0p = __shfl_down(t0, 1);  // tmp[u][2l+2] (from lane l+1)
      float val;
      if (lane == 0)
        val = t0 + 0.75f * t1 + 0.25f * t0p;
      else if (lane == MW - 1)
        val = 0.25f * t1m + 0.75f * t0 + t1;
      else
        val = 0.25f * (t1m + t0p) + 0.75f * (t0 + t1);
      outp[u * MW + lane] = val;
    }
  }
}

// ---------------- Kernel B: f_ms stats (mean + norm of centered upsampled) ----------------
__device__ __forceinline__ void taps96(int h, int& i0, int& i1, float& w0, float& w1) {
  if (h == 0) { i0 = 0; i1 = 0; w0 = 1.f; w1 = 0.f; }
  else if (h == 95) { i0 = 47; i1 = 47; w0 = 1.f; w1 = 0.f; }
  else if (h & 1) { int k = h >> 1; i0 = k; i1 = k + 1; w0 = 0.75f; w1 = 0.25f; }
  else { int k = h >> 1; i0 = k - 1; i1 = k; w0 = 0.25f; w1 = 0.75f; }
}

__global__ __launch_bounds__(256) void k_msstats(const float* __restrict__ fms,
                                                 float* __restrict__ meanms,
                                                 float* __restrict__ msn) {
  __shared__ __align__(16) float sm[MHW];  // 9 KB
  __shared__ float rs[4], rss[4];
  const int bc = blockIdx.x, tid = threadIdx.x;
  const float* img = fms + (size_t)bc * MHW;
  float s = 0.f;
  for (int q = tid; q < MHW / 4; q += 256) {
    float4 v = ((const float4*)img)[q];
    ((float4*)sm)[q] = v;
    s += v.x + v.y + v.z + v.w;
  }
  for (int off = 32; off; off >>= 1) s += __shfl_down(s, off);
  if ((tid & 63) == 0) rs[tid >> 6] = s;
  __syncthreads();
  const float mean = (rs[0] + rs[1] + rs[2] + rs[3]) / (float)MHW;  // == mean of upsampled
  float ss = 0.f;
  for (int i = tid; i < PHW; i += 256) {
    int h = i / PW, w = i - h * PW;
    int r0, r1, c0, c1; float wr0, wr1, wc0, wc1;
    taps96(h, r0, r1, wr0, wr1);
    taps96(w, c0, c1, wc0, wc1);
    float v = wr0 * (wc0 * sm[r0 * MW + c0] + wc1 * sm[r0 * MW + c1]) +
              wr1 * (wc0 * sm[r1 * MW + c0] + wc1 * sm[r1 * MW + c1]);
    ss += v * v;
  }
  for (int off = 32; off; off >>= 1) ss += __shfl_down(ss, off);
  if ((tid & 63) == 0) rss[tid >> 6] = ss;
  __syncthreads();
  if (tid == 0) {
    float SS = rss[0] + rss[1] + rss[2] + rss[3];
    meanms[bc] = mean;
    msn[bc] = sqrtf(fmaxf(SS - (float)PHW * mean * mean, 0.f));
  }
}

// ---------------- Kernel C: batched fp32 GEMM  dot[ks][b][i][j] = sum_k ms[b,i,k]*padj[b,j,k]
// 32x64 tile, 2x4 acc, 1024 blocks (4/CU, 16 waves/CU), stride-32 LDS rows with float4-
// granular XOR swizzle (aligned b128, <=2-way reads, even stores). Sequential k ascending
// per output element -> bitwise identical scores.
__device__ __forceinline__ int lat(int row, int k4) {
  return row * GKT + (k4 ^ (((row >> 2) & 7) << 2));
}

__global__ __launch_bounds__(256, 4) void k_gemm(const float* __restrict__ A,
                                                 const float* __restrict__ Bm,
                                                 float* __restrict__ Cp) {
  __shared__ __align__(16) float Asm[2][GTM * GKT];   // 2 * 4 KB
  __shared__ __align__(16) float Bsm[2][GTN * GKT];   // 2 * 8 KB
  // XCD-aware swizzle: 1024 blocks; XCD n&7 gets 4 consecutive z=(b,ks) slices, all 32
  // xy-tiles each -> per-z A/B panels (2.4 MB) L2-resident per XCD.
  const int n = blockIdx.x;                  // 0..1023
  const int xcd = n & 7, slot = n >> 3;      // slot 0..127
  const int z = xcd * 4 + (slot >> 5);       // 0..31
  const int xy = slot & 31;                  // 0..31
  const int bi = xy >> 2, bj = xy & 3;       // bi 0..7, bj 0..3
  const int b = z >> 1, ks = z & 1;
  const int i0 = bi * GTM, j0 = bj * GTN;
  const int tid = threadIdx.x;
  const int ty = tid >> 4, tx = tid & 15;    // 16 x 16
  const float* Ab = A + ((size_t)b * CC + i0) * MHW + ks * KHALF;
  const float* Bb = Bm + ((size_t)b * CC + j0) * MHW + ks * KHALF;
  float acc[2][4] = {};
  float4 ra, rb0, rb1;

  const int srow = tid >> 3, sk4 = (tid & 7) << 2;
  const int soffA = lat(srow, sk4);
  const int soffB0 = soffA;                    // same row index
  const int soffB1 = lat(srow + 32, sk4);
  const size_t gA = (size_t)srow * MHW + sk4;
  const size_t gB1 = (size_t)(srow + 32) * MHW + sk4;

  const int baseA = (ty * 2) * GKT;            // rows ty*2, ty*2+1
  const int swzA = ((ty >> 1) & 7) << 2;       // == ((2ty)>>2)&7 <<2, same for both rows
  const int baseB = (tx * 4) * GKT;            // rows tx*4 .. tx*4+3
  const int swzB = (tx & 7) << 2;              // same for all 4 rows

  auto load_regs = [&](int kt) {
    ra  = *(const float4*)(Ab + gA + kt);
    rb0 = *(const float4*)(Bb + gA + kt);
    rb1 = *(const float4*)(Bb + gB1 + kt);
  };
  auto store_lds = [&](int buf) {
    *(float4*)&Asm[buf][soffA]  = ra;
    *(float4*)&Bsm[buf][soffB0] = rb0;
    *(float4*)&Bsm[buf][soffB1] = rb1;
  };

  load_regs(0);
  store_lds(0);
  __syncthreads();
  int cur = 0;
  for (int step = 0; step < GSTEPS; ++step) {
    if (step + 1 < GSTEPS) load_regs((step + 1) * GKT);
#pragma unroll
    for (int k4c = 0; k4c < GKT / 4; ++k4c) {
      const int k4 = k4c * 4;
      const int ka = k4 ^ swzA, kb = k4 ^ swzB;
      float4 a4[2], b4[4];
      a4[0] = *(const float4*)&Asm[cur][baseA + ka];
      a4[1] = *(const float4*)&Asm[cur][baseA + GKT + ka];
#pragma unroll
      for (int v = 0; v < 4; ++v)
        b4[v] = *(const float4*)&Bsm[cur][baseB + v * GKT + kb];
#pragma unroll
      for (int kk = 0; kk < 4; ++kk)
#pragma unroll
        for (int u = 0; u < 2; ++u)
#pragma unroll
          for (int v = 0; v < 4; ++v)
            acc[u][v] = fmaf(((const float*)&a4[u])[kk], ((const float*)&b4[v])[kk], acc[u][v]);
    }
    if (step + 1 < GSTEPS) {
      store_lds(cur ^ 1);   // idle buffer: no barrier needed before store
      __syncthreads();      // single barrier per step
      cur ^= 1;
    }
  }
  float* outp = Cp + (((size_t)ks * CB + b) * CC + (i0 + ty * 2)) * CC + j0 + tx * 4;
  *(float4*)(outp)      = make_float4(acc[0][0], acc[0][1], acc[0][2], acc[0][3]);
  *(float4*)(outp + CC) = make_float4(acc[1][0], acc[1][1], acc[1][2], acc[1][3]);
}

// ---------------- Kernel C2: per-row max/argmax of similarity ----------------
__global__ __launch_bounds__(256) void k_rowmax(const float* __restrict__ dotp,
                                                const float* __restrict__ meanp,
                                                const float* __restrict__ pn,
                                                const float* __restrict__ meanms,
                                                const float* __restrict__ msn,
                                                float* __restrict__ maxv,
                                                int* __restrict__ amax) {
  const int tid = threadIdx.x;
  const int r = blockIdx.x * 4 + (tid >> 6);  // row in [0, CB*CC)
  const int lane = tid & 63;
  const int b = r >> 8;
  const float* d0 = dotp + (size_t)r * CC;
  const float* d1 = d0 + (size_t)CB * CC * CC;
  const float mm = meanms[r];
  const float inv = 100.f / msn[r];
  const int j = lane * 4;
  float4 v0 = *(const float4*)(d0 + j);
  float4 v1 = *(const float4*)(d1 + j);
  float4 mp4 = *(const float4*)(meanp + b * CC + j);
  float4 pn4 = *(const float4*)(pn + b * CC + j);
  float sv[4];
  sv[0] = (v0.x + v1.x - (float)PHW * mm * mp4.x) * inv / pn4.x;
  sv[1] = (v0.y + v1.y - (float)PHW * mm * mp4.y) * inv / pn4.y;
  sv[2] = (v0.z + v1.z - (float)PHW * mm * mp4.z) * inv / pn4.z;
  sv[3] = (v0.w + v1.w - (float)PHW * mm * mp4.w) * inv / pn4.w;
  float best = sv[0]; int bj = j;
#pragma unroll
  for (int t = 1; t < 4; ++t)
    if (sv[t] > best) { best = sv[t]; bj = j + t; }
  for (int off = 32; off; off >>= 1) {
    float ov = __shfl_down(best, off);
    int oi = __shfl_down(bj, off);
    if (ov > best || (ov == best && oi < bj)) { best = ov; bj = oi; }
  }
  if (lane == 0) { maxv[r] = best; amax[r] = bj; }
}

// ---------------- Kernel D: group select + deterministic bitonic sort (per batch) ----------------
__global__ __launch_bounds__(256) void k_group(const float* __restrict__ maxv,
                                               const int* __restrict__ amax,
                                               float* __restrict__ sscore,
                                               int* __restrict__ svals,
                                               int* __restrict__ cnt) {
  const int b = blockIdx.x, tid = threadIdx.x;
  __shared__ float mv[CC];
  __shared__ int sidx[CC];
  __shared__ float gsc[CC];
  __shared__ int pres[CC];
  __shared__ unsigned long long keys[CC];
  __shared__ float r1[4], r2[4];
  __shared__ int r3[4];
  float v = maxv[b * CC + tid];
  sidx[tid] = amax[b * CC + tid];
  float m = v;
  for (int off = 32; off; off >>= 1) m = fmaxf(m, __shfl_down(m, off));
  if ((tid & 63) == 0) r1[tid >> 6] = m;
  __syncthreads();
  float mt = fmaxf(fmaxf(r1[0], r1[1]), fmaxf(r1[2], r1[3]));
  float e = __expf(v - mt);
  float s = e;
  for (int off = 32; off; off >>= 1) s += __shfl_down(s, off);
  if ((tid & 63) == 0) r2[tid >> 6] = s;
  __syncthreads();
  float st = r2[0] + r2[1] + r2[2] + r2[3];
  mv[tid] = e / st;
  __syncthreads();
  // group score for channel j = tid (sequential over i -> deterministic)
  float g = 0.f; int p = 0;
  for (int i2 = 0; i2 < CC; ++i2)
    if (sidx[i2] == tid) { g += mv[i2]; p = 1; }
  gsc[tid] = g; pres[tid] = p;
  int pc = p;
  for (int off = 32; off; off >>= 1) pc += __shfl_down(pc, off);
  if ((tid & 63) == 0) r3[tid >> 6] = pc;
  __syncthreads();
  if (tid == 0) cnt[b] = r3[0] + r3[1] + r3[2] + r3[3];
  // key: (ordered score << 32) | channel; descending sort => ties -> larger channel first
  int c = 255 - tid;
  float val = pres[c] ? gsc[c] : -INFINITY;
  keys[tid] = ((unsigned long long)f2ord(val) << 32) | (unsigned)c;
  __syncthreads();
  for (int ksz = 2; ksz <= 256; ksz <<= 1) {
    for (int jj = ksz >> 1; jj > 0; jj >>= 1) {
      int ixj = tid ^ jj;
      if (ixj > tid) {
        unsigned long long a = keys[tid], o = keys[ixj];
        bool descBlock = ((tid & ksz) == 0);
        bool sw = descBlock ? (a < o) : (a > o);
        if (sw) { keys[tid] = o; keys[ixj] = a; }
      }
      __syncthreads();
    }
  }
  unsigned long long kk = keys[tid];
  int cc2 = (int)(kk & 0xFFFFFFFFull);
  float vv = pres[cc2] ? gsc[cc2] : -INFINITY;
  sscore[b * CC + tid] = vv;
  svals[b * CC + tid] = cc2;
}

// ---------------- Kernel E: min_k + softmax weights ----------------
__global__ __launch_bounds__(128) void k_wsel(const float* __restrict__ sscore,
                                              const int* __restrict__ cnt,
                                              float* __restrict__ wgt,
                                              int* __restrict__ minkp) {
  const int b = blockIdx.x, tid = threadIdx.x;
  int mn = 0x7fffffff;
#pragma unroll
  for (int t = 0; t < CB; ++t) mn = min(mn, cnt[t]);
  const int mink = (mn + 1) >> 1;
  if (b == 0 && tid == 0) *minkp = mink;
  __shared__ float sh1[2], sh2[2];
  float v = (tid < mink) ? sscore[b * CC + tid] : -INFINITY;
  float m = v;
  for (int off = 32; off; off >>= 1) m = fmaxf(m, __shfl_down(m, off));
  if ((tid & 63) == 0) sh1[tid >> 6] = m;
  __syncthreads();
  float mt = fmaxf(sh1[0], sh1[1]);
  float e = (tid < mink) ? __expf(v - mt) : 0.f;
  float s = e;
  for (int off = 32; off; off >>= 1) s += __shfl_down(s, off);
  if ((tid & 63) == 0) sh2[tid >> 6] = s;
  __syncthreads();
  float st = sh2[0] + sh2[1];
  if (tid < mink) wgt[b * 128 + tid] = e / st;
}

// ---------------- Kernel F1: mask[b,hw] = sum_k w[b,k]*sigmoid(fp[b,sel[k],hw]) ----------------
__global__ __launch_bounds__(256) void k_mask(const float* __restrict__ fp,
                                              const float* __restrict__ wgt,
                                              const int* __restrict__ svals,
                                              const int* __restrict__ minkp,
                                              float* __restrict__ mask) {
  const int b = blockIdx.y;
  const int hw4 = blockIdx.x * 256 + threadIdx.x;  // float4 index < 2304
  const int mink = *minkp;
  const float* base = fp + (size_t)b * CC * PHW;
  float4 acc = make_float4(0.f, 0.f, 0.f, 0.f);
  for (int k = 0; k < mink; ++k) {
    int c = svals[b * CC + k];
    float wk = wgt[b * 128 + k];
    float4 v = ((const float4*)(base + (size_t)c * PHW))[hw4];
    acc.x += wk * sigmoidf_(v.x);
    acc.y += wk * sigmoidf_(v.y);
    acc.z += wk * sigmoidf_(v.z);
    acc.w += wk * sigmoidf_(v.w);
  }
  ((float4*)(mask + (size_t)b * PHW))[hw4] = acc;
}

// ---------------- Kernel F2: out = fp * (1 + mask) ----------------
__global__ __launch_bounds__(256) void k_out(const float* __restrict__ fp,
                                             const float* __restrict__ mask,
                                             float* __restrict__ out) {
  const int idx = blockIdx.x * 256 + threadIdx.x;  // float4 index
  const int img = idx / (PHW / 4);
  const int hw4 = idx - img * (PHW / 4);
  const int b = img >> 8;
  float4 mk = ((const float4*)mask)[b * (PHW / 4) + hw4];
  float4 v = ((const float4*)fp)[idx];
  float4 o;
  o.x = v.x * (1.f + mk.x);
  o.y = v.y * (1.f + mk.y);
  o.z = v.z * (1.f + mk.z);
  o.w = v.w * (1.f + mk.w);
  ((float4*)out)[idx] = o;
}

extern "C" void kernel_launch(void* const* d_in, const int* in_sizes, int n_in,
                              void* d_out, int out_size, void* d_ws, size_t ws_size,
                              hipStream_t stream) {
  (void)in_sizes; (void)n_in; (void)out_size;
  const float* fp = (const float*)d_in[0];
  const float* fms = (const float*)d_in[1];
  float* out = (float*)d_out;

  // Big scratch lives in d_out (dead before k_out overwrites it):
  //   padj: 16*256*2304 = 9,437,184 floats
  //   dot : 2*16*256*256 = 2,097,152 floats
  float* padj = out;
  float* dotp = out + (size_t)CB * CC * MHW;

  // Small scratch in d_ws (~730 KB)
  if (ws_size < (size_t)183000 * 4) return;
  float* wsf = (float*)d_ws;
  float* meanp = wsf;               // 4096
  float* pnv = wsf + 4096;          // 4096
  float* meanms = wsf + 8192;       // 4096
  float* msn = wsf + 12288;         // 4096
  float* maxv = wsf + 16384;        // 4096
  float* ssc = wsf + 20480;         // 4096
  float* wgt = wsf + 24576;         // 2048
  float* maskp = wsf + 26624;       // 147456 -> ends at 174080
  int* amax = (int*)(wsf + 174080); // 4096
  int* sv = (int*)(wsf + 178176);   // 4096
  int* cntp = (int*)(wsf + 182272); // 16
  int* minkp = (int*)(wsf + 182288);// 1

  k_pstats<<<CB * CC, 256, 0, stream>>>(fp, padj, meanp, pnv);
  k_msstats<<<CB * CC, 256, 0, stream>>>(fms, meanms, msn);
  k_gemm<<<1024, 256, 0, stream>>>(fms, padj, dotp);
  k_rowmax<<<(CB * CC) / 4, 256, 0, stream>>>(dotp, meanp, pnv, meanms, msn, maxv, amax);
  k_group<<<CB, 256, 0, stream>>>(maxv, amax, ssc, sv, cntp);
  k_wsel<<<CB, 128, 0, stream>>>(ssc, cntp, wgt, minkp);
  k_mask<<<dim3(PHW / 4 / 256, CB), 256, 0, stream>>>(fp, wgt, sv, minkp, maskp);
  k_out<<<(CB * CC * PHW / 4) / 256, 256, 0, stream>>>(fp, maskp, out);
}

// Round 6
// 330.201 us; speedup vs baseline: 1.1627x; 1.0350x over previous
//
#include <hip/hip_runtime.h>
#include <math.h>
#include <float.h>

// Problem constants
constexpr int CB = 16;        // batch
constexpr int CC = 256;       // channels
constexpr int PH = 96, PW = 96, PHW = 9216;
constexpr int MH = 48, MW = 48, MHW = 2304;
constexpr int KSPLIT = 4;
constexpr int KQ = 576;       // MHW / KSPLIT
constexpr int GKT = 32;       // GEMM k-tile
constexpr int GSTEPS = KQ / GKT;  // 18
constexpr int GTM = 64;       // GEMM i-tile
constexpr int GTN = 128;      // GEMM j-tile

__device__ __forceinline__ float sigmoidf_(float x) { return 1.f / (1.f + __expf(-x)); }

__device__ __forceinline__ unsigned f2ord(float f) {
  unsigned u = __float_as_uint(f);
  return (u & 0x80000000u) ? ~u : (u | 0x80000000u);
}

// ---------------- Kernel A: f_p stats + fused bilinear-adjoint downsample ----------------
__global__ __launch_bounds__(256) void k_pstats(const float* __restrict__ fp,
                                                float* __restrict__ padj,
                                                float* __restrict__ meanp,
                                                float* __restrict__ pn) {
  __shared__ __align__(16) float sm[PHW];       // 36 KB
  __shared__ float rs[4], rss[4];
  const int bc = blockIdx.x;
  const int tid = threadIdx.x;
  const float* img = fp + (size_t)bc * PHW;
  float s = 0.f, ss = 0.f;
  for (int q = tid; q < PHW / 4; q += 256) {
    float4 v = ((const float4*)img)[q];
    ((float4*)sm)[q] = v;
    s += v.x + v.y + v.z + v.w;
    ss += v.x * v.x + v.y * v.y + v.z * v.z + v.w * v.w;
  }
  for (int off = 32; off; off >>= 1) { s += __shfl_down(s, off); ss += __shfl_down(ss, off); }
  if ((tid & 63) == 0) { rs[tid >> 6] = s; rss[tid >> 6] = ss; }
  __syncthreads();
  if (tid == 0) {
    float S = rs[0] + rs[1] + rs[2] + rs[3];
    float SS = rss[0] + rss[1] + rss[2] + rss[3];
    meanp[bc] = S / (float)PHW;
    pn[bc] = sqrtf(fmaxf(SS - S * S / (float)PHW, 0.f));
  }
  const int wid = tid >> 6, lane = tid & 63;
  float* outp = padj + (size_t)bc * MHW;
  for (int g = 0; g < 12; ++g) {
    const int u = g * 4 + wid;
    if (lane < 48) {
      const int w0 = 2 * lane;
      float t0, t1;
      if (u == 0) {
        float2 r0 = *(const float2*)&sm[w0];
        float2 r1 = *(const float2*)&sm[PW + w0];
        float2 r2 = *(const float2*)&sm[2 * PW + w0];
        t0 = r0.x + 0.75f * r1.x + 0.25f * r2.x;
        t1 = r0.y + 0.75f * r1.y + 0.25f * r2.y;
      } else if (u == MH - 1) {
        float2 ra = *(const float2*)&sm[(PH - 3) * PW + w0];
        float2 rb = *(const float2*)&sm[(PH - 2) * PW + w0];
        float2 rc = *(const float2*)&sm[(PH - 1) * PW + w0];
        t0 = 0.25f * ra.x + 0.75f * rb.x + rc.x;
        t1 = 0.25f * ra.y + 0.75f * rb.y + rc.y;
      } else {
        float2 r0 = *(const float2*)&sm[(2 * u - 1) * PW + w0];
        float2 r1 = *(const float2*)&sm[2 * u * PW + w0];
        float2 r2 = *(const float2*)&sm[(2 * u + 1) * PW + w0];
        float2 r3 = *(const float2*)&sm[(2 * u + 2) * PW + w0];
        t0 = 0.25f * (r0.x + r3.x) + 0.75f * (r1.x + r2.x);
        t1 = 0.25f * (r0.y + r3.y) + 0.75f * (r1.y + r2.y);
      }
      const float t1m = __shfl_up(t1, 1);
      const float t0p = __shfl_down(t0, 1);
      float val;
      if (lane == 0)
        val = t0 + 0.75f * t1 + 0.25f * t0p;
      else if (lane == MW - 1)
        val = 0.25f * t1m + 0.75f * t0 + t1;
      else
        val = 0.25f * (t1m + t0p) + 0.75f * (t0 + t1);
      outp[u * MW + lane] = val;
    }
  }
}

// ---------------- Kernel B: f_ms stats ----------------
__device__ __forceinline__ void taps96(int h, int& i0, int& i1, float& w0, float& w1) {
  if (h == 0) { i0 = 0; i1 = 0; w0 = 1.f; w1 = 0.f; }
  else if (h == 95) { i0 = 47; i1 = 47; w0 = 1.f; w1 = 0.f; }
  else if (h & 1) { int k = h >> 1; i0 = k; i1 = k + 1; w0 = 0.75f; w1 = 0.25f; }
  else { int k = h >> 1; i0 = k - 1; i1 = k; w0 = 0.25f; w1 = 0.75f; }
}

__global__ __launch_bounds__(256) void k_msstats(const float* __restrict__ fms,
                                                 float* __restrict__ meanms,
                                                 float* __restrict__ msn) {
  __shared__ __align__(16) float sm[MHW];
  __shared__ float rs[4], rss[4];
  const int bc = blockIdx.x, tid = threadIdx.x;
  const float* img = fms + (size_t)bc * MHW;
  float s = 0.f;
  for (int q = tid; q < MHW / 4; q += 256) {
    float4 v = ((const float4*)img)[q];
    ((float4*)sm)[q] = v;
    s += v.x + v.y + v.z + v.w;
  }
  for (int off = 32; off; off >>= 1) s += __shfl_down(s, off);
  if ((tid & 63) == 0) rs[tid >> 6] = s;
  __syncthreads();
  const float mean = (rs[0] + rs[1] + rs[2] + rs[3]) / (float)MHW;
  float ss = 0.f;
  for (int i = tid; i < PHW; i += 256) {
    int h = i / PW, w = i - h * PW;
    int r0, r1, c0, c1; float wr0, wr1, wc0, wc1;
    taps96(h, r0, r1, wr0, wr1);
    taps96(w, c0, c1, wc0, wc1);
    float v = wr0 * (wc0 * sm[r0 * MW + c0] + wc1 * sm[r0 * MW + c1]) +
              wr1 * (wc0 * sm[r1 * MW + c0] + wc1 * sm[r1 * MW + c1]);
    ss += v * v;
  }
  for (int off = 32; off; off >>= 1) ss += __shfl_down(ss, off);
  if ((tid & 63) == 0) rss[tid >> 6] = ss;
  __syncthreads();
  if (tid == 0) {
    float SS = rss[0] + rss[1] + rss[2] + rss[3];
    meanms[bc] = mean;
    msn[bc] = sqrtf(fmaxf(SS - (float)PHW * mean * mean, 0.f));
  }
}

// ---------------- Kernel C: batched fp32 GEMM  dot[ks][b][i][j] = sum_k ms[b,i,k]*padj[b,j,k]
// 64x128 tile, 4x8 acc/thread (1.5 B/MAC LDS), KSPLIT=4 -> 512 blocks (2/CU). Ascending-k
// fmaf chain per output within each K-quarter.
__device__ __forceinline__ int lat(int row, int k4) {
  return row * GKT + (k4 ^ (((row >> 3) & 7) << 2));
}

__global__ __launch_bounds__(256) void k_gemm(const float* __restrict__ A,
                                              const float* __restrict__ Bm,
                                              float* __restrict__ Cp) {
  __shared__ __align__(16) float Asm[2][GTM * GKT];   // 2 * 8 KB
  __shared__ __align__(16) float Bsm[2][GTN * GKT];   // 2 * 16 KB
  // XCD swizzle: XCD n&7 gets z = xcd*8 + 0..7 (all 8 xy-tiles each).
  const int n = blockIdx.x;                  // 0..511
  const int xcd = n & 7, slot = n >> 3;      // slot 0..63
  const int z = xcd * 8 + (slot >> 3);       // 0..63
  const int xy = slot & 7;                   // 0..7
  const int bi = xy >> 1, bj = xy & 1;       // bi 0..3, bj 0..1
  const int b = z >> 2, ks = z & 3;
  const int i0 = bi * GTM, j0 = bj * GTN;
  const int tid = threadIdx.x;
  const int ty = tid >> 4, tx = tid & 15;    // 16 x 16; rows ty*4+[0,4), cols tx*8+[0,8)
  const float* Ab = A + ((size_t)b * CC + i0) * MHW + ks * KQ;
  const float* Bb = Bm + ((size_t)b * CC + j0) * MHW + ks * KQ;
  float acc[4][8] = {};
  float4 ra[2], rb[4];

  const int srow = tid >> 3, sk4 = (tid & 7) << 2;

  auto load_regs = [&](int kt) {
#pragma unroll
    for (int qq = 0; qq < 2; ++qq) {
      int row = srow + qq * 32;
      ra[qq] = *(const float4*)(Ab + (size_t)row * MHW + kt + sk4);
    }
#pragma unroll
    for (int qq = 0; qq < 4; ++qq) {
      int row = srow + qq * 32;
      rb[qq] = *(const float4*)(Bb + (size_t)row * MHW + kt + sk4);
    }
  };
  auto store_lds = [&](int buf) {
#pragma unroll
    for (int qq = 0; qq < 2; ++qq)
      *(float4*)&Asm[buf][lat(srow + qq * 32, sk4)] = ra[qq];
#pragma unroll
    for (int qq = 0; qq < 4; ++qq)
      *(float4*)&Bsm[buf][lat(srow + qq * 32, sk4)] = rb[qq];
  };

  const int baseA = (ty * 4) * GKT;
  const int swzA = ((ty >> 1) & 7) << 2;     // rows ty*4+u: (row>>3)&7 == (ty>>1)&7
  const int baseB = (tx * 8) * GKT;
  const int swzB = (tx & 7) << 2;            // rows tx*8+v: (row>>3)&7 == tx&7

  load_regs(0);
  store_lds(0);
  __syncthreads();
  int cur = 0;
  for (int step = 0; step < GSTEPS; ++step) {
    if (step + 1 < GSTEPS) load_regs((step + 1) * GKT);
#pragma unroll
    for (int k4c = 0; k4c < GKT / 4; ++k4c) {
      const int k4 = k4c * 4;
      const int ka = k4 ^ swzA, kb = k4 ^ swzB;
      float4 a4[4], b4[8];
#pragma unroll
      for (int u = 0; u < 4; ++u)
        a4[u] = *(const float4*)&Asm[cur][baseA + u * GKT + ka];
#pragma unroll
      for (int v = 0; v < 8; ++v)
        b4[v] = *(const float4*)&Bsm[cur][baseB + v * GKT + kb];
#pragma unroll
      for (int kk = 0; kk < 4; ++kk)
#pragma unroll
        for (int u = 0; u < 4; ++u)
#pragma unroll
          for (int v = 0; v < 8; ++v)
            acc[u][v] = fmaf(((const float*)&a4[u])[kk], ((const float*)&b4[v])[kk], acc[u][v]);
    }
    if (step + 1 < GSTEPS) {
      store_lds(cur ^ 1);
      __syncthreads();
      cur ^= 1;
    }
  }
  float* outp = Cp + (((size_t)ks * CB + b) * CC + (i0 + ty * 4)) * CC + j0 + tx * 8;
#pragma unroll
  for (int u = 0; u < 4; ++u) {
    *(float4*)(outp + (size_t)u * CC + 0) = make_float4(acc[u][0], acc[u][1], acc[u][2], acc[u][3]);
    *(float4*)(outp + (size_t)u * CC + 4) = make_float4(acc[u][4], acc[u][5], acc[u][6], acc[u][7]);
  }
}

// ---------------- Kernel C2: per-row max/argmax of similarity ----------------
__global__ __launch_bounds__(256) void k_rowmax(const float* __restrict__ dotp,
                                                const float* __restrict__ meanp,
                                                const float* __restrict__ pn,
                                                const float* __restrict__ meanms,
                                                const float* __restrict__ msn,
                                                float* __restrict__ maxv,
                                                int* __restrict__ amax) {
  const int tid = threadIdx.x;
  const int r = blockIdx.x * 4 + (tid >> 6);
  const int lane = tid & 63;
  const int b = r >> 8;
  const size_t QS = (size_t)CB * CC * CC;
  const float* d0 = dotp + (size_t)r * CC;
  const float mm = meanms[r];
  const float inv = 100.f / msn[r];
  const int j = lane * 4;
  float4 v0 = *(const float4*)(d0 + j);
  float4 v1 = *(const float4*)(d0 + QS + j);
  float4 v2 = *(const float4*)(d0 + 2 * QS + j);
  float4 v3 = *(const float4*)(d0 + 3 * QS + j);
  float4 mp4 = *(const float4*)(meanp + b * CC + j);
  float4 pn4 = *(const float4*)(pn + b * CC + j);
  float sv[4];
  sv[0] = ((((v0.x + v1.x) + v2.x) + v3.x) - (float)PHW * mm * mp4.x) * inv / pn4.x;
  sv[1] = ((((v0.y + v1.y) + v2.y) + v3.y) - (float)PHW * mm * mp4.y) * inv / pn4.y;
  sv[2] = ((((v0.z + v1.z) + v2.z) + v3.z) - (float)PHW * mm * mp4.z) * inv / pn4.z;
  sv[3] = ((((v0.w + v1.w) + v2.w) + v3.w) - (float)PHW * mm * mp4.w) * inv / pn4.w;
  float best = sv[0]; int bj = j;
#pragma unroll
  for (int t = 1; t < 4; ++t)
    if (sv[t] > best) { best = sv[t]; bj = j + t; }
  for (int off = 32; off; off >>= 1) {
    float ov = __shfl_down(best, off);
    int oi = __shfl_down(bj, off);
    if (ov > best || (ov == best && oi < bj)) { best = ov; bj = oi; }
  }
  if (lane == 0) { maxv[r] = best; amax[r] = bj; }
}

// ---------------- Kernel D: group select + deterministic bitonic sort (per batch) ----------------
__global__ __launch_bounds__(256) void k_group(const float* __restrict__ maxv,
                                               const int* __restrict__ amax,
                                               float* __restrict__ sscore,
                                               int* __restrict__ svals,
                                               int* __restrict__ cnt) {
  const int b = blockIdx.x, tid = threadIdx.x;
  __shared__ float mv[CC];
  __shared__ int sidx[CC];
  __shared__ float gsc[CC];
  __shared__ int pres[CC];
  __shared__ unsigned long long keys[CC];
  __shared__ float r1[4], r2[4];
  __shared__ int r3[4];
  float v = maxv[b * CC + tid];
  sidx[tid] = amax[b * CC + tid];
  float m = v;
  for (int off = 32; off; off >>= 1) m = fmaxf(m, __shfl_down(m, off));
  if ((tid & 63) == 0) r1[tid >> 6] = m;
  __syncthreads();
  float mt = fmaxf(fmaxf(r1[0], r1[1]), fmaxf(r1[2], r1[3]));
  float e = __expf(v - mt);
  float s = e;
  for (int off = 32; off; off >>= 1) s += __shfl_down(s, off);
  if ((tid & 63) == 0) r2[tid >> 6] = s;
  __syncthreads();
  float st = r2[0] + r2[1] + r2[2] + r2[3];
  mv[tid] = e / st;
  __syncthreads();
  float g = 0.f; int p = 0;
  for (int i2 = 0; i2 < CC; ++i2)
    if (sidx[i2] == tid) { g += mv[i2]; p = 1; }
  gsc[tid] = g; pres[tid] = p;
  int pc = p;
  for (int off = 32; off; off >>= 1) pc += __shfl_down(pc, off);
  if ((tid & 63) == 0) r3[tid >> 6] = pc;
  __syncthreads();
  if (tid == 0) cnt[b] = r3[0] + r3[1] + r3[2] + r3[3];
  int c = 255 - tid;
  float val = pres[c] ? gsc[c] : -INFINITY;
  keys[tid] = ((unsigned long long)f2ord(val) << 32) | (unsigned)c;
  __syncthreads();
  for (int ksz = 2; ksz <= 256; ksz <<= 1) {
    for (int jj = ksz >> 1; jj > 0; jj >>= 1) {
      int ixj = tid ^ jj;
      if (ixj > tid) {
        unsigned long long a = keys[tid], o = keys[ixj];
        bool descBlock = ((tid & ksz) == 0);
        bool sw = descBlock ? (a < o) : (a > o);
        if (sw) { keys[tid] = o; keys[ixj] = a; }
      }
      __syncthreads();
    }
  }
  unsigned long long kk = keys[tid];
  int cc2 = (int)(kk & 0xFFFFFFFFull);
  float vv = pres[cc2] ? gsc[cc2] : -INFINITY;
  sscore[b * CC + tid] = vv;
  svals[b * CC + tid] = cc2;
}

// ---------------- Kernel E: min_k + softmax weights ----------------
__global__ __launch_bounds__(128) void k_wsel(const float* __restrict__ sscore,
                                              const int* __restrict__ cnt,
                                              float* __restrict__ wgt,
                                              int* __restrict__ minkp) {
  const int b = blockIdx.x, tid = threadIdx.x;
  int mn = 0x7fffffff;
#pragma unroll
  for (int t = 0; t < CB; ++t) mn = min(mn, cnt[t]);
  const int mink = (mn + 1) >> 1;
  if (b == 0 && tid == 0) *minkp = mink;
  __shared__ float sh1[2], sh2[2];
  float v = (tid < mink) ? sscore[b * CC + tid] : -INFINITY;
  float m = v;
  for (int off = 32; off; off >>= 1) m = fmaxf(m, __shfl_down(m, off));
  if ((tid & 63) == 0) sh1[tid >> 6] = m;
  __syncthreads();
  float mt = fmaxf(sh1[0], sh1[1]);
  float e = (tid < mink) ? __expf(v - mt) : 0.f;
  float s = e;
  for (int off = 32; off; off >>= 1) s += __shfl_down(s, off);
  if ((tid & 63) == 0) sh2[tid >> 6] = s;
  __syncthreads();
  float st = sh2[0] + sh2[1];
  if (tid < mink) wgt[b * 128 + tid] = e / st;
}

// ---------------- Kernel F1: mask[b,hw] = sum_k w[b,k]*sigmoid(fp[b,sel[k],hw])
// 4-way k-partition per block (576 blocks); deterministic LDS combine p0+p1+p2+p3.
__global__ __launch_bounds__(256) void k_mask(const float* __restrict__ fp,
                                              const float* __restrict__ wgt,
                                              const int* __restrict__ svals,
                                              const int* __restrict__ minkp,
                                              float* __restrict__ mask) {
  const int b = blockIdx.y;
  const int i = threadIdx.x & 63;
  const int kq = threadIdx.x >> 6;           // 0..3
  const int hw4 = blockIdx.x * 64 + i;       // float4 index < 2304
  const int mink = *minkp;
  const int qlo = (mink * kq) >> 2, qhi = (mink * (kq + 1)) >> 2;
  const float* base = fp + (size_t)b * CC * PHW;
  float4 acc = make_float4(0.f, 0.f, 0.f, 0.f);
  for (int k = qlo; k < qhi; ++k) {
    int c = svals[b * CC + k];
    float wk = wgt[b * 128 + k];
    float4 v = ((const float4*)(base + (size_t)c * PHW))[hw4];
    acc.x += wk * sigmoidf_(v.x);
    acc.y += wk * sigmoidf_(v.y);
    acc.z += wk * sigmoidf_(v.z);
    acc.w += wk * sigmoidf_(v.w);
  }
  __shared__ __align__(16) float4 sh[4][64];
  sh[kq][i] = acc;
  __syncthreads();
  if (kq == 0) {
    float4 a0 = sh[0][i], a1 = sh[1][i], a2 = sh[2][i], a3 = sh[3][i];
    float4 r;
    r.x = ((a0.x + a1.x) + a2.x) + a3.x;
    r.y = ((a0.y + a1.y) + a2.y) + a3.y;
    r.z = ((a0.z + a1.z) + a2.z) + a3.z;
    r.w = ((a0.w + a1.w) + a2.w) + a3.w;
    ((float4*)(mask + (size_t)b * PHW))[hw4] = r;
  }
}

// ---------------- Kernel F2: out = fp * (1 + mask) ----------------
__global__ __launch_bounds__(256) void k_out(const float* __restrict__ fp,
                                             const float* __restrict__ mask,
                                             float* __restrict__ out) {
  const int idx = blockIdx.x * 256 + threadIdx.x;
  const int img = idx / (PHW / 4);
  const int hw4 = idx - img * (PHW / 4);
  const int b = img >> 8;
  float4 mk = ((const float4*)mask)[b * (PHW / 4) + hw4];
  float4 v = ((const float4*)fp)[idx];
  float4 o;
  o.x = v.x * (1.f + mk.x);
  o.y = v.y * (1.f + mk.y);
  o.z = v.z * (1.f + mk.z);
  o.w = v.w * (1.f + mk.w);
  ((float4*)out)[idx] = o;
}

extern "C" void kernel_launch(void* const* d_in, const int* in_sizes, int n_in,
                              void* d_out, int out_size, void* d_ws, size_t ws_size,
                              hipStream_t stream) {
  (void)in_sizes; (void)n_in; (void)out_size;
  const float* fp = (const float*)d_in[0];
  const float* fms = (const float*)d_in[1];
  float* out = (float*)d_out;

  // Big scratch in d_out (dead before k_out overwrites it):
  //   padj: 9,437,184 floats; dot: 4*16*256*256 = 4,194,304 floats
  float* padj = out;
  float* dotp = out + (size_t)CB * CC * MHW;

  if (ws_size < (size_t)183000 * 4) return;
  float* wsf = (float*)d_ws;
  float* meanp = wsf;               // 4096
  float* pnv = wsf + 4096;          // 4096
  float* meanms = wsf + 8192;       // 4096
  float* msn = wsf + 12288;         // 4096
  float* maxv = wsf + 16384;        // 4096
  float* ssc = wsf + 20480;         // 4096
  float* wgt = wsf + 24576;         // 2048
  float* maskp = wsf + 26624;       // 147456 -> ends at 174080
  int* amax = (int*)(wsf + 174080); // 4096
  int* sv = (int*)(wsf + 178176);   // 4096
  int* cntp = (int*)(wsf + 182272); // 16
  int* minkp = (int*)(wsf + 182288);// 1

  k_pstats<<<CB * CC, 256, 0, stream>>>(fp, padj, meanp, pnv);
  k_msstats<<<CB * CC, 256, 0, stream>>>(fms, meanms, msn);
  k_gemm<<<512, 256, 0, stream>>>(fms, padj, dotp);
  k_rowmax<<<(CB * CC) / 4, 256, 0, stream>>>(dotp, meanp, pnv, meanms, msn, maxv, amax);
  k_group<<<CB, 256, 0, stream>>>(maxv, amax, ssc, sv, cntp);
  k_wsel<<<CB, 128, 0, stream>>>(ssc, cntp, wgt, minkp);
  k_mask<<<dim3(PHW / 4 / 64, CB), 256, 0, stream>>>(fp, wgt, sv, minkp, maskp);
  k_out<<<(CB * CC * PHW / 4) / 256, 256, 0, stream>>>(fp, maskp, out);
}

// Round 7
// 323.787 us; speedup vs baseline: 1.1857x; 1.0198x over previous
//
#include <hip/hip_runtime.h>
#include <math.h>
#include <float.h>

// Problem constants
constexpr int CB = 16;        // batch
constexpr int CC = 256;       // channels
constexpr int PH = 96, PW = 96, PHW = 9216;
constexpr int MH = 48, MW = 48, MHW = 2304;
constexpr int KSPLIT = 4;
constexpr int KQ = 576;       // MHW / KSPLIT
constexpr int GM = 64;        // GEMM i-tile
constexpr int GN = 128;       // GEMM j-tile
constexpr int GKT = 32;       // GEMM k-tile
constexpr int GSTEPS = KQ / GKT;  // 18

__device__ __forceinline__ float sigmoidf_(float x) { return 1.f / (1.f + __expf(-x)); }

__device__ __forceinline__ unsigned f2ord(float f) {
  unsigned u = __float_as_uint(f);
  return (u & 0x80000000u) ? ~u : (u | 0x80000000u);
}

// ---------------- Kernel A: f_p stats + fused bilinear-adjoint downsample ----------------
__global__ __launch_bounds__(256) void k_pstats(const float* __restrict__ fp,
                                                float* __restrict__ padj,
                                                float* __restrict__ meanp,
                                                float* __restrict__ pn) {
  __shared__ __align__(16) float sm[PHW];       // 36 KB
  __shared__ float rs[4], rss[4];
  const int bc = blockIdx.x;
  const int tid = threadIdx.x;
  const float* img = fp + (size_t)bc * PHW;
  float s = 0.f, ss = 0.f;
  for (int q = tid; q < PHW / 4; q += 256) {
    float4 v = ((const float4*)img)[q];
    ((float4*)sm)[q] = v;
    s += v.x + v.y + v.z + v.w;
    ss += v.x * v.x + v.y * v.y + v.z * v.z + v.w * v.w;
  }
  for (int off = 32; off; off >>= 1) { s += __shfl_down(s, off); ss += __shfl_down(ss, off); }
  if ((tid & 63) == 0) { rs[tid >> 6] = s; rss[tid >> 6] = ss; }
  __syncthreads();
  if (tid == 0) {
    float S = rs[0] + rs[1] + rs[2] + rs[3];
    float SS = rss[0] + rss[1] + rss[2] + rss[3];
    meanp[bc] = S / (float)PHW;
    pn[bc] = sqrtf(fmaxf(SS - S * S / (float)PHW, 0.f));
  }
  const int wid = tid >> 6, lane = tid & 63;
  float* outp = padj + (size_t)bc * MHW;
  for (int g = 0; g < 12; ++g) {
    const int u = g * 4 + wid;
    if (lane < 48) {
      const int w0 = 2 * lane;
      float t0, t1;
      if (u == 0) {
        float2 r0 = *(const float2*)&sm[w0];
        float2 r1 = *(const float2*)&sm[PW + w0];
        float2 r2 = *(const float2*)&sm[2 * PW + w0];
        t0 = r0.x + 0.75f * r1.x + 0.25f * r2.x;
        t1 = r0.y + 0.75f * r1.y + 0.25f * r2.y;
      } else if (u == MH - 1) {
        float2 ra = *(const float2*)&sm[(PH - 3) * PW + w0];
        float2 rb = *(const float2*)&sm[(PH - 2) * PW + w0];
        float2 rc = *(const float2*)&sm[(PH - 1) * PW + w0];
        t0 = 0.25f * ra.x + 0.75f * rb.x + rc.x;
        t1 = 0.25f * ra.y + 0.75f * rb.y + rc.y;
      } else {
        float2 r0 = *(const float2*)&sm[(2 * u - 1) * PW + w0];
        float2 r1 = *(const float2*)&sm[2 * u * PW + w0];
        float2 r2 = *(const float2*)&sm[(2 * u + 1) * PW + w0];
        float2 r3 = *(const float2*)&sm[(2 * u + 2) * PW + w0];
        t0 = 0.25f * (r0.x + r3.x) + 0.75f * (r1.x + r2.x);
        t1 = 0.25f * (r0.y + r3.y) + 0.75f * (r1.y + r2.y);
      }
      const float t1m = __shfl_up(t1, 1);
      const float t0p = __shfl_down(t0, 1);
      float val;
      if (lane == 0)
        val = t0 + 0.75f * t1 + 0.25f * t0p;
      else if (lane == MW - 1)
        val = 0.25f * t1m + 0.75f * t0 + t1;
      else
        val = 0.25f * (t1m + t0p) + 0.75f * (t0 + t1);
      outp[u * MW + lane] = val;
    }
  }
}

// ---------------- Kernel B: f_ms stats ----------------
__device__ __forceinline__ void taps96(int h, int& i0, int& i1, float& w0, float& w1) {
  if (h == 0) { i0 = 0; i1 = 0; w0 = 1.f; w1 = 0.f; }
  else if (h == 95) { i0 = 47; i1 = 47; w0 = 1.f; w1 = 0.f; }
  else if (h & 1) { int k = h >> 1; i0 = k; i1 = k + 1; w0 = 0.75f; w1 = 0.25f; }
  else { int k = h >> 1; i0 = k - 1; i1 = k; w0 = 0.25f; w1 = 0.75f; }
}

__global__ __launch_bounds__(256) void k_msstats(const float* __restrict__ fms,
                                                 float* __restrict__ meanms,
                                                 float* __restrict__ msn) {
  __shared__ __align__(16) float sm[MHW];
  __shared__ float rs[4], rss[4];
  const int bc = blockIdx.x, tid = threadIdx.x;
  const float* img = fms + (size_t)bc * MHW;
  float s = 0.f;
  for (int q = tid; q < MHW / 4; q += 256) {
    float4 v = ((const float4*)img)[q];
    ((float4*)sm)[q] = v;
    s += v.x + v.y + v.z + v.w;
  }
  for (int off = 32; off; off >>= 1) s += __shfl_down(s, off);
  if ((tid & 63) == 0) rs[tid >> 6] = s;
  __syncthreads();
  const float mean = (rs[0] + rs[1] + rs[2] + rs[3]) / (float)MHW;
  float ss = 0.f;
  for (int i = tid; i < PHW; i += 256) {
    int h = i / PW, w = i - h * PW;
    int r0, r1, c0, c1; float wr0, wr1, wc0, wc1;
    taps96(h, r0, r1, wr0, wr1);
    taps96(w, c0, c1, wc0, wc1);
    float v = wr0 * (wc0 * sm[r0 * MW + c0] + wc1 * sm[r0 * MW + c1]) +
              wr1 * (wc0 * sm[r1 * MW + c0] + wc1 * sm[r1 * MW + c1]);
    ss += v * v;
  }
  for (int off = 32; off; off >>= 1) ss += __shfl_down(ss, off);
  if ((tid & 63) == 0) rss[tid >> 6] = ss;
  __syncthreads();
  if (tid == 0) {
    float SS = rss[0] + rss[1] + rss[2] + rss[3];
    meanms[bc] = mean;
    msn[bc] = sqrtf(fmaxf(SS - (float)PHW * mean * mean, 0.f));
  }
}

// ---------------- Kernel C: batched fp32 GEMM (round-3 structure, KSPLIT=4)
// dot[ks][b][i][j] = sum_k ms[b,i,k]*padj[b,j,k]; k-major LDS [k][row+pad], 64x128 tile,
// 4x8 acc, per-k fragment reads. Ascending-k fmaf chain per output within each K-quarter.
__global__ __launch_bounds__(256) void k_gemm(const float* __restrict__ A,
                                              const float* __restrict__ Bm,
                                              float* __restrict__ Cp) {
  __shared__ __align__(16) float At[2][GKT][GM + 4];   // 2*32*68*4  = 17408 B
  __shared__ __align__(16) float Bt[2][GKT][GN + 4];   // 2*32*132*4 = 33792 B
  // XCD swizzle: XCD n&7 owns z = xcd*8 .. xcd*8+7 (all 8 xy-tiles each).
  const int n = blockIdx.x;                  // 0..511
  const int xcd = n & 7, slot = n >> 3;      // slot 0..63
  const int z = xcd * 8 + (slot >> 3);       // 0..63
  const int xy = slot & 7;                   // 0..7
  const int bx = xy & 3, by = xy >> 2;       // bx 0..3 (i), by 0..1 (j)
  const int b = z >> 2, ks = z & 3;
  const int i0 = bx * GM, j0 = by * GN;
  const int tid = threadIdx.x;
  const int ty = tid >> 4, tx = tid & 15;    // 16 x 16
  const float* Ab = A + ((size_t)b * CC + i0) * MHW + ks * KQ;
  const float* Bb = Bm + ((size_t)b * CC + j0) * MHW + ks * KQ;
  float acc[4][8] = {};
  float4 ra[2], rb[4];

  auto load_regs = [&](int kt) {
#pragma unroll
    for (int qq = 0; qq < 2; ++qq) {
      int q = tid + qq * 256;               // 512 tasks: 64 rows x 8 float4
      int row = q >> 3, k4 = (q & 7) << 2;
      ra[qq] = *(const float4*)(Ab + (size_t)row * MHW + kt + k4);
    }
#pragma unroll
    for (int qq = 0; qq < 4; ++qq) {
      int q = tid + qq * 256;               // 1024 tasks: 128 rows x 8 float4
      int row = q >> 3, k4 = (q & 7) << 2;
      rb[qq] = *(const float4*)(Bb + (size_t)row * MHW + kt + k4);
    }
  };
  auto store_lds = [&](int buf) {
#pragma unroll
    for (int qq = 0; qq < 2; ++qq) {
      int q = tid + qq * 256;
      int row = q >> 3, k4 = (q & 7) << 2;
      At[buf][k4 + 0][row] = ra[qq].x; At[buf][k4 + 1][row] = ra[qq].y;
      At[buf][k4 + 2][row] = ra[qq].z; At[buf][k4 + 3][row] = ra[qq].w;
    }
#pragma unroll
    for (int qq = 0; qq < 4; ++qq) {
      int q = tid + qq * 256;
      int row = q >> 3, k4 = (q & 7) << 2;
      Bt[buf][k4 + 0][row] = rb[qq].x; Bt[buf][k4 + 1][row] = rb[qq].y;
      Bt[buf][k4 + 2][row] = rb[qq].z; Bt[buf][k4 + 3][row] = rb[qq].w;
    }
  };

  load_regs(0);
  store_lds(0);
  __syncthreads();
  int cur = 0;
  for (int step = 0; step < GSTEPS; ++step) {
    if (step + 1 < GSTEPS) load_regs((step + 1) * GKT);
#pragma unroll
    for (int k = 0; k < GKT; ++k) {
      float a[4], bb[8];
      *(float4*)a = *(const float4*)&At[cur][k][ty * 4];
      *(float4*)&bb[0] = *(const float4*)&Bt[cur][k][tx * 8];
      *(float4*)&bb[4] = *(const float4*)&Bt[cur][k][tx * 8 + 4];
#pragma unroll
      for (int u = 0; u < 4; ++u)
#pragma unroll
        for (int v = 0; v < 8; ++v)
          acc[u][v] = fmaf(a[u], bb[v], acc[u][v]);
    }
    if (step + 1 < GSTEPS) {
      __syncthreads();
      store_lds(cur ^ 1);
      __syncthreads();
      cur ^= 1;
    }
  }
  float* outp = Cp + (((size_t)ks * CB + b) * CC + (i0 + ty * 4)) * CC + j0 + tx * 8;
#pragma unroll
  for (int u = 0; u < 4; ++u) {
    *(float4*)(outp + (size_t)u * CC + 0) = make_float4(acc[u][0], acc[u][1], acc[u][2], acc[u][3]);
    *(float4*)(outp + (size_t)u * CC + 4) = make_float4(acc[u][4], acc[u][5], acc[u][6], acc[u][7]);
  }
}

// ---------------- Kernel C2: per-row max/argmax of similarity (4 partials) ----------------
__global__ __launch_bounds__(256) void k_rowmax(const float* __restrict__ dotp,
                                                const float* __restrict__ meanp,
                                                const float* __restrict__ pn,
                                                const float* __restrict__ meanms,
                                                const float* __restrict__ msn,
                                                float* __restrict__ maxv,
                                                int* __restrict__ amax) {
  const int tid = threadIdx.x;
  const int r = blockIdx.x * 4 + (tid >> 6);
  const int lane = tid & 63;
  const int b = r >> 8;
  const size_t QS = (size_t)CB * CC * CC;
  const float* d0 = dotp + (size_t)r * CC;
  const float mm = meanms[r];
  const float inv = 100.f / msn[r];
  const int j = lane * 4;
  float4 v0 = *(const float4*)(d0 + j);
  float4 v1 = *(const float4*)(d0 + QS + j);
  float4 v2 = *(const float4*)(d0 + 2 * QS + j);
  float4 v3 = *(const float4*)(d0 + 3 * QS + j);
  float4 mp4 = *(const float4*)(meanp + b * CC + j);
  float4 pn4 = *(const float4*)(pn + b * CC + j);
  float sv[4];
  sv[0] = ((((v0.x + v1.x) + v2.x) + v3.x) - (float)PHW * mm * mp4.x) * inv / pn4.x;
  sv[1] = ((((v0.y + v1.y) + v2.y) + v3.y) - (float)PHW * mm * mp4.y) * inv / pn4.y;
  sv[2] = ((((v0.z + v1.z) + v2.z) + v3.z) - (float)PHW * mm * mp4.z) * inv / pn4.z;
  sv[3] = ((((v0.w + v1.w) + v2.w) + v3.w) - (float)PHW * mm * mp4.w) * inv / pn4.w;
  float best = sv[0]; int bj = j;
#pragma unroll
  for (int t = 1; t < 4; ++t)
    if (sv[t] > best) { best = sv[t]; bj = j + t; }
  for (int off = 32; off; off >>= 1) {
    float ov = __shfl_down(best, off);
    int oi = __shfl_down(bj, off);
    if (ov > best || (ov == best && oi < bj)) { best = ov; bj = oi; }
  }
  if (lane == 0) { maxv[r] = best; amax[r] = bj; }
}

// ---------------- Kernel D: group select + deterministic bitonic sort ----------------
__global__ __launch_bounds__(256) void k_group(const float* __restrict__ maxv,
                                               const int* __restrict__ amax,
                                               float* __restrict__ sscore,
                                               int* __restrict__ svals,
                                               int* __restrict__ cnt) {
  const int b = blockIdx.x, tid = threadIdx.x;
  __shared__ float mv[CC];
  __shared__ int sidx[CC];
  __shared__ float gsc[CC];
  __shared__ int pres[CC];
  __shared__ unsigned long long keys[CC];
  __shared__ float r1[4], r2[4];
  __shared__ int r3[4];
  float v = maxv[b * CC + tid];
  sidx[tid] = amax[b * CC + tid];
  float m = v;
  for (int off = 32; off; off >>= 1) m = fmaxf(m, __shfl_down(m, off));
  if ((tid & 63) == 0) r1[tid >> 6] = m;
  __syncthreads();
  float mt = fmaxf(fmaxf(r1[0], r1[1]), fmaxf(r1[2], r1[3]));
  float e = __expf(v - mt);
  float s = e;
  for (int off = 32; off; off >>= 1) s += __shfl_down(s, off);
  if ((tid & 63) == 0) r2[tid >> 6] = s;
  __syncthreads();
  float st = r2[0] + r2[1] + r2[2] + r2[3];
  mv[tid] = e / st;
  __syncthreads();
  float g = 0.f; int p = 0;
  for (int i2 = 0; i2 < CC; ++i2)
    if (sidx[i2] == tid) { g += mv[i2]; p = 1; }
  gsc[tid] = g; pres[tid] = p;
  int pc = p;
  for (int off = 32; off; off >>= 1) pc += __shfl_down(pc, off);
  if ((tid & 63) == 0) r3[tid >> 6] = pc;
  __syncthreads();
  if (tid == 0) cnt[b] = r3[0] + r3[1] + r3[2] + r3[3];
  int c = 255 - tid;
  float val = pres[c] ? gsc[c] : -INFINITY;
  keys[tid] = ((unsigned long long)f2ord(val) << 32) | (unsigned)c;
  __syncthreads();
  for (int ksz = 2; ksz <= 256; ksz <<= 1) {
    for (int jj = ksz >> 1; jj > 0; jj >>= 1) {
      int ixj = tid ^ jj;
      if (ixj > tid) {
        unsigned long long a = keys[tid], o = keys[ixj];
        bool descBlock = ((tid & ksz) == 0);
        bool sw = descBlock ? (a < o) : (a > o);
        if (sw) { keys[tid] = o; keys[ixj] = a; }
      }
      __syncthreads();
    }
  }
  unsigned long long kk = keys[tid];
  int cc2 = (int)(kk & 0xFFFFFFFFull);
  float vv = pres[cc2] ? gsc[cc2] : -INFINITY;
  sscore[b * CC + tid] = vv;
  svals[b * CC + tid] = cc2;
}

// ---------------- Kernel E: min_k + softmax weights ----------------
__global__ __launch_bounds__(128) void k_wsel(const float* __restrict__ sscore,
                                              const int* __restrict__ cnt,
                                              float* __restrict__ wgt,
                                              int* __restrict__ minkp) {
  const int b = blockIdx.x, tid = threadIdx.x;
  int mn = 0x7fffffff;
#pragma unroll
  for (int t = 0; t < CB; ++t) mn = min(mn, cnt[t]);
  const int mink = (mn + 1) >> 1;
  if (b == 0 && tid == 0) *minkp = mink;
  __shared__ float sh1[2], sh2[2];
  float v = (tid < mink) ? sscore[b * CC + tid] : -INFINITY;
  float m = v;
  for (int off = 32; off; off >>= 1) m = fmaxf(m, __shfl_down(m, off));
  if ((tid & 63) == 0) sh1[tid >> 6] = m;
  __syncthreads();
  float mt = fmaxf(sh1[0], sh1[1]);
  float e = (tid < mink) ? __expf(v - mt) : 0.f;
  float s = e;
  for (int off = 32; off; off >>= 1) s += __shfl_down(s, off);
  if ((tid & 63) == 0) sh2[tid >> 6] = s;
  __syncthreads();
  float st = sh2[0] + sh2[1];
  if (tid < mink) wgt[b * 128 + tid] = e / st;
}

// ---------------- Kernel F: fused mask + output
// Phase 1: mask[b,hw-chunk] = sum_k w*sigmoid(fp[b,sel[k],hw]) (4-way k-split, LDS combine
// identical to previous k_mask). Phase 2: out[b,c,hw] = fp*(1+mask) for all 256 c.
__global__ __launch_bounds__(256) void k_maskout(const float* __restrict__ fp,
                                                 const float* __restrict__ wgt,
                                                 const int* __restrict__ svals,
                                                 const int* __restrict__ minkp,
                                                 float* __restrict__ out) {
  const int b = blockIdx.y;
  const int i = threadIdx.x & 63;
  const int kq = threadIdx.x >> 6;           // 0..3
  const int hw4 = blockIdx.x * 64 + i;       // float4 index < 2304
  const int mink = *minkp;
  const int qlo = (mink * kq) >> 2, qhi = (mink * (kq + 1)) >> 2;
  const float* base = fp + (size_t)b * CC * PHW;
  float4 acc = make_float4(0.f, 0.f, 0.f, 0.f);
  for (int k = qlo; k < qhi; ++k) {
    int c = svals[b * CC + k];
    float wk = wgt[b * 128 + k];
    float4 v = ((const float4*)(base + (size_t)c * PHW))[hw4];
    acc.x += wk * sigmoidf_(v.x);
    acc.y += wk * sigmoidf_(v.y);
    acc.z += wk * sigmoidf_(v.z);
    acc.w += wk * sigmoidf_(v.w);
  }
  __shared__ __align__(16) float4 sh[4][64];
  __shared__ __align__(16) float4 msh[64];
  sh[kq][i] = acc;
  __syncthreads();
  if (kq == 0) {
    float4 a0 = sh[0][i], a1 = sh[1][i], a2 = sh[2][i], a3 = sh[3][i];
    float4 r;
    r.x = ((a0.x + a1.x) + a2.x) + a3.x;
    r.y = ((a0.y + a1.y) + a2.y) + a3.y;
    r.z = ((a0.z + a1.z) + a2.z) + a3.z;
    r.w = ((a0.w + a1.w) + a2.w) + a3.w;
    msh[i] = r;
  }
  __syncthreads();
  const float4 mk = msh[i];
  float* outb = out + (size_t)b * CC * PHW;
#pragma unroll 4
  for (int it = 0; it < 64; ++it) {
    const int c = it * 4 + kq;
    float4 v = ((const float4*)(base + (size_t)c * PHW))[hw4];
    float4 o;
    o.x = v.x * (1.f + mk.x);
    o.y = v.y * (1.f + mk.y);
    o.z = v.z * (1.f + mk.z);
    o.w = v.w * (1.f + mk.w);
    ((float4*)(outb + (size_t)c * PHW))[hw4] = o;
  }
}

extern "C" void kernel_launch(void* const* d_in, const int* in_sizes, int n_in,
                              void* d_out, int out_size, void* d_ws, size_t ws_size,
                              hipStream_t stream) {
  (void)in_sizes; (void)n_in; (void)out_size;
  const float* fp = (const float*)d_in[0];
  const float* fms = (const float*)d_in[1];
  float* out = (float*)d_out;

  // Big scratch in d_out (dead before k_maskout overwrites it):
  //   padj: 9,437,184 floats; dot: 4*16*256*256 = 16,777,216 floats (ends 26.2M < 37.7M)
  float* padj = out;
  float* dotp = out + (size_t)CB * CC * MHW;

  if (ws_size < (size_t)183000 * 4) return;
  float* wsf = (float*)d_ws;
  float* meanp = wsf;               // 4096
  float* pnv = wsf + 4096;          // 4096
  float* meanms = wsf + 8192;       // 4096
  float* msn = wsf + 12288;         // 4096
  float* maxv = wsf + 16384;        // 4096
  float* ssc = wsf + 20480;         // 4096
  float* wgt = wsf + 24576;         // 2048
  int* amax = (int*)(wsf + 174080); // 4096
  int* sv = (int*)(wsf + 178176);   // 4096
  int* cntp = (int*)(wsf + 182272); // 16
  int* minkp = (int*)(wsf + 182288);// 1

  k_pstats<<<CB * CC, 256, 0, stream>>>(fp, padj, meanp, pnv);
  k_msstats<<<CB * CC, 256, 0, stream>>>(fms, meanms, msn);
  k_gemm<<<512, 256, 0, stream>>>(fms, padj, dotp);
  k_rowmax<<<(CB * CC) / 4, 256, 0, stream>>>(dotp, meanp, pnv, meanms, msn, maxv, amax);
  k_group<<<CB, 256, 0, stream>>>(maxv, amax, ssc, sv, cntp);
  k_wsel<<<CB, 128, 0, stream>>>(ssc, cntp, wgt, minkp);
  k_maskout<<<dim3(PHW / 4 / 64, CB), 256, 0, stream>>>(fp, wgt, sv, minkp, out);
}

// Round 8
// 307.939 us; speedup vs baseline: 1.2468x; 1.0515x over previous
//
#include <hip/hip_runtime.h>
#include <hip/hip_bf16.h>
#include <math.h>
#include <float.h>

// Problem constants
constexpr int CB = 16;        // batch
constexpr int CC = 256;       // channels
constexpr int PH = 96, PW = 96, PHW = 9216;
constexpr int MH = 48, MW = 48, MHW = 2304;
constexpr int GSTEPS = MHW / 32;   // 72 mfma k-steps

typedef __bf16 bf16x8 __attribute__((ext_vector_type(8)));
typedef float f32x4 __attribute__((ext_vector_type(4)));

__device__ __forceinline__ float sigmoidf_(float x) { return 1.f / (1.f + __expf(-x)); }

__device__ __forceinline__ unsigned f2ord(float f) {
  unsigned u = __float_as_uint(f);
  return (u & 0x80000000u) ? ~u : (u | 0x80000000u);
}

// Exact 3-term bf16 split: v = b1 + b2 + b3 + O(2^-25 |v|).
__device__ __forceinline__ void split3(float v, unsigned short& h1, unsigned short& h2,
                                       unsigned short& h3) {
  __hip_bfloat16 b1 = __float2bfloat16(v);
  float r1 = v - __bfloat162float(b1);
  __hip_bfloat16 b2 = __float2bfloat16(r1);
  float r2 = r1 - __bfloat162float(b2);
  __hip_bfloat16 b3 = __float2bfloat16(r2);
  h1 = *reinterpret_cast<unsigned short*>(&b1);
  h2 = *reinterpret_cast<unsigned short*>(&b2);
  h3 = *reinterpret_cast<unsigned short*>(&b3);
}

// ---------------- Kernel A: f_p stats + fused bilinear-adjoint downsample -> bf16 planes
__global__ __launch_bounds__(256) void k_pstats(const float* __restrict__ fp,
                                                unsigned short* __restrict__ padjP,
                                                float* __restrict__ meanp,
                                                float* __restrict__ pn) {
  __shared__ __align__(16) float sm[PHW];       // 36 KB
  __shared__ float rs[4], rss[4];
  const int bc = blockIdx.x;
  const int tid = threadIdx.x;
  const float* img = fp + (size_t)bc * PHW;
  float s = 0.f, ss = 0.f;
  for (int q = tid; q < PHW / 4; q += 256) {
    float4 v = ((const float4*)img)[q];
    ((float4*)sm)[q] = v;
    s += v.x + v.y + v.z + v.w;
    ss += v.x * v.x + v.y * v.y + v.z * v.z + v.w * v.w;
  }
  for (int off = 32; off; off >>= 1) { s += __shfl_down(s, off); ss += __shfl_down(ss, off); }
  if ((tid & 63) == 0) { rs[tid >> 6] = s; rss[tid >> 6] = ss; }
  __syncthreads();
  if (tid == 0) {
    float S = rs[0] + rs[1] + rs[2] + rs[3];
    float SS = rss[0] + rss[1] + rss[2] + rss[3];
    meanp[bc] = S / (float)PHW;
    pn[bc] = sqrtf(fmaxf(SS - S * S / (float)PHW, 0.f));
  }
  const int wid = tid >> 6, lane = tid & 63;
  unsigned short* outp = padjP + (size_t)bc * 3 * MHW;   // [c][plane][k]
  for (int g = 0; g < 12; ++g) {
    const int u = g * 4 + wid;
    if (lane < 48) {
      const int w0 = 2 * lane;
      float t0, t1;
      if (u == 0) {
        float2 r0 = *(const float2*)&sm[w0];
        float2 r1 = *(const float2*)&sm[PW + w0];
        float2 r2 = *(const float2*)&sm[2 * PW + w0];
        t0 = r0.x + 0.75f * r1.x + 0.25f * r2.x;
        t1 = r0.y + 0.75f * r1.y + 0.25f * r2.y;
      } else if (u == MH - 1) {
        float2 ra = *(const float2*)&sm[(PH - 3) * PW + w0];
        float2 rb = *(const float2*)&sm[(PH - 2) * PW + w0];
        float2 rc = *(const float2*)&sm[(PH - 1) * PW + w0];
        t0 = 0.25f * ra.x + 0.75f * rb.x + rc.x;
        t1 = 0.25f * ra.y + 0.75f * rb.y + rc.y;
      } else {
        float2 r0 = *(const float2*)&sm[(2 * u - 1) * PW + w0];
        float2 r1 = *(const float2*)&sm[2 * u * PW + w0];
        float2 r2 = *(const float2*)&sm[(2 * u + 1) * PW + w0];
        float2 r3 = *(const float2*)&sm[(2 * u + 2) * PW + w0];
        t0 = 0.25f * (r0.x + r3.x) + 0.75f * (r1.x + r2.x);
        t1 = 0.25f * (r0.y + r3.y) + 0.75f * (r1.y + r2.y);
      }
      const float t1m = __shfl_up(t1, 1);
      const float t0p = __shfl_down(t0, 1);
      float val;
      if (lane == 0)
        val = t0 + 0.75f * t1 + 0.25f * t0p;
      else if (lane == MW - 1)
        val = 0.25f * t1m + 0.75f * t0 + t1;
      else
        val = 0.25f * (t1m + t0p) + 0.75f * (t0 + t1);
      unsigned short h1, h2, h3;
      split3(val, h1, h2, h3);
      const int idx = u * MW + lane;
      outp[idx] = h1;
      outp[MHW + idx] = h2;
      outp[2 * MHW + idx] = h3;
    }
  }
}

// ---------------- Kernel B: f_ms stats + bf16 planes ----------------
__device__ __forceinline__ void taps96(int h, int& i0, int& i1, float& w0, float& w1) {
  if (h == 0) { i0 = 0; i1 = 0; w0 = 1.f; w1 = 0.f; }
  else if (h == 95) { i0 = 47; i1 = 47; w0 = 1.f; w1 = 0.f; }
  else if (h & 1) { int k = h >> 1; i0 = k; i1 = k + 1; w0 = 0.75f; w1 = 0.25f; }
  else { int k = h >> 1; i0 = k - 1; i1 = k; w0 = 0.25f; w1 = 0.75f; }
}

__global__ __launch_bounds__(256) void k_msstats(const float* __restrict__ fms,
                                                 unsigned short* __restrict__ msP,
                                                 float* __restrict__ meanms,
                                                 float* __restrict__ msn) {
  __shared__ __align__(16) float sm[MHW];
  __shared__ float rs[4], rss[4];
  const int bc = blockIdx.x, tid = threadIdx.x;
  const float* img = fms + (size_t)bc * MHW;
  float s = 0.f;
  for (int q = tid; q < MHW / 4; q += 256) {
    float4 v = ((const float4*)img)[q];
    ((float4*)sm)[q] = v;
    s += v.x + v.y + v.z + v.w;
  }
  for (int off = 32; off; off >>= 1) s += __shfl_down(s, off);
  if ((tid & 63) == 0) rs[tid >> 6] = s;
  __syncthreads();
  const float mean = (rs[0] + rs[1] + rs[2] + rs[3]) / (float)MHW;
  float ss = 0.f;
  for (int i = tid; i < PHW; i += 256) {
    int h = i / PW, w = i - h * PW;
    int r0, r1, c0, c1; float wr0, wr1, wc0, wc1;
    taps96(h, r0, r1, wr0, wr1);
    taps96(w, c0, c1, wc0, wc1);
    float v = wr0 * (wc0 * sm[r0 * MW + c0] + wc1 * sm[r0 * MW + c1]) +
              wr1 * (wc0 * sm[r1 * MW + c0] + wc1 * sm[r1 * MW + c1]);
    ss += v * v;
  }
  for (int off = 32; off; off >>= 1) ss += __shfl_down(ss, off);
  if ((tid & 63) == 0) rss[tid >> 6] = ss;
  __syncthreads();
  if (tid == 0) {
    float SS = rss[0] + rss[1] + rss[2] + rss[3];
    meanms[bc] = mean;
    msn[bc] = sqrtf(fmaxf(SS - (float)PHW * mean * mean, 0.f));
  }
  unsigned short* outp = msP + (size_t)bc * 3 * MHW;   // [c][plane][k]
  for (int i = tid; i < MHW; i += 256) {
    unsigned short h1, h2, h3;
    split3(sm[i], h1, h2, h3);
    outp[i] = h1;
    outp[MHW + i] = h2;
    outp[2 * MHW + i] = h3;
  }
}

// ---------------- Kernel C: split-bf16 MFMA GEMM  dot[b][i][j] = sum_k ms[b,i,k]*padj[b,j,k]
// 64x64 tile, 4 waves (32x32 quadrant each), K=2304 whole, 6 plane-products accumulated
// in fp32 (error ~2^-24-level, selection-safe). LDS 60 KB single-buffer, reg-prefetch.
__global__ __launch_bounds__(256) void k_gemm(const unsigned short* __restrict__ msP,
                                              const unsigned short* __restrict__ padjP,
                                              float* __restrict__ dotp) {
  __shared__ unsigned short As[2][3][64][40];   // [mat][plane][row][k] = 61440 B
  const int n = blockIdx.x;                     // 0..255
  const int xcd = n & 7, slot = n >> 3;
  const int b = xcd * 2 + (slot >> 4);          // 2 batches per XCD
  const int xy = slot & 15;
  const int i0 = (xy >> 2) * 64, j0 = (xy & 3) * 64;
  const int tid = threadIdx.x, lane = tid & 63, wid = tid >> 6;
  const int wr = wid >> 1, wc = wid & 1;        // wave quadrant
  const int fr = lane & 15, fq = lane >> 4;

  const unsigned short* mats[2] = {
    msP + (size_t)(b * CC + i0) * 3 * MHW,
    padjP + (size_t)(b * CC + j0) * 3 * MHW
  };
  const unsigned short* gsrc[6];
  unsigned short* ldst[6];
#pragma unroll
  for (int q = 0; q < 6; ++q) {
    int t = tid + q * 256;                      // 1536 tasks: 128 rows x 3 planes x 4 chunks
    int ch = t & 3, pl = (t >> 2) % 3, r128 = t / 12;
    int mat = r128 >> 6, row = r128 & 63;
    gsrc[q] = mats[mat] + ((size_t)row * 3 + pl) * MHW + ch * 8;
    ldst[q] = &As[mat][pl][row][ch * 8];
  }
  bf16x8 stg[6];
  f32x4 acc[2][2] = {};

  auto g_load = [&](int kt) {
#pragma unroll
    for (int q = 0; q < 6; ++q) stg[q] = *(const bf16x8*)(gsrc[q] + kt);
  };
  auto l_store = [&]() {
#pragma unroll
    for (int q = 0; q < 6; ++q) *(bf16x8*)ldst[q] = stg[q];
  };

  g_load(0);
  l_store();
  __syncthreads();
  for (int step = 0; step < GSTEPS; ++step) {
    if (step + 1 < GSTEPS) g_load((step + 1) * 32);
    bf16x8 af[2][3], bfr[2][3];
#pragma unroll
    for (int ti = 0; ti < 2; ++ti)
#pragma unroll
      for (int p = 0; p < 3; ++p) {
        af[ti][p] = *(const bf16x8*)&As[0][p][wr * 32 + ti * 16 + fr][fq * 8];
        bfr[ti][p] = *(const bf16x8*)&As[1][p][wc * 32 + ti * 16 + fr][fq * 8];
      }
#pragma unroll
    for (int ti = 0; ti < 2; ++ti)
#pragma unroll
      for (int tj = 0; tj < 2; ++tj) {
        f32x4 c = acc[ti][tj];
        c = __builtin_amdgcn_mfma_f32_16x16x32_bf16(af[ti][0], bfr[tj][0], c, 0, 0, 0);
        c = __builtin_amdgcn_mfma_f32_16x16x32_bf16(af[ti][0], bfr[tj][1], c, 0, 0, 0);
        c = __builtin_amdgcn_mfma_f32_16x16x32_bf16(af[ti][1], bfr[tj][0], c, 0, 0, 0);
        c = __builtin_amdgcn_mfma_f32_16x16x32_bf16(af[ti][0], bfr[tj][2], c, 0, 0, 0);
        c = __builtin_amdgcn_mfma_f32_16x16x32_bf16(af[ti][1], bfr[tj][1], c, 0, 0, 0);
        c = __builtin_amdgcn_mfma_f32_16x16x32_bf16(af[ti][2], bfr[tj][0], c, 0, 0, 0);
        acc[ti][tj] = c;
      }
    __syncthreads();
    if (step + 1 < GSTEPS) {
      l_store();
      __syncthreads();
    }
  }
  // Epilogue: C/D layout col = lane&15, row = (lane>>4)*4 + reg  [m89-verified]
  float* drow = dotp + ((size_t)b * CC + i0) * CC + j0;
#pragma unroll
  for (int ti = 0; ti < 2; ++ti)
#pragma unroll
    for (int tj = 0; tj < 2; ++tj)
#pragma unroll
      for (int j = 0; j < 4; ++j) {
        int row = wr * 32 + ti * 16 + fq * 4 + j;
        int col = wc * 32 + tj * 16 + fr;
        drow[(size_t)row * CC + col] = acc[ti][tj][j];
      }
}

// ---------------- Kernel C2: per-row max/argmax of similarity ----------------
__global__ __launch_bounds__(256) void k_rowmax(const float* __restrict__ dotp,
                                                const float* __restrict__ meanp,
                                                const float* __restrict__ pn,
                                                const float* __restrict__ meanms,
                                                const float* __restrict__ msn,
                                                float* __restrict__ maxv,
                                                int* __restrict__ amax) {
  const int tid = threadIdx.x;
  const int r = blockIdx.x * 4 + (tid >> 6);
  const int lane = tid & 63;
  const int b = r >> 8;
  const float* d0 = dotp + (size_t)r * CC;
  const float mm = meanms[r];
  const float inv = 100.f / msn[r];
  const int j = lane * 4;
  float4 v0 = *(const float4*)(d0 + j);
  float4 mp4 = *(const float4*)(meanp + b * CC + j);
  float4 pn4 = *(const float4*)(pn + b * CC + j);
  float sv[4];
  sv[0] = (v0.x - (float)PHW * mm * mp4.x) * inv / pn4.x;
  sv[1] = (v0.y - (float)PHW * mm * mp4.y) * inv / pn4.y;
  sv[2] = (v0.z - (float)PHW * mm * mp4.z) * inv / pn4.z;
  sv[3] = (v0.w - (float)PHW * mm * mp4.w) * inv / pn4.w;
  float best = sv[0]; int bj = j;
#pragma unroll
  for (int t = 1; t < 4; ++t)
    if (sv[t] > best) { best = sv[t]; bj = j + t; }
  for (int off = 32; off; off >>= 1) {
    float ov = __shfl_down(best, off);
    int oi = __shfl_down(bj, off);
    if (ov > best || (ov == best && oi < bj)) { best = ov; bj = oi; }
  }
  if (lane == 0) { maxv[r] = best; amax[r] = bj; }
}

// ---------------- Kernel D: group select + deterministic bitonic sort ----------------
__global__ __launch_bounds__(256) void k_group(const float* __restrict__ maxv,
                                               const int* __restrict__ amax,
                                               float* __restrict__ sscore,
                                               int* __restrict__ svals,
                                               int* __restrict__ cnt) {
  const int b = blockIdx.x, tid = threadIdx.x;
  __shared__ float mv[CC];
  __shared__ int sidx[CC];
  __shared__ float gsc[CC];
  __shared__ int pres[CC];
  __shared__ unsigned long long keys[CC];
  __shared__ float r1[4], r2[4];
  __shared__ int r3[4];
  float v = maxv[b * CC + tid];
  sidx[tid] = amax[b * CC + tid];
  float m = v;
  for (int off = 32; off; off >>= 1) m = fmaxf(m, __shfl_down(m, off));
  if ((tid & 63) == 0) r1[tid >> 6] = m;
  __syncthreads();
  float mt = fmaxf(fmaxf(r1[0], r1[1]), fmaxf(r1[2], r1[3]));
  float e = __expf(v - mt);
  float s = e;
  for (int off = 32; off; off >>= 1) s += __shfl_down(s, off);
  if ((tid & 63) == 0) r2[tid >> 6] = s;
  __syncthreads();
  float st = r2[0] + r2[1] + r2[2] + r2[3];
  mv[tid] = e / st;
  __syncthreads();
  float g = 0.f; int p = 0;
  for (int i2 = 0; i2 < CC; ++i2)
    if (sidx[i2] == tid) { g += mv[i2]; p = 1; }
  gsc[tid] = g; pres[tid] = p;
  int pc = p;
  for (int off = 32; off; off >>= 1) pc += __shfl_down(pc, off);
  if ((tid & 63) == 0) r3[tid >> 6] = pc;
  __syncthreads();
  if (tid == 0) cnt[b] = r3[0] + r3[1] + r3[2] + r3[3];
  int c = 255 - tid;
  float val = pres[c] ? gsc[c] : -INFINITY;
  keys[tid] = ((unsigned long long)f2ord(val) << 32) | (unsigned)c;
  __syncthreads();
  for (int ksz = 2; ksz <= 256; ksz <<= 1) {
    for (int jj = ksz >> 1; jj > 0; jj >>= 1) {
      int ixj = tid ^ jj;
      if (ixj > tid) {
        unsigned long long a = keys[tid], o = keys[ixj];
        bool descBlock = ((tid & ksz) == 0);
        bool sw = descBlock ? (a < o) : (a > o);
        if (sw) { keys[tid] = o; keys[ixj] = a; }
      }
      __syncthreads();
    }
  }
  unsigned long long kk = keys[tid];
  int cc2 = (int)(kk & 0xFFFFFFFFull);
  float vv = pres[cc2] ? gsc[cc2] : -INFINITY;
  sscore[b * CC + tid] = vv;
  svals[b * CC + tid] = cc2;
}

// ---------------- Kernel E: min_k + softmax weights ----------------
__global__ __launch_bounds__(128) void k_wsel(const float* __restrict__ sscore,
                                              const int* __restrict__ cnt,
                                              float* __restrict__ wgt,
                                              int* __restrict__ minkp) {
  const int b = blockIdx.x, tid = threadIdx.x;
  int mn = 0x7fffffff;
#pragma unroll
  for (int t = 0; t < CB; ++t) mn = min(mn, cnt[t]);
  const int mink = (mn + 1) >> 1;
  if (b == 0 && tid == 0) *minkp = mink;
  __shared__ float sh1[2], sh2[2];
  float v = (tid < mink) ? sscore[b * CC + tid] : -INFINITY;
  float m = v;
  for (int off = 32; off; off >>= 1) m = fmaxf(m, __shfl_down(m, off));
  if ((tid & 63) == 0) sh1[tid >> 6] = m;
  __syncthreads();
  float mt = fmaxf(sh1[0], sh1[1]);
  float e = (tid < mink) ? __expf(v - mt) : 0.f;
  float s = e;
  for (int off = 32; off; off >>= 1) s += __shfl_down(s, off);
  if ((tid & 63) == 0) sh2[tid >> 6] = s;
  __syncthreads();
  float st = sh2[0] + sh2[1];
  if (tid < mink) wgt[b * 128 + tid] = e / st;
}

// ---------------- Kernel F: fused mask + output ----------------
__global__ __launch_bounds__(256) void k_maskout(const float* __restrict__ fp,
                                                 const float* __restrict__ wgt,
                                                 const int* __restrict__ svals,
                                                 const int* __restrict__ minkp,
                                                 float* __restrict__ out) {
  const int b = blockIdx.y;
  const int i = threadIdx.x & 63;
  const int kq = threadIdx.x >> 6;           // 0..3
  const int hw4 = blockIdx.x * 64 + i;       // float4 index < 2304
  const int mink = *minkp;
  const int qlo = (mink * kq) >> 2, qhi = (mink * (kq + 1)) >> 2;
  const float* base = fp + (size_t)b * CC * PHW;
  float4 acc = make_float4(0.f, 0.f, 0.f, 0.f);
  for (int k = qlo; k < qhi; ++k) {
    int c = svals[b * CC + k];
    float wk = wgt[b * 128 + k];
    float4 v = ((const float4*)(base + (size_t)c * PHW))[hw4];
    acc.x += wk * sigmoidf_(v.x);
    acc.y += wk * sigmoidf_(v.y);
    acc.z += wk * sigmoidf_(v.z);
    acc.w += wk * sigmoidf_(v.w);
  }
  __shared__ __align__(16) float4 sh[4][64];
  __shared__ __align__(16) float4 msh[64];
  sh[kq][i] = acc;
  __syncthreads();
  if (kq == 0) {
    float4 a0 = sh[0][i], a1 = sh[1][i], a2 = sh[2][i], a3 = sh[3][i];
    float4 r;
    r.x = ((a0.x + a1.x) + a2.x) + a3.x;
    r.y = ((a0.y + a1.y) + a2.y) + a3.y;
    r.z = ((a0.z + a1.z) + a2.z) + a3.z;
    r.w = ((a0.w + a1.w) + a2.w) + a3.w;
    msh[i] = r;
  }
  __syncthreads();
  const float4 mk = msh[i];
  float* outb = out + (size_t)b * CC * PHW;
#pragma unroll 4
  for (int it = 0; it < 64; ++it) {
    const int c = it * 4 + kq;
    float4 v = ((const float4*)(base + (size_t)c * PHW))[hw4];
    float4 o;
    o.x = v.x * (1.f + mk.x);
    o.y = v.y * (1.f + mk.y);
    o.z = v.z * (1.f + mk.z);
    o.w = v.w * (1.f + mk.w);
    ((float4*)(outb + (size_t)c * PHW))[hw4] = o;
  }
}

extern "C" void kernel_launch(void* const* d_in, const int* in_sizes, int n_in,
                              void* d_out, int out_size, void* d_ws, size_t ws_size,
                              hipStream_t stream) {
  (void)in_sizes; (void)n_in; (void)out_size;
  const float* fp = (const float*)d_in[0];
  const float* fms = (const float*)d_in[1];
  float* out = (float*)d_out;

  // Big scratch in d_out (dead before k_maskout overwrites it):
  //   padjP: 16*256*3*2304 ushorts = 14,155,776 float-slots
  //   msP  : same, at float-offset 14,155,776
  //   dot  : 16*256*256 floats at float-offset 28,311,552  (ends 29.36M < 37.75M)
  unsigned short* padjP = (unsigned short*)out;
  unsigned short* msP = (unsigned short*)(out + (size_t)14155776);
  float* dotp = out + (size_t)28311552;

  if (ws_size < (size_t)183000 * 4) return;
  float* wsf = (float*)d_ws;
  float* meanp = wsf;               // 4096
  float* pnv = wsf + 4096;          // 4096
  float* meanms = wsf + 8192;       // 4096
  float* msn = wsf + 12288;         // 4096
  float* maxv = wsf + 16384;        // 4096
  float* ssc = wsf + 20480;         // 4096
  float* wgt = wsf + 24576;         // 2048
  int* amax = (int*)(wsf + 174080); // 4096
  int* sv = (int*)(wsf + 178176);   // 4096
  int* cntp = (int*)(wsf + 182272); // 16
  int* minkp = (int*)(wsf + 182288);// 1

  k_pstats<<<CB * CC, 256, 0, stream>>>(fp, padjP, meanp, pnv);
  k_msstats<<<CB * CC, 256, 0, stream>>>(fms, msP, meanms, msn);
  k_gemm<<<256, 256, 0, stream>>>(msP, padjP, dotp);
  k_rowmax<<<(CB * CC) / 4, 256, 0, stream>>>(dotp, meanp, pnv, meanms, msn, maxv, amax);
  k_group<<<CB, 256, 0, stream>>>(maxv, amax, ssc, sv, cntp);
  k_wsel<<<CB, 128, 0, stream>>>(ssc, cntp, wgt, minkp);
  k_maskout<<<dim3(PHW / 4 / 64, CB), 256, 0, stream>>>(fp, wgt, sv, minkp, out);
}

// Round 9
// 295.708 us; speedup vs baseline: 1.2983x; 1.0414x over previous
//
#include <hip/hip_runtime.h>
#include <hip/hip_bf16.h>
#include <math.h>
#include <float.h>

// Problem constants
constexpr int CB = 16;        // batch
constexpr int CC = 256;       // channels
constexpr int PH = 96, PW = 96, PHW = 9216;
constexpr int MH = 48, MW = 48, MHW = 2304;
constexpr int GSTEPS = MHW / 32;   // 72 mfma k-steps

typedef __bf16 bf16x8 __attribute__((ext_vector_type(8)));
typedef float f32x4 __attribute__((ext_vector_type(4)));

__device__ __forceinline__ float sigmoidf_(float x) { return 1.f / (1.f + __expf(-x)); }

__device__ __forceinline__ unsigned f2ord(float f) {
  unsigned u = __float_as_uint(f);
  return (u & 0x80000000u) ? ~u : (u | 0x80000000u);
}

// Exact 3-term bf16 split: v = b1 + b2 + b3 + O(2^-25 |v|).
__device__ __forceinline__ void split3(float v, unsigned short& h1, unsigned short& h2,
                                       unsigned short& h3) {
  __hip_bfloat16 b1 = __float2bfloat16(v);
  float r1 = v - __bfloat162float(b1);
  __hip_bfloat16 b2 = __float2bfloat16(r1);
  float r2 = r1 - __bfloat162float(b2);
  __hip_bfloat16 b3 = __float2bfloat16(r2);
  h1 = *reinterpret_cast<unsigned short*>(&b1);
  h2 = *reinterpret_cast<unsigned short*>(&b2);
  h3 = *reinterpret_cast<unsigned short*>(&b3);
}

// ---------------- Kernel A: f_p stats + bilinear-adjoint -> bf16 planes
// Stats: straight global read (same reduction order as before). Row-adjoint reads global
// (L1/L2-warm) into 18 KB LDS tmp; col-adjoint + split3 with paired ushort2 stores.
// All adjoint expressions verbatim from the original two-pass version.
__global__ __launch_bounds__(256) void k_pstats(const float* __restrict__ fp,
                                                unsigned short* __restrict__ padjP,
                                                float* __restrict__ meanp,
                                                float* __restrict__ pn) {
  __shared__ __align__(16) float tmp[MH][PW];   // 18 KB
  __shared__ float rs[4], rss[4];
  const int bc = blockIdx.x;
  const int tid = threadIdx.x;
  const float* img = fp + (size_t)bc * PHW;
  float s = 0.f, ss = 0.f;
  for (int q = tid; q < PHW / 4; q += 256) {
    float4 v = ((const float4*)img)[q];
    s += v.x + v.y + v.z + v.w;
    ss += v.x * v.x + v.y * v.y + v.z * v.z + v.w * v.w;
  }
  for (int off = 32; off; off >>= 1) { s += __shfl_down(s, off); ss += __shfl_down(ss, off); }
  if ((tid & 63) == 0) { rs[tid >> 6] = s; rss[tid >> 6] = ss; }
  // Row adjoint: tmp[u][w] = sum_h Wrow[h,u] * p[h,w]  (reads global; rows are L1/L2-warm)
  for (int idx = tid; idx < MH * PW; idx += 256) {
    const int u = idx / PW, w = idx - u * PW;
    float v;
    if (u == 0)
      v = img[w] + 0.75f * img[PW + w] + 0.25f * img[2 * PW + w];
    else if (u == MH - 1)
      v = 0.25f * img[(PH - 3) * PW + w] + 0.75f * img[(PH - 2) * PW + w] + img[(PH - 1) * PW + w];
    else
      v = 0.25f * (img[(2 * u - 1) * PW + w] + img[(2 * u + 2) * PW + w]) +
          0.75f * (img[2 * u * PW + w] + img[(2 * u + 1) * PW + w]);
    tmp[u][w] = v;
  }
  __syncthreads();
  if (tid == 0) {
    float S = rs[0] + rs[1] + rs[2] + rs[3];
    float SS = rss[0] + rss[1] + rss[2] + rss[3];
    meanp[bc] = S / (float)PHW;
    pn[bc] = sqrtf(fmaxf(SS - S * S / (float)PHW, 0.f));
  }
  // Col adjoint + split3; pairs (v0,v0+1) -> ushort2 stores per plane.
  unsigned short* outp = padjP + (size_t)bc * 3 * MHW;   // [c][plane][k]
  for (int idx = tid; idx < MH * (MW / 2); idx += 256) {
    const int u = idx / (MW / 2), j = idx - u * (MW / 2);
    const float* r = tmp[u];
    const int v0 = 2 * j, v1 = 2 * j + 1;
    float val0, val1;
    if (v0 == 0)
      val0 = r[0] + 0.75f * r[1] + 0.25f * r[2];
    else
      val0 = 0.25f * (r[2 * v0 - 1] + r[2 * v0 + 2]) + 0.75f * (r[2 * v0] + r[2 * v0 + 1]);
    if (v1 == MW - 1)
      val1 = 0.25f * r[PW - 3] + 0.75f * r[PW - 2] + r[PW - 1];
    else
      val1 = 0.25f * (r[2 * v1 - 1] + r[2 * v1 + 2]) + 0.75f * (r[2 * v1] + r[2 * v1 + 1]);
    unsigned short a1, a2, a3, b1, b2, b3;
    split3(val0, a1, a2, a3);
    split3(val1, b1, b2, b3);
    const int k = u * MW + v0;
    ushort2 t;
    t.x = a1; t.y = b1; *(ushort2*)&outp[k] = t;
    t.x = a2; t.y = b2; *(ushort2*)&outp[MHW + k] = t;
    t.x = a3; t.y = b3; *(ushort2*)&outp[2 * MHW + k] = t;
  }
}

// ---------------- Kernel B: f_ms stats + bf16 planes ----------------
__device__ __forceinline__ void taps96(int h, int& i0, int& i1, float& w0, float& w1) {
  if (h == 0) { i0 = 0; i1 = 0; w0 = 1.f; w1 = 0.f; }
  else if (h == 95) { i0 = 47; i1 = 47; w0 = 1.f; w1 = 0.f; }
  else if (h & 1) { int k = h >> 1; i0 = k; i1 = k + 1; w0 = 0.75f; w1 = 0.25f; }
  else { int k = h >> 1; i0 = k - 1; i1 = k; w0 = 0.25f; w1 = 0.75f; }
}

__global__ __launch_bounds__(256) void k_msstats(const float* __restrict__ fms,
                                                 unsigned short* __restrict__ msP,
                                                 float* __restrict__ meanms,
                                                 float* __restrict__ msn) {
  __shared__ __align__(16) float sm[MHW];
  __shared__ float rs[4], rss[4];
  const int bc = blockIdx.x, tid = threadIdx.x;
  const float* img = fms + (size_t)bc * MHW;
  float s = 0.f;
  for (int q = tid; q < MHW / 4; q += 256) {
    float4 v = ((const float4*)img)[q];
    ((float4*)sm)[q] = v;
    s += v.x + v.y + v.z + v.w;
  }
  for (int off = 32; off; off >>= 1) s += __shfl_down(s, off);
  if ((tid & 63) == 0) rs[tid >> 6] = s;
  __syncthreads();
  const float mean = (rs[0] + rs[1] + rs[2] + rs[3]) / (float)MHW;
  float ss = 0.f;
  for (int i = tid; i < PHW; i += 256) {
    int h = i / PW, w = i - h * PW;
    int r0, r1, c0, c1; float wr0, wr1, wc0, wc1;
    taps96(h, r0, r1, wr0, wr1);
    taps96(w, c0, c1, wc0, wc1);
    float v = wr0 * (wc0 * sm[r0 * MW + c0] + wc1 * sm[r0 * MW + c1]) +
              wr1 * (wc0 * sm[r1 * MW + c0] + wc1 * sm[r1 * MW + c1]);
    ss += v * v;
  }
  for (int off = 32; off; off >>= 1) ss += __shfl_down(ss, off);
  if ((tid & 63) == 0) rss[tid >> 6] = ss;
  __syncthreads();
  if (tid == 0) {
    float SS = rss[0] + rss[1] + rss[2] + rss[3];
    meanms[bc] = mean;
    msn[bc] = sqrtf(fmaxf(SS - (float)PHW * mean * mean, 0.f));
  }
  unsigned short* outp = msP + (size_t)bc * 3 * MHW;   // [c][plane][k]
  for (int i2 = tid; i2 < MHW / 2; i2 += 256) {
    const int i = 2 * i2;
    unsigned short a1, a2, a3, b1, b2, b3;
    split3(sm[i], a1, a2, a3);
    split3(sm[i + 1], b1, b2, b3);
    ushort2 t;
    t.x = a1; t.y = b1; *(ushort2*)&outp[i] = t;
    t.x = a2; t.y = b2; *(ushort2*)&outp[MHW + i] = t;
    t.x = a3; t.y = b3; *(ushort2*)&outp[2 * MHW + i] = t;
  }
}

// ---------------- Kernel C: split-bf16 MFMA GEMM (unchanged from round 8) ----------------
__global__ __launch_bounds__(256) void k_gemm(const unsigned short* __restrict__ msP,
                                              const unsigned short* __restrict__ padjP,
                                              float* __restrict__ dotp) {
  __shared__ unsigned short As[2][3][64][40];   // [mat][plane][row][k] = 61440 B
  const int n = blockIdx.x;                     // 0..255
  const int xcd = n & 7, slot = n >> 3;
  const int b = xcd * 2 + (slot >> 4);          // 2 batches per XCD
  const int xy = slot & 15;
  const int i0 = (xy >> 2) * 64, j0 = (xy & 3) * 64;
  const int tid = threadIdx.x, lane = tid & 63, wid = tid >> 6;
  const int wr = wid >> 1, wc = wid & 1;        // wave quadrant
  const int fr = lane & 15, fq = lane >> 4;

  const unsigned short* mats[2] = {
    msP + (size_t)(b * CC + i0) * 3 * MHW,
    padjP + (size_t)(b * CC + j0) * 3 * MHW
  };
  const unsigned short* gsrc[6];
  unsigned short* ldst[6];
#pragma unroll
  for (int q = 0; q < 6; ++q) {
    int t = tid + q * 256;                      // 1536 tasks: 128 rows x 3 planes x 4 chunks
    int ch = t & 3, pl = (t >> 2) % 3, r128 = t / 12;
    int mat = r128 >> 6, row = r128 & 63;
    gsrc[q] = mats[mat] + ((size_t)row * 3 + pl) * MHW + ch * 8;
    ldst[q] = &As[mat][pl][row][ch * 8];
  }
  bf16x8 stg[6];
  f32x4 acc[2][2] = {};

  auto g_load = [&](int kt) {
#pragma unroll
    for (int q = 0; q < 6; ++q) stg[q] = *(const bf16x8*)(gsrc[q] + kt);
  };
  auto l_store = [&]() {
#pragma unroll
    for (int q = 0; q < 6; ++q) *(bf16x8*)ldst[q] = stg[q];
  };

  g_load(0);
  l_store();
  __syncthreads();
  for (int step = 0; step < GSTEPS; ++step) {
    if (step + 1 < GSTEPS) g_load((step + 1) * 32);
    bf16x8 af[2][3], bfr[2][3];
#pragma unroll
    for (int ti = 0; ti < 2; ++ti)
#pragma unroll
      for (int p = 0; p < 3; ++p) {
        af[ti][p] = *(const bf16x8*)&As[0][p][wr * 32 + ti * 16 + fr][fq * 8];
        bfr[ti][p] = *(const bf16x8*)&As[1][p][wc * 32 + ti * 16 + fr][fq * 8];
      }
#pragma unroll
    for (int ti = 0; ti < 2; ++ti)
#pragma unroll
      for (int tj = 0; tj < 2; ++tj) {
        f32x4 c = acc[ti][tj];
        c = __builtin_amdgcn_mfma_f32_16x16x32_bf16(af[ti][0], bfr[tj][0], c, 0, 0, 0);
        c = __builtin_amdgcn_mfma_f32_16x16x32_bf16(af[ti][0], bfr[tj][1], c, 0, 0, 0);
        c = __builtin_amdgcn_mfma_f32_16x16x32_bf16(af[ti][1], bfr[tj][0], c, 0, 0, 0);
        c = __builtin_amdgcn_mfma_f32_16x16x32_bf16(af[ti][0], bfr[tj][2], c, 0, 0, 0);
        c = __builtin_amdgcn_mfma_f32_16x16x32_bf16(af[ti][1], bfr[tj][1], c, 0, 0, 0);
        c = __builtin_amdgcn_mfma_f32_16x16x32_bf16(af[ti][2], bfr[tj][0], c, 0, 0, 0);
        acc[ti][tj] = c;
      }
    __syncthreads();
    if (step + 1 < GSTEPS) {
      l_store();
      __syncthreads();
    }
  }
  // Epilogue: C/D layout col = lane&15, row = (lane>>4)*4 + reg  [m89-verified]
  float* drow = dotp + ((size_t)b * CC + i0) * CC + j0;
#pragma unroll
  for (int ti = 0; ti < 2; ++ti)
#pragma unroll
    for (int tj = 0; tj < 2; ++tj)
#pragma unroll
      for (int j = 0; j < 4; ++j) {
        int row = wr * 32 + ti * 16 + fq * 4 + j;
        int col = wc * 32 + tj * 16 + fr;
        drow[(size_t)row * CC + col] = acc[ti][tj][j];
      }
}

// ---------------- Kernel C2: per-row max/argmax of similarity ----------------
__global__ __launch_bounds__(256) void k_rowmax(const float* __restrict__ dotp,
                                                const float* __restrict__ meanp,
                                                const float* __restrict__ pn,
                                                const float* __restrict__ meanms,
                                                const float* __restrict__ msn,
                                                float* __restrict__ maxv,
                                                int* __restrict__ amax) {
  const int tid = threadIdx.x;
  const int r = blockIdx.x * 4 + (tid >> 6);
  const int lane = tid & 63;
  const int b = r >> 8;
  const float* d0 = dotp + (size_t)r * CC;
  const float mm = meanms[r];
  const float inv = 100.f / msn[r];
  const int j = lane * 4;
  float4 v0 = *(const float4*)(d0 + j);
  float4 mp4 = *(const float4*)(meanp + b * CC + j);
  float4 pn4 = *(const float4*)(pn + b * CC + j);
  float sv[4];
  sv[0] = (v0.x - (float)PHW * mm * mp4.x) * inv / pn4.x;
  sv[1] = (v0.y - (float)PHW * mm * mp4.y) * inv / pn4.y;
  sv[2] = (v0.z - (float)PHW * mm * mp4.z) * inv / pn4.z;
  sv[3] = (v0.w - (float)PHW * mm * mp4.w) * inv / pn4.w;
  float best = sv[0]; int bj = j;
#pragma unroll
  for (int t = 1; t < 4; ++t)
    if (sv[t] > best) { best = sv[t]; bj = j + t; }
  for (int off = 32; off; off >>= 1) {
    float ov = __shfl_down(best, off);
    int oi = __shfl_down(bj, off);
    if (ov > best || (ov == best && oi < bj)) { best = ov; bj = oi; }
  }
  if (lane == 0) { maxv[r] = best; amax[r] = bj; }
}

// ---------------- Kernel D: group select + deterministic bitonic sort ----------------
__global__ __launch_bounds__(256) void k_group(const float* __restrict__ maxv,
                                               const int* __restrict__ amax,
                                               float* __restrict__ sscore,
                                               int* __restrict__ svals,
                                               int* __restrict__ cnt) {
  const int b = blockIdx.x, tid = threadIdx.x;
  __shared__ float mv[CC];
  __shared__ int sidx[CC];
  __shared__ float gsc[CC];
  __shared__ int pres[CC];
  __shared__ unsigned long long keys[CC];
  __shared__ float r1[4], r2[4];
  __shared__ int r3[4];
  float v = maxv[b * CC + tid];
  sidx[tid] = amax[b * CC + tid];
  float m = v;
  for (int off = 32; off; off >>= 1) m = fmaxf(m, __shfl_down(m, off));
  if ((tid & 63) == 0) r1[tid >> 6] = m;
  __syncthreads();
  float mt = fmaxf(fmaxf(r1[0], r1[1]), fmaxf(r1[2], r1[3]));
  float e = __expf(v - mt);
  float s = e;
  for (int off = 32; off; off >>= 1) s += __shfl_down(s, off);
  if ((tid & 63) == 0) r2[tid >> 6] = s;
  __syncthreads();
  float st = r2[0] + r2[1] + r2[2] + r2[3];
  mv[tid] = e / st;
  __syncthreads();
  float g = 0.f; int p = 0;
  for (int i2 = 0; i2 < CC; ++i2)
    if (sidx[i2] == tid) { g += mv[i2]; p = 1; }
  gsc[tid] = g; pres[tid] = p;
  int pc = p;
  for (int off = 32; off; off >>= 1) pc += __shfl_down(pc, off);
  if ((tid & 63) == 0) r3[tid >> 6] = pc;
  __syncthreads();
  if (tid == 0) cnt[b] = r3[0] + r3[1] + r3[2] + r3[3];
  int c = 255 - tid;
  float val = pres[c] ? gsc[c] : -INFINITY;
  keys[tid] = ((unsigned long long)f2ord(val) << 32) | (unsigned)c;
  __syncthreads();
  for (int ksz = 2; ksz <= 256; ksz <<= 1) {
    for (int jj = ksz >> 1; jj > 0; jj >>= 1) {
      int ixj = tid ^ jj;
      if (ixj > tid) {
        unsigned long long a = keys[tid], o = keys[ixj];
        bool descBlock = ((tid & ksz) == 0);
        bool sw = descBlock ? (a < o) : (a > o);
        if (sw) { keys[tid] = o; keys[ixj] = a; }
      }
      __syncthreads();
    }
  }
  unsigned long long kk = keys[tid];
  int cc2 = (int)(kk & 0xFFFFFFFFull);
  float vv = pres[cc2] ? gsc[cc2] : -INFINITY;
  sscore[b * CC + tid] = vv;
  svals[b * CC + tid] = cc2;
}

// ---------------- Kernel E: min_k + softmax weights ----------------
__global__ __launch_bounds__(128) void k_wsel(const float* __restrict__ sscore,
                                              const int* __restrict__ cnt,
                                              float* __restrict__ wgt,
                                              int* __restrict__ minkp) {
  const int b = blockIdx.x, tid = threadIdx.x;
  int mn = 0x7fffffff;
#pragma unroll
  for (int t = 0; t < CB; ++t) mn = min(mn, cnt[t]);
  const int mink = (mn + 1) >> 1;
  if (b == 0 && tid == 0) *minkp = mink;
  __shared__ float sh1[2], sh2[2];
  float v = (tid < mink) ? sscore[b * CC + tid] : -INFINITY;
  float m = v;
  for (int off = 32; off; off >>= 1) m = fmaxf(m, __shfl_down(m, off));
  if ((tid & 63) == 0) sh1[tid >> 6] = m;
  __syncthreads();
  float mt = fmaxf(sh1[0], sh1[1]);
  float e = (tid < mink) ? __expf(v - mt) : 0.f;
  float s = e;
  for (int off = 32; off; off >>= 1) s += __shfl_down(s, off);
  if ((tid & 63) == 0) sh2[tid >> 6] = s;
  __syncthreads();
  float st = sh2[0] + sh2[1];
  if (tid < mink) wgt[b * 128 + tid] = e / st;
}

// ---------------- Kernel F: fused mask + output, fine grid (2304 blocks)
// Block = 16 float4 positions x one batch. Phase 1: 16-way k-partition mask; phase 2:
// all 256 channels apply.
__global__ __launch_bounds__(256) void k_maskout(const float* __restrict__ fp,
                                                 const float* __restrict__ wgt,
                                                 const int* __restrict__ svals,
                                                 const int* __restrict__ minkp,
                                                 float* __restrict__ out) {
  const int b = blockIdx.y;
  const int pos = threadIdx.x & 15;
  const int kq = threadIdx.x >> 4;           // 0..15
  const int hw4 = blockIdx.x * 16 + pos;     // float4 index < 2304
  const int mink = *minkp;
  const int qlo = (mink * kq) >> 4, qhi = (mink * (kq + 1)) >> 4;
  const float* base = fp + (size_t)b * CC * PHW;
  float4 acc = make_float4(0.f, 0.f, 0.f, 0.f);
  for (int k = qlo; k < qhi; ++k) {
    int c = svals[b * CC + k];
    float wk = wgt[b * 128 + k];
    float4 v = ((const float4*)(base + (size_t)c * PHW))[hw4];
    acc.x += wk * sigmoidf_(v.x);
    acc.y += wk * sigmoidf_(v.y);
    acc.z += wk * sigmoidf_(v.z);
    acc.w += wk * sigmoidf_(v.w);
  }
  __shared__ __align__(16) float4 sh[16][16];
  __shared__ __align__(16) float4 msh[16];
  sh[kq][pos] = acc;
  __syncthreads();
  if (kq == 0) {
    float4 r = sh[0][pos];
#pragma unroll
    for (int t = 1; t < 16; ++t) {
      float4 a = sh[t][pos];
      r.x += a.x; r.y += a.y; r.z += a.z; r.w += a.w;
    }
    msh[pos] = r;
  }
  __syncthreads();
  const float4 mk = msh[pos];
  float* outb = out + (size_t)b * CC * PHW;
#pragma unroll 4
  for (int it = 0; it < 16; ++it) {
    const int c = it * 16 + kq;
    float4 v = ((const float4*)(base + (size_t)c * PHW))[hw4];
    float4 o;
    o.x = v.x * (1.f + mk.x);
    o.y = v.y * (1.f + mk.y);
    o.z = v.z * (1.f + mk.z);
    o.w = v.w * (1.f + mk.w);
    ((float4*)(outb + (size_t)c * PHW))[hw4] = o;
  }
}

extern "C" void kernel_launch(void* const* d_in, const int* in_sizes, int n_in,
                              void* d_out, int out_size, void* d_ws, size_t ws_size,
                              hipStream_t stream) {
  (void)in_sizes; (void)n_in; (void)out_size;
  const float* fp = (const float*)d_in[0];
  const float* fms = (const float*)d_in[1];
  float* out = (float*)d_out;

  // Big scratch in d_out (dead before k_maskout overwrites it):
  //   padjP: 16*256*3*2304 ushorts = 14,155,776 float-slots
  //   msP  : same, at float-offset 14,155,776
  //   dot  : 16*256*256 floats at float-offset 28,311,552  (ends 29.36M < 37.75M)
  unsigned short* padjP = (unsigned short*)out;
  unsigned short* msP = (unsigned short*)(out + (size_t)14155776);
  float* dotp = out + (size_t)28311552;

  if (ws_size < (size_t)183000 * 4) return;
  float* wsf = (float*)d_ws;
  float* meanp = wsf;               // 4096
  float* pnv = wsf + 4096;          // 4096
  float* meanms = wsf + 8192;       // 4096
  float* msn = wsf + 12288;         // 4096
  float* maxv = wsf + 16384;        // 4096
  float* ssc = wsf + 20480;         // 4096
  float* wgt = wsf + 24576;         // 2048
  int* amax = (int*)(wsf + 174080); // 4096
  int* sv = (int*)(wsf + 178176);   // 4096
  int* cntp = (int*)(wsf + 182272); // 16
  int* minkp = (int*)(wsf + 182288);// 1

  k_pstats<<<CB * CC, 256, 0, stream>>>(fp, padjP, meanp, pnv);
  k_msstats<<<CB * CC, 256, 0, stream>>>(fms, msP, meanms, msn);
  k_gemm<<<256, 256, 0, stream>>>(msP, padjP, dotp);
  k_rowmax<<<(CB * CC) / 4, 256, 0, stream>>>(dotp, meanp, pnv, meanms, msn, maxv, amax);
  k_group<<<CB, 256, 0, stream>>>(maxv, amax, ssc, sv, cntp);
  k_wsel<<<CB, 128, 0, stream>>>(ssc, cntp, wgt, minkp);
  k_maskout<<<dim3(PHW / 4 / 16, CB), 256, 0, stream>>>(fp, wgt, sv, minkp, out);
}

// Round 10
// 285.728 us; speedup vs baseline: 1.3437x; 1.0349x over previous
//
#include <hip/hip_runtime.h>
#include <hip/hip_bf16.h>
#include <math.h>
#include <float.h>

// Problem constants
constexpr int CB = 16;        // batch
constexpr int CC = 256;       // channels
constexpr int PH = 96, PW = 96, PHW = 9216;
constexpr int MH = 48, MW = 48, MHW = 2304;
constexpr int GSTEPS = MHW / 32;   // 72 mfma k-steps

typedef __bf16 bf16x8 __attribute__((ext_vector_type(8)));
typedef float f32x4 __attribute__((ext_vector_type(4)));

__device__ __forceinline__ float sigmoidf_(float x) { return 1.f / (1.f + __expf(-x)); }

__device__ __forceinline__ unsigned f2ord(float f) {
  unsigned u = __float_as_uint(f);
  return (u & 0x80000000u) ? ~u : (u | 0x80000000u);
}

// Exact 3-term bf16 split: v = b1 + b2 + b3 + O(2^-25 |v|).
__device__ __forceinline__ void split3(float v, unsigned short& h1, unsigned short& h2,
                                       unsigned short& h3) {
  __hip_bfloat16 b1 = __float2bfloat16(v);
  float r1 = v - __bfloat162float(b1);
  __hip_bfloat16 b2 = __float2bfloat16(r1);
  float r2 = r1 - __bfloat162float(b2);
  __hip_bfloat16 b3 = __float2bfloat16(r2);
  h1 = *reinterpret_cast<unsigned short*>(&b1);
  h2 = *reinterpret_cast<unsigned short*>(&b2);
  h3 = *reinterpret_cast<unsigned short*>(&b3);
}

__device__ __forceinline__ void taps96(int h, int& i0, int& i1, float& w0, float& w1) {
  if (h == 0) { i0 = 0; i1 = 0; w0 = 1.f; w1 = 0.f; }
  else if (h == 95) { i0 = 47; i1 = 47; w0 = 1.f; w1 = 0.f; }
  else if (h & 1) { int k = h >> 1; i0 = k; i1 = k + 1; w0 = 0.75f; w1 = 0.25f; }
  else { int k = h >> 1; i0 = k - 1; i1 = k; w0 = 0.25f; w1 = 0.75f; }
}

// ---------------- Kernel A+B merged: stats + bf16 planes for both inputs
// blocks [0,4096): f_p path (identical to round-9 k_pstats);
// blocks [4096,8192): f_ms path (identical to round-9 k_msstats).
__global__ __launch_bounds__(256) void k_stats(const float* __restrict__ fp,
                                               const float* __restrict__ fms,
                                               unsigned short* __restrict__ padjP,
                                               unsigned short* __restrict__ msP,
                                               float* __restrict__ meanp,
                                               float* __restrict__ pn,
                                               float* __restrict__ meanms,
                                               float* __restrict__ msn) {
  __shared__ __align__(16) float smem[MH * PW];   // 18.4 KB (aliased by both paths)
  __shared__ float rs[4], rss[4];
  const int tid = threadIdx.x;
  if (blockIdx.x < 4096) {
    // ---- f_p path ----
    const int bc = blockIdx.x;
    float (*tmp)[PW] = (float(*)[PW])smem;
    const float* img = fp + (size_t)bc * PHW;
    float s = 0.f, ss = 0.f;
    for (int q = tid; q < PHW / 4; q += 256) {
      float4 v = ((const float4*)img)[q];
      s += v.x + v.y + v.z + v.w;
      ss += v.x * v.x + v.y * v.y + v.z * v.z + v.w * v.w;
    }
    for (int off = 32; off; off >>= 1) { s += __shfl_down(s, off); ss += __shfl_down(ss, off); }
    if ((tid & 63) == 0) { rs[tid >> 6] = s; rss[tid >> 6] = ss; }
    // Row adjoint: tmp[u][w] = sum_h Wrow[h,u] * p[h,w]  (global reads, L1/L2-warm)
    for (int idx = tid; idx < MH * PW; idx += 256) {
      const int u = idx / PW, w = idx - u * PW;
      float v;
      if (u == 0)
        v = img[w] + 0.75f * img[PW + w] + 0.25f * img[2 * PW + w];
      else if (u == MH - 1)
        v = 0.25f * img[(PH - 3) * PW + w] + 0.75f * img[(PH - 2) * PW + w] + img[(PH - 1) * PW + w];
      else
        v = 0.25f * (img[(2 * u - 1) * PW + w] + img[(2 * u + 2) * PW + w]) +
            0.75f * (img[2 * u * PW + w] + img[(2 * u + 1) * PW + w]);
      tmp[u][w] = v;
    }
    __syncthreads();
    if (tid == 0) {
      float S = rs[0] + rs[1] + rs[2] + rs[3];
      float SS = rss[0] + rss[1] + rss[2] + rss[3];
      meanp[bc] = S / (float)PHW;
      pn[bc] = sqrtf(fmaxf(SS - S * S / (float)PHW, 0.f));
    }
    unsigned short* outp = padjP + (size_t)bc * 3 * MHW;   // [c][plane][k]
    for (int idx = tid; idx < MH * (MW / 2); idx += 256) {
      const int u = idx / (MW / 2), j = idx - u * (MW / 2);
      const float* r = tmp[u];
      const int v0 = 2 * j, v1 = 2 * j + 1;
      float val0, val1;
      if (v0 == 0)
        val0 = r[0] + 0.75f * r[1] + 0.25f * r[2];
      else
        val0 = 0.25f * (r[2 * v0 - 1] + r[2 * v0 + 2]) + 0.75f * (r[2 * v0] + r[2 * v0 + 1]);
      if (v1 == MW - 1)
        val1 = 0.25f * r[PW - 3] + 0.75f * r[PW - 2] + r[PW - 1];
      else
        val1 = 0.25f * (r[2 * v1 - 1] + r[2 * v1 + 2]) + 0.75f * (r[2 * v1] + r[2 * v1 + 1]);
      unsigned short a1, a2, a3, b1, b2, b3;
      split3(val0, a1, a2, a3);
      split3(val1, b1, b2, b3);
      const int k = u * MW + v0;
      ushort2 t;
      t.x = a1; t.y = b1; *(ushort2*)&outp[k] = t;
      t.x = a2; t.y = b2; *(ushort2*)&outp[MHW + k] = t;
      t.x = a3; t.y = b3; *(ushort2*)&outp[2 * MHW + k] = t;
    }
  } else {
    // ---- f_ms path ----
    const int bc = blockIdx.x - 4096;
    float* sm = smem;
    const float* img = fms + (size_t)bc * MHW;
    float s = 0.f;
    for (int q = tid; q < MHW / 4; q += 256) {
      float4 v = ((const float4*)img)[q];
      ((float4*)sm)[q] = v;
      s += v.x + v.y + v.z + v.w;
    }
    for (int off = 32; off; off >>= 1) s += __shfl_down(s, off);
    if ((tid & 63) == 0) rs[tid >> 6] = s;
    __syncthreads();
    const float mean = (rs[0] + rs[1] + rs[2] + rs[3]) / (float)MHW;
    float ss = 0.f;
    for (int i = tid; i < PHW; i += 256) {
      int h = i / PW, w = i - h * PW;
      int r0, r1, c0, c1; float wr0, wr1, wc0, wc1;
      taps96(h, r0, r1, wr0, wr1);
      taps96(w, c0, c1, wc0, wc1);
      float v = wr0 * (wc0 * sm[r0 * MW + c0] + wc1 * sm[r0 * MW + c1]) +
                wr1 * (wc0 * sm[r1 * MW + c0] + wc1 * sm[r1 * MW + c1]);
      ss += v * v;
    }
    for (int off = 32; off; off >>= 1) ss += __shfl_down(ss, off);
    if ((tid & 63) == 0) rss[tid >> 6] = ss;
    __syncthreads();
    if (tid == 0) {
      float SS = rss[0] + rss[1] + rss[2] + rss[3];
      meanms[bc] = mean;
      msn[bc] = sqrtf(fmaxf(SS - (float)PHW * mean * mean, 0.f));
    }
    unsigned short* outp = msP + (size_t)bc * 3 * MHW;   // [c][plane][k]
    for (int i2 = tid; i2 < MHW / 2; i2 += 256) {
      const int i = 2 * i2;
      unsigned short a1, a2, a3, b1, b2, b3;
      split3(sm[i], a1, a2, a3);
      split3(sm[i + 1], b1, b2, b3);
      ushort2 t;
      t.x = a1; t.y = b1; *(ushort2*)&outp[i] = t;
      t.x = a2; t.y = b2; *(ushort2*)&outp[MHW + i] = t;
      t.x = a3; t.y = b3; *(ushort2*)&outp[2 * MHW + i] = t;
    }
  }
}

// ---------------- Kernel C: split-bf16 MFMA GEMM, double-buffered (1 barrier/step)
// Same MFMA sequence per accumulator as rounds 8-9 -> bitwise-identical dot.
__global__ __launch_bounds__(256) void k_gemm(const unsigned short* __restrict__ msP,
                                              const unsigned short* __restrict__ padjP,
                                              float* __restrict__ dotp) {
  __shared__ unsigned short As[2][2][3][64][40];   // [buf][mat][plane][row][k] = 122880 B
  const int n = blockIdx.x;                     // 0..255
  const int xcd = n & 7, slot = n >> 3;
  const int b = xcd * 2 + (slot >> 4);          // 2 batches per XCD
  const int xy = slot & 15;
  const int i0 = (xy >> 2) * 64, j0 = (xy & 3) * 64;
  const int tid = threadIdx.x, lane = tid & 63, wid = tid >> 6;
  const int wr = wid >> 1, wc = wid & 1;        // wave quadrant
  const int fr = lane & 15, fq = lane >> 4;

  const unsigned short* mats[2] = {
    msP + (size_t)(b * CC + i0) * 3 * MHW,
    padjP + (size_t)(b * CC + j0) * 3 * MHW
  };
  const unsigned short* gsrc[6];
  int lmat[6], lpl[6], lrow[6], lch[6];
#pragma unroll
  for (int q = 0; q < 6; ++q) {
    int t = tid + q * 256;                      // 1536 tasks: 128 rows x 3 planes x 4 chunks
    int ch = t & 3, pl = (t >> 2) % 3, r128 = t / 12;
    int mat = r128 >> 6, row = r128 & 63;
    gsrc[q] = mats[mat] + ((size_t)row * 3 + pl) * MHW + ch * 8;
    lmat[q] = mat; lpl[q] = pl; lrow[q] = row; lch[q] = ch;
  }
  bf16x8 stg[6];
  f32x4 acc[2][2] = {};

  auto g_load = [&](int kt) {
#pragma unroll
    for (int q = 0; q < 6; ++q) stg[q] = *(const bf16x8*)(gsrc[q] + kt);
  };
  auto l_store = [&](int buf) {
#pragma unroll
    for (int q = 0; q < 6; ++q)
      *(bf16x8*)&As[buf][lmat[q]][lpl[q]][lrow[q]][lch[q] * 8] = stg[q];
  };

  g_load(0);
  l_store(0);
  if (GSTEPS > 1) g_load(32);
  __syncthreads();
  int cur = 0;
  for (int step = 0; step < GSTEPS; ++step) {
    if (step + 1 < GSTEPS) l_store(cur ^ 1);     // store prefetched step+1 into idle buffer
    if (step + 2 < GSTEPS) g_load((step + 2) * 32);
    bf16x8 af[2][3], bfr[2][3];
#pragma unroll
    for (int ti = 0; ti < 2; ++ti)
#pragma unroll
      for (int p = 0; p < 3; ++p) {
        af[ti][p] = *(const bf16x8*)&As[cur][0][p][wr * 32 + ti * 16 + fr][fq * 8];
        bfr[ti][p] = *(const bf16x8*)&As[cur][1][p][wc * 32 + ti * 16 + fr][fq * 8];
      }
#pragma unroll
    for (int ti = 0; ti < 2; ++ti)
#pragma unroll
      for (int tj = 0; tj < 2; ++tj) {
        f32x4 c = acc[ti][tj];
        c = __builtin_amdgcn_mfma_f32_16x16x32_bf16(af[ti][0], bfr[tj][0], c, 0, 0, 0);
        c = __builtin_amdgcn_mfma_f32_16x16x32_bf16(af[ti][0], bfr[tj][1], c, 0, 0, 0);
        c = __builtin_amdgcn_mfma_f32_16x16x32_bf16(af[ti][1], bfr[tj][0], c, 0, 0, 0);
        c = __builtin_amdgcn_mfma_f32_16x16x32_bf16(af[ti][0], bfr[tj][2], c, 0, 0, 0);
        c = __builtin_amdgcn_mfma_f32_16x16x32_bf16(af[ti][1], bfr[tj][1], c, 0, 0, 0);
        c = __builtin_amdgcn_mfma_f32_16x16x32_bf16(af[ti][2], bfr[tj][0], c, 0, 0, 0);
        acc[ti][tj] = c;
      }
    __syncthreads();   // waves done reading As[cur]; stores to As[cur^1] visible
    cur ^= 1;
  }
  // Epilogue: C/D layout col = lane&15, row = (lane>>4)*4 + reg  [m89-verified]
  float* drow = dotp + ((size_t)b * CC + i0) * CC + j0;
#pragma unroll
  for (int ti = 0; ti < 2; ++ti)
#pragma unroll
    for (int tj = 0; tj < 2; ++tj)
#pragma unroll
      for (int j = 0; j < 4; ++j) {
        int row = wr * 32 + ti * 16 + fq * 4 + j;
        int col = wc * 32 + tj * 16 + fr;
        drow[(size_t)row * CC + col] = acc[ti][tj][j];
      }
}

// ---------------- Kernel C2: per-row max/argmax of similarity ----------------
__global__ __launch_bounds__(256) void k_rowmax(const float* __restrict__ dotp,
                                                const float* __restrict__ meanp,
                                                const float* __restrict__ pn,
                                                const float* __restrict__ meanms,
                                                const float* __restrict__ msn,
                                                float* __restrict__ maxv,
                                                int* __restrict__ amax) {
  const int tid = threadIdx.x;
  const int r = blockIdx.x * 4 + (tid >> 6);
  const int lane = tid & 63;
  const int b = r >> 8;
  const float* d0 = dotp + (size_t)r * CC;
  const float mm = meanms[r];
  const float inv = 100.f / msn[r];
  const int j = lane * 4;
  float4 v0 = *(const float4*)(d0 + j);
  float4 mp4 = *(const float4*)(meanp + b * CC + j);
  float4 pn4 = *(const float4*)(pn + b * CC + j);
  float sv[4];
  sv[0] = (v0.x - (float)PHW * mm * mp4.x) * inv / pn4.x;
  sv[1] = (v0.y - (float)PHW * mm * mp4.y) * inv / pn4.y;
  sv[2] = (v0.z - (float)PHW * mm * mp4.z) * inv / pn4.z;
  sv[3] = (v0.w - (float)PHW * mm * mp4.w) * inv / pn4.w;
  float best = sv[0]; int bj = j;
#pragma unroll
  for (int t = 1; t < 4; ++t)
    if (sv[t] > best) { best = sv[t]; bj = j + t; }
  for (int off = 32; off; off >>= 1) {
    float ov = __shfl_down(best, off);
    int oi = __shfl_down(bj, off);
    if (ov > best || (ov == best && oi < bj)) { best = ov; bj = oi; }
  }
  if (lane == 0) { maxv[r] = best; amax[r] = bj; }
}

// ---------------- Kernel D: group select + deterministic bitonic sort ----------------
__global__ __launch_bounds__(256) void k_group(const float* __restrict__ maxv,
                                               const int* __restrict__ amax,
                                               float* __restrict__ sscore,
                                               int* __restrict__ svals,
                                               int* __restrict__ cnt) {
  const int b = blockIdx.x, tid = threadIdx.x;
  __shared__ float mv[CC];
  __shared__ int sidx[CC];
  __shared__ float gsc[CC];
  __shared__ int pres[CC];
  __shared__ unsigned long long keys[CC];
  __shared__ float r1[4], r2[4];
  __shared__ int r3[4];
  float v = maxv[b * CC + tid];
  sidx[tid] = amax[b * CC + tid];
  float m = v;
  for (int off = 32; off; off >>= 1) m = fmaxf(m, __shfl_down(m, off));
  if ((tid & 63) == 0) r1[tid >> 6] = m;
  __syncthreads();
  float mt = fmaxf(fmaxf(r1[0], r1[1]), fmaxf(r1[2], r1[3]));
  float e = __expf(v - mt);
  float s = e;
  for (int off = 32; off; off >>= 1) s += __shfl_down(s, off);
  if ((tid & 63) == 0) r2[tid >> 6] = s;
  __syncthreads();
  float st = r2[0] + r2[1] + r2[2] + r2[3];
  mv[tid] = e / st;
  __syncthreads();
  float g = 0.f; int p = 0;
  for (int i2 = 0; i2 < CC; ++i2)
    if (sidx[i2] == tid) { g += mv[i2]; p = 1; }
  gsc[tid] = g; pres[tid] = p;
  int pc = p;
  for (int off = 32; off; off >>= 1) pc += __shfl_down(pc, off);
  if ((tid & 63) == 0) r3[tid >> 6] = pc;
  __syncthreads();
  if (tid == 0) cnt[b] = r3[0] + r3[1] + r3[2] + r3[3];
  int c = 255 - tid;
  float val = pres[c] ? gsc[c] : -INFINITY;
  keys[tid] = ((unsigned long long)f2ord(val) << 32) | (unsigned)c;
  __syncthreads();
  for (int ksz = 2; ksz <= 256; ksz <<= 1) {
    for (int jj = ksz >> 1; jj > 0; jj >>= 1) {
      int ixj = tid ^ jj;
      if (ixj > tid) {
        unsigned long long a = keys[tid], o = keys[ixj];
        bool descBlock = ((tid & ksz) == 0);
        bool sw = descBlock ? (a < o) : (a > o);
        if (sw) { keys[tid] = o; keys[ixj] = a; }
      }
      __syncthreads();
    }
  }
  unsigned long long kk = keys[tid];
  int cc2 = (int)(kk & 0xFFFFFFFFull);
  float vv = pres[cc2] ? gsc[cc2] : -INFINITY;
  sscore[b * CC + tid] = vv;
  svals[b * CC + tid] = cc2;
}

// ---------------- Kernel E: min_k + softmax weights ----------------
__global__ __launch_bounds__(128) void k_wsel(const float* __restrict__ sscore,
                                              const int* __restrict__ cnt,
                                              float* __restrict__ wgt,
                                              int* __restrict__ minkp) {
  const int b = blockIdx.x, tid = threadIdx.x;
  int mn = 0x7fffffff;
#pragma unroll
  for (int t = 0; t < CB; ++t) mn = min(mn, cnt[t]);
  const int mink = (mn + 1) >> 1;
  if (b == 0 && tid == 0) *minkp = mink;
  __shared__ float sh1[2], sh2[2];
  float v = (tid < mink) ? sscore[b * CC + tid] : -INFINITY;
  float m = v;
  for (int off = 32; off; off >>= 1) m = fmaxf(m, __shfl_down(m, off));
  if ((tid & 63) == 0) sh1[tid >> 6] = m;
  __syncthreads();
  float mt = fmaxf(sh1[0], sh1[1]);
  float e = (tid < mink) ? __expf(v - mt) : 0.f;
  float s = e;
  for (int off = 32; off; off >>= 1) s += __shfl_down(s, off);
  if ((tid & 63) == 0) sh2[tid >> 6] = s;
  __syncthreads();
  float st = sh2[0] + sh2[1];
  if (tid < mink) wgt[b * 128 + tid] = e / st;
}

// ---------------- Kernel F: fused mask + output, fine grid (2304 blocks) ----------------
__global__ __launch_bounds__(256) void k_maskout(const float* __restrict__ fp,
                                                 const float* __restrict__ wgt,
                                                 const int* __restrict__ svals,
                                                 const int* __restrict__ minkp,
                                                 float* __restrict__ out) {
  const int b = blockIdx.y;
  const int pos = threadIdx.x & 15;
  const int kq = threadIdx.x >> 4;           // 0..15
  const int hw4 = blockIdx.x * 16 + pos;     // float4 index < 2304
  const int mink = *minkp;
  const int qlo = (mink * kq) >> 4, qhi = (mink * (kq + 1)) >> 4;
  const float* base = fp + (size_t)b * CC * PHW;
  float4 acc = make_float4(0.f, 0.f, 0.f, 0.f);
  for (int k = qlo; k < qhi; ++k) {
    int c = svals[b * CC + k];
    float wk = wgt[b * 128 + k];
    float4 v = ((const float4*)(base + (size_t)c * PHW))[hw4];
    acc.x += wk * sigmoidf_(v.x);
    acc.y += wk * sigmoidf_(v.y);
    acc.z += wk * sigmoidf_(v.z);
    acc.w += wk * sigmoidf_(v.w);
  }
  __shared__ __align__(16) float4 sh[16][16];
  __shared__ __align__(16) float4 msh[16];
  sh[kq][pos] = acc;
  __syncthreads();
  if (kq == 0) {
    float4 r = sh[0][pos];
#pragma unroll
    for (int t = 1; t < 16; ++t) {
      float4 a = sh[t][pos];
      r.x += a.x; r.y += a.y; r.z += a.z; r.w += a.w;
    }
    msh[pos] = r;
  }
  __syncthreads();
  const float4 mk = msh[pos];
  float* outb = out + (size_t)b * CC * PHW;
#pragma unroll 4
  for (int it = 0; it < 16; ++it) {
    const int c = it * 16 + kq;
    float4 v = ((const float4*)(base + (size_t)c * PHW))[hw4];
    float4 o;
    o.x = v.x * (1.f + mk.x);
    o.y = v.y * (1.f + mk.y);
    o.z = v.z * (1.f + mk.z);
    o.w = v.w * (1.f + mk.w);
    ((float4*)(outb + (size_t)c * PHW))[hw4] = o;
  }
}

extern "C" void kernel_launch(void* const* d_in, const int* in_sizes, int n_in,
                              void* d_out, int out_size, void* d_ws, size_t ws_size,
                              hipStream_t stream) {
  (void)in_sizes; (void)n_in; (void)out_size;
  const float* fp = (const float*)d_in[0];
  const float* fms = (const float*)d_in[1];
  float* out = (float*)d_out;

  // Big scratch in d_out (dead before k_maskout overwrites it):
  //   padjP: 16*256*3*2304 ushorts = 14,155,776 float-slots
  //   msP  : same, at float-offset 14,155,776
  //   dot  : 16*256*256 floats at float-offset 28,311,552  (ends 29.36M < 37.75M)
  unsigned short* padjP = (unsigned short*)out;
  unsigned short* msP = (unsigned short*)(out + (size_t)14155776);
  float* dotp = out + (size_t)28311552;

  if (ws_size < (size_t)183000 * 4) return;
  float* wsf = (float*)d_ws;
  float* meanp = wsf;               // 4096
  float* pnv = wsf + 4096;          // 4096
  float* meanms = wsf + 8192;       // 4096
  float* msn = wsf + 12288;         // 4096
  float* maxv = wsf + 16384;        // 4096
  float* ssc = wsf + 20480;         // 4096
  float* wgt = wsf + 24576;         // 2048
  int* amax = (int*)(wsf + 174080); // 4096
  int* sv = (int*)(wsf + 178176);   // 4096
  int* cntp = (int*)(wsf + 182272); // 16
  int* minkp = (int*)(wsf + 182288);// 1

  k_stats<<<8192, 256, 0, stream>>>(fp, fms, padjP, msP, meanp, pnv, meanms, msn);
  k_gemm<<<256, 256, 0, stream>>>(msP, padjP, dotp);
  k_rowmax<<<(CB * CC) / 4, 256, 0, stream>>>(dotp, meanp, pnv, meanms, msn, maxv, amax);
  k_group<<<CB, 256, 0, stream>>>(maxv, amax, ssc, sv, cntp);
  k_wsel<<<CB, 128, 0, stream>>>(ssc, cntp, wgt, minkp);
  k_maskout<<<dim3(PHW / 4 / 16, CB), 256, 0, stream>>>(fp, wgt, sv, minkp, out);
}

// Round 11
// 270.957 us; speedup vs baseline: 1.4169x; 1.0545x over previous
//
#include <hip/hip_runtime.h>
#include <hip/hip_bf16.h>
#include <math.h>
#include <float.h>

// Problem constants
constexpr int CB = 16;        // batch
constexpr int CC = 256;       // channels
constexpr int PH = 96, PW = 96, PHW = 9216;
constexpr int MH = 48, MW = 48, MHW = 2304;
constexpr int GSTEPS = MHW / 32;   // 72 mfma k-steps

typedef __bf16 bf16x8 __attribute__((ext_vector_type(8)));
typedef float f32x4 __attribute__((ext_vector_type(4)));

__device__ __forceinline__ float sigmoidf_(float x) { return 1.f / (1.f + __expf(-x)); }

__device__ __forceinline__ unsigned f2ord(float f) {
  unsigned u = __float_as_uint(f);
  return (u & 0x80000000u) ? ~u : (u | 0x80000000u);
}

// Truncation-based 3-term bf16 split: v = b1 + b2 + b3 + err, |err| <= 2^-24 |v|.
// b1,b2 subtractions are exact (mantissa prefixes); only b3 truncates.
__device__ __forceinline__ void split3(float v, unsigned short& h1, unsigned short& h2,
                                       unsigned short& h3) {
  unsigned u1 = __float_as_uint(v) & 0xFFFF0000u;
  float r1 = v - __uint_as_float(u1);
  unsigned u2 = __float_as_uint(r1) & 0xFFFF0000u;
  float r2 = r1 - __uint_as_float(u2);
  h1 = (unsigned short)(u1 >> 16);
  h2 = (unsigned short)(u2 >> 16);
  h3 = (unsigned short)(__float_as_uint(r2) >> 16);
}

__device__ __forceinline__ void taps96(int h, int& i0, int& i1, float& w0, float& w1) {
  if (h == 0) { i0 = 0; i1 = 0; w0 = 1.f; w1 = 0.f; }
  else if (h == 95) { i0 = 47; i1 = 47; w0 = 1.f; w1 = 0.f; }
  else if (h & 1) { int k = h >> 1; i0 = k; i1 = k + 1; w0 = 0.75f; w1 = 0.25f; }
  else { int k = h >> 1; i0 = k - 1; i1 = k; w0 = 0.25f; w1 = 0.75f; }
}

// ---------------- Kernel A+B merged: stats + bf16 planes for both inputs
// blocks [0,4096): f_p path; blocks [4096,8192): f_ms path.
__global__ __launch_bounds__(256) void k_stats(const float* __restrict__ fp,
                                               const float* __restrict__ fms,
                                               unsigned short* __restrict__ padjP,
                                               unsigned short* __restrict__ msP,
                                               float* __restrict__ meanp,
                                               float* __restrict__ pn,
                                               float* __restrict__ meanms,
                                               float* __restrict__ msn) {
  __shared__ __align__(16) float smem[MH * PW];   // 18.4 KB (aliased by both paths)
  __shared__ float rs[4], rss[4];
  __shared__ int2 tIdx[96];
  __shared__ float2 tWt[96];
  const int tid = threadIdx.x;
  if (blockIdx.x < 4096) {
    // ---- f_p path ----
    const int bc = blockIdx.x;
    float (*tmp)[PW] = (float(*)[PW])smem;
    const float* img = fp + (size_t)bc * PHW;
    float s = 0.f, ss = 0.f;
    for (int q = tid; q < PHW / 4; q += 256) {
      float4 v = ((const float4*)img)[q];
      s += v.x + v.y + v.z + v.w;
      ss += v.x * v.x + v.y * v.y + v.z * v.z + v.w * v.w;
    }
    for (int off = 32; off; off >>= 1) { s += __shfl_down(s, off); ss += __shfl_down(ss, off); }
    if ((tid & 63) == 0) { rs[tid >> 6] = s; rss[tid >> 6] = ss; }
    // Row adjoint, float4-wide: tmp[u][w] = sum_h Wrow[h,u] * p[h,w]
    for (int idx4 = tid; idx4 < MH * (PW / 4); idx4 += 256) {   // 1152
      const int u = idx4 / (PW / 4), w4 = (idx4 - u * (PW / 4)) * 4;
      float4 v;
      if (u == 0) {
        float4 a = *(const float4*)&img[w4];
        float4 b = *(const float4*)&img[PW + w4];
        float4 c = *(const float4*)&img[2 * PW + w4];
        v.x = a.x + 0.75f * b.x + 0.25f * c.x;
        v.y = a.y + 0.75f * b.y + 0.25f * c.y;
        v.z = a.z + 0.75f * b.z + 0.25f * c.z;
        v.w = a.w + 0.75f * b.w + 0.25f * c.w;
      } else if (u == MH - 1) {
        float4 a = *(const float4*)&img[(PH - 3) * PW + w4];
        float4 b = *(const float4*)&img[(PH - 2) * PW + w4];
        float4 c = *(const float4*)&img[(PH - 1) * PW + w4];
        v.x = 0.25f * a.x + 0.75f * b.x + c.x;
        v.y = 0.25f * a.y + 0.75f * b.y + c.y;
        v.z = 0.25f * a.z + 0.75f * b.z + c.z;
        v.w = 0.25f * a.w + 0.75f * b.w + c.w;
      } else {
        float4 a = *(const float4*)&img[(2 * u - 1) * PW + w4];
        float4 b = *(const float4*)&img[2 * u * PW + w4];
        float4 c = *(const float4*)&img[(2 * u + 1) * PW + w4];
        float4 d = *(const float4*)&img[(2 * u + 2) * PW + w4];
        v.x = 0.25f * (a.x + d.x) + 0.75f * (b.x + c.x);
        v.y = 0.25f * (a.y + d.y) + 0.75f * (b.y + c.y);
        v.z = 0.25f * (a.z + d.z) + 0.75f * (b.z + c.z);
        v.w = 0.25f * (a.w + d.w) + 0.75f * (b.w + c.w);
      }
      *(float4*)&tmp[u][w4] = v;
    }
    __syncthreads();
    if (tid == 0) {
      float S = rs[0] + rs[1] + rs[2] + rs[3];
      float SS = rss[0] + rss[1] + rss[2] + rss[3];
      meanp[bc] = S / (float)PHW;
      pn[bc] = sqrtf(fmaxf(SS - S * S / (float)PHW, 0.f));
    }
    unsigned short* outp = padjP + (size_t)bc * 3 * MHW;   // [c][plane][k]
    for (int idx = tid; idx < MH * (MW / 2); idx += 256) {
      const int u = idx / (MW / 2), j = idx - u * (MW / 2);
      const float* r = tmp[u];
      const int v0 = 2 * j, v1 = 2 * j + 1;
      float val0, val1;
      if (v0 == 0)
        val0 = r[0] + 0.75f * r[1] + 0.25f * r[2];
      else
        val0 = 0.25f * (r[2 * v0 - 1] + r[2 * v0 + 2]) + 0.75f * (r[2 * v0] + r[2 * v0 + 1]);
      if (v1 == MW - 1)
        val1 = 0.25f * r[PW - 3] + 0.75f * r[PW - 2] + r[PW - 1];
      else
        val1 = 0.25f * (r[2 * v1 - 1] + r[2 * v1 + 2]) + 0.75f * (r[2 * v1] + r[2 * v1 + 1]);
      unsigned short a1, a2, a3, b1, b2, b3;
      split3(val0, a1, a2, a3);
      split3(val1, b1, b2, b3);
      const int k = u * MW + v0;
      ushort2 t;
      t.x = a1; t.y = b1; *(ushort2*)&outp[k] = t;
      t.x = a2; t.y = b2; *(ushort2*)&outp[MHW + k] = t;
      t.x = a3; t.y = b3; *(ushort2*)&outp[2 * MHW + k] = t;
    }
  } else {
    // ---- f_ms path ----
    const int bc = blockIdx.x - 4096;
    float* sm = smem;
    const float* img = fms + (size_t)bc * MHW;
    if (tid < 96) {
      int i0, i1; float w0, w1;
      taps96(tid, i0, i1, w0, w1);
      tIdx[tid] = make_int2(i0, i1);
      tWt[tid] = make_float2(w0, w1);
    }
    float s = 0.f;
    for (int q = tid; q < MHW / 4; q += 256) {
      float4 v = ((const float4*)img)[q];
      ((float4*)sm)[q] = v;
      s += v.x + v.y + v.z + v.w;
    }
    for (int off = 32; off; off >>= 1) s += __shfl_down(s, off);
    if ((tid & 63) == 0) rs[tid >> 6] = s;
    __syncthreads();
    const float mean = (rs[0] + rs[1] + rs[2] + rs[3]) / (float)MHW;
    float ss = 0.f;
    for (int i = tid; i < PHW; i += 256) {
      const int h = i / PW, w = i - h * PW;
      const int2 rI = tIdx[h]; const float2 rW = tWt[h];
      const int2 cI = tIdx[w]; const float2 cW = tWt[w];
      float v = rW.x * (cW.x * sm[rI.x * MW + cI.x] + cW.y * sm[rI.x * MW + cI.y]) +
                rW.y * (cW.x * sm[rI.y * MW + cI.x] + cW.y * sm[rI.y * MW + cI.y]);
      ss += v * v;
    }
    for (int off = 32; off; off >>= 1) ss += __shfl_down(ss, off);
    if ((tid & 63) == 0) rss[tid >> 6] = ss;
    __syncthreads();
    if (tid == 0) {
      float SS = rss[0] + rss[1] + rss[2] + rss[3];
      meanms[bc] = mean;
      msn[bc] = sqrtf(fmaxf(SS - (float)PHW * mean * mean, 0.f));
    }
    unsigned short* outp = msP + (size_t)bc * 3 * MHW;   // [c][plane][k]
    for (int i4 = tid; i4 < MHW / 4; i4 += 256) {
      const int i = 4 * i4;
      float4 v = *(const float4*)&sm[i];
      unsigned short p1[4], p2[4], p3[4];
      split3(v.x, p1[0], p2[0], p3[0]);
      split3(v.y, p1[1], p2[1], p3[1]);
      split3(v.z, p1[2], p2[2], p3[2]);
      split3(v.w, p1[3], p2[3], p3[3]);
      *(ushort4*)&outp[i] = make_ushort4(p1[0], p1[1], p1[2], p1[3]);
      *(ushort4*)&outp[MHW + i] = make_ushort4(p2[0], p2[1], p2[2], p2[3]);
      *(ushort4*)&outp[2 * MHW + i] = make_ushort4(p3[0], p3[1], p3[2], p3[3]);
    }
  }
}

// ---------------- Kernel C: split-bf16 MFMA GEMM, double-buffered (1 barrier/step) ----------------
__global__ __launch_bounds__(256) void k_gemm(const unsigned short* __restrict__ msP,
                                              const unsigned short* __restrict__ padjP,
                                              float* __restrict__ dotp) {
  __shared__ unsigned short As[2][2][3][64][40];   // [buf][mat][plane][row][k] = 122880 B
  const int n = blockIdx.x;                     // 0..255
  const int xcd = n & 7, slot = n >> 3;
  const int b = xcd * 2 + (slot >> 4);          // 2 batches per XCD
  const int xy = slot & 15;
  const int i0 = (xy >> 2) * 64, j0 = (xy & 3) * 64;
  const int tid = threadIdx.x, lane = tid & 63, wid = tid >> 6;
  const int wr = wid >> 1, wc = wid & 1;        // wave quadrant
  const int fr = lane & 15, fq = lane >> 4;

  const unsigned short* mats[2] = {
    msP + (size_t)(b * CC + i0) * 3 * MHW,
    padjP + (size_t)(b * CC + j0) * 3 * MHW
  };
  const unsigned short* gsrc[6];
  int lmat[6], lpl[6], lrow[6], lch[6];
#pragma unroll
  for (int q = 0; q < 6; ++q) {
    int t = tid + q * 256;                      // 1536 tasks: 128 rows x 3 planes x 4 chunks
    int ch = t & 3, pl = (t >> 2) % 3, r128 = t / 12;
    int mat = r128 >> 6, row = r128 & 63;
    gsrc[q] = mats[mat] + ((size_t)row * 3 + pl) * MHW + ch * 8;
    lmat[q] = mat; lpl[q] = pl; lrow[q] = row; lch[q] = ch;
  }
  bf16x8 stg[6];
  f32x4 acc[2][2] = {};

  auto g_load = [&](int kt) {
#pragma unroll
    for (int q = 0; q < 6; ++q) stg[q] = *(const bf16x8*)(gsrc[q] + kt);
  };
  auto l_store = [&](int buf) {
#pragma unroll
    for (int q = 0; q < 6; ++q)
      *(bf16x8*)&As[buf][lmat[q]][lpl[q]][lrow[q]][lch[q] * 8] = stg[q];
  };

  g_load(0);
  l_store(0);
  if (GSTEPS > 1) g_load(32);
  __syncthreads();
  int cur = 0;
  for (int step = 0; step < GSTEPS; ++step) {
    if (step + 1 < GSTEPS) l_store(cur ^ 1);     // store prefetched step+1 into idle buffer
    if (step + 2 < GSTEPS) g_load((step + 2) * 32);
    bf16x8 af[2][3], bfr[2][3];
#pragma unroll
    for (int ti = 0; ti < 2; ++ti)
#pragma unroll
      for (int p = 0; p < 3; ++p) {
        af[ti][p] = *(const bf16x8*)&As[cur][0][p][wr * 32 + ti * 16 + fr][fq * 8];
        bfr[ti][p] = *(const bf16x8*)&As[cur][1][p][wc * 32 + ti * 16 + fr][fq * 8];
      }
#pragma unroll
    for (int ti = 0; ti < 2; ++ti)
#pragma unroll
      for (int tj = 0; tj < 2; ++tj) {
        f32x4 c = acc[ti][tj];
        c = __builtin_amdgcn_mfma_f32_16x16x32_bf16(af[ti][0], bfr[tj][0], c, 0, 0, 0);
        c = __builtin_amdgcn_mfma_f32_16x16x32_bf16(af[ti][0], bfr[tj][1], c, 0, 0, 0);
        c = __builtin_amdgcn_mfma_f32_16x16x32_bf16(af[ti][1], bfr[tj][0], c, 0, 0, 0);
        c = __builtin_amdgcn_mfma_f32_16x16x32_bf16(af[ti][0], bfr[tj][2], c, 0, 0, 0);
        c = __builtin_amdgcn_mfma_f32_16x16x32_bf16(af[ti][1], bfr[tj][1], c, 0, 0, 0);
        c = __builtin_amdgcn_mfma_f32_16x16x32_bf16(af[ti][2], bfr[tj][0], c, 0, 0, 0);
        acc[ti][tj] = c;
      }
    __syncthreads();   // waves done reading As[cur]; stores to As[cur^1] visible
    cur ^= 1;
  }
  // Epilogue: C/D layout col = lane&15, row = (lane>>4)*4 + reg  [m89-verified]
  float* drow = dotp + ((size_t)b * CC + i0) * CC + j0;
#pragma unroll
  for (int ti = 0; ti < 2; ++ti)
#pragma unroll
    for (int tj = 0; tj < 2; ++tj)
#pragma unroll
      for (int j = 0; j < 4; ++j) {
        int row = wr * 32 + ti * 16 + fq * 4 + j;
        int col = wc * 32 + tj * 16 + fr;
        drow[(size_t)row * CC + col] = acc[ti][tj][j];
      }
}

// ---------------- Kernel C2: per-row max/argmax of similarity ----------------
__global__ __launch_bounds__(256) void k_rowmax(const float* __restrict__ dotp,
                                                const float* __restrict__ meanp,
                                                const float* __restrict__ pn,
                                                const float* __restrict__ meanms,
                                                const float* __restrict__ msn,
                                                float* __restrict__ maxv,
                                                int* __restrict__ amax) {
  const int tid = threadIdx.x;
  const int r = blockIdx.x * 4 + (tid >> 6);
  const int lane = tid & 63;
  const int b = r >> 8;
  const float* d0 = dotp + (size_t)r * CC;
  const float mm = meanms[r];
  const float inv = 100.f / msn[r];
  const int j = lane * 4;
  float4 v0 = *(const float4*)(d0 + j);
  float4 mp4 = *(const float4*)(meanp + b * CC + j);
  float4 pn4 = *(const float4*)(pn + b * CC + j);
  float sv[4];
  sv[0] = (v0.x - (float)PHW * mm * mp4.x) * inv / pn4.x;
  sv[1] = (v0.y - (float)PHW * mm * mp4.y) * inv / pn4.y;
  sv[2] = (v0.z - (float)PHW * mm * mp4.z) * inv / pn4.z;
  sv[3] = (v0.w - (float)PHW * mm * mp4.w) * inv / pn4.w;
  float best = sv[0]; int bj = j;
#pragma unroll
  for (int t = 1; t < 4; ++t)
    if (sv[t] > best) { best = sv[t]; bj = j + t; }
  for (int off = 32; off; off >>= 1) {
    float ov = __shfl_down(best, off);
    int oi = __shfl_down(bj, off);
    if (ov > best || (ov == best && oi < bj)) { best = ov; bj = oi; }
  }
  if (lane == 0) { maxv[r] = best; amax[r] = bj; }
}

// ---------------- Kernel D: group select + deterministic bitonic sort ----------------
__global__ __launch_bounds__(256) void k_group(const float* __restrict__ maxv,
                                               const int* __restrict__ amax,
                                               float* __restrict__ sscore,
                                               int* __restrict__ svals,
                                               int* __restrict__ cnt) {
  const int b = blockIdx.x, tid = threadIdx.x;
  __shared__ float mv[CC];
  __shared__ int sidx[CC];
  __shared__ float gsc[CC];
  __shared__ int pres[CC];
  __shared__ unsigned long long keys[CC];
  __shared__ float r1[4], r2[4];
  __shared__ int r3[4];
  float v = maxv[b * CC + tid];
  sidx[tid] = amax[b * CC + tid];
  float m = v;
  for (int off = 32; off; off >>= 1) m = fmaxf(m, __shfl_down(m, off));
  if ((tid & 63) == 0) r1[tid >> 6] = m;
  __syncthreads();
  float mt = fmaxf(fmaxf(r1[0], r1[1]), fmaxf(r1[2], r1[3]));
  float e = __expf(v - mt);
  float s = e;
  for (int off = 32; off; off >>= 1) s += __shfl_down(s, off);
  if ((tid & 63) == 0) r2[tid >> 6] = s;
  __syncthreads();
  float st = r2[0] + r2[1] + r2[2] + r2[3];
  mv[tid] = e / st;
  __syncthreads();
  float g = 0.f; int p = 0;
  for (int i2 = 0; i2 < CC; ++i2)
    if (sidx[i2] == tid) { g += mv[i2]; p = 1; }
  gsc[tid] = g; pres[tid] = p;
  int pc = p;
  for (int off = 32; off; off >>= 1) pc += __shfl_down(pc, off);
  if ((tid & 63) == 0) r3[tid >> 6] = pc;
  __syncthreads();
  if (tid == 0) cnt[b] = r3[0] + r3[1] + r3[2] + r3[3];
  int c = 255 - tid;
  float val = pres[c] ? gsc[c] : -INFINITY;
  keys[tid] = ((unsigned long long)f2ord(val) << 32) | (unsigned)c;
  __syncthreads();
  for (int ksz = 2; ksz <= 256; ksz <<= 1) {
    for (int jj = ksz >> 1; jj > 0; jj >>= 1) {
      int ixj = tid ^ jj;
      if (ixj > tid) {
        unsigned long long a = keys[tid], o = keys[ixj];
        bool descBlock = ((tid & ksz) == 0);
        bool sw = descBlock ? (a < o) : (a > o);
        if (sw) { keys[tid] = o; keys[ixj] = a; }
      }
      __syncthreads();
    }
  }
  unsigned long long kk = keys[tid];
  int cc2 = (int)(kk & 0xFFFFFFFFull);
  float vv = pres[cc2] ? gsc[cc2] : -INFINITY;
  sscore[b * CC + tid] = vv;
  svals[b * CC + tid] = cc2;
}

// ---------------- Kernel E: min_k + softmax weights ----------------
__global__ __launch_bounds__(128) void k_wsel(const float* __restrict__ sscore,
                                              const int* __restrict__ cnt,
                                              float* __restrict__ wgt,
                                              int* __restrict__ minkp) {
  const int b = blockIdx.x, tid = threadIdx.x;
  int mn = 0x7fffffff;
#pragma unroll
  for (int t = 0; t < CB; ++t) mn = min(mn, cnt[t]);
  const int mink = (mn + 1) >> 1;
  if (b == 0 && tid == 0) *minkp = mink;
  __shared__ float sh1[2], sh2[2];
  float v = (tid < mink) ? sscore[b * CC + tid] : -INFINITY;
  float m = v;
  for (int off = 32; off; off >>= 1) m = fmaxf(m, __shfl_down(m, off));
  if ((tid & 63) == 0) sh1[tid >> 6] = m;
  __syncthreads();
  float mt = fmaxf(sh1[0], sh1[1]);
  float e = (tid < mink) ? __expf(v - mt) : 0.f;
  float s = e;
  for (int off = 32; off; off >>= 1) s += __shfl_down(s, off);
  if ((tid & 63) == 0) sh2[tid >> 6] = s;
  __syncthreads();
  float st = sh2[0] + sh2[1];
  if (tid < mink) wgt[b * 128 + tid] = e / st;
}

// ---------------- Kernel F: fused mask + output, fine grid (2304 blocks) ----------------
__global__ __launch_bounds__(256) void k_maskout(const float* __restrict__ fp,
                                                 const float* __restrict__ wgt,
                                                 const int* __restrict__ svals,
                                                 const int* __restrict__ minkp,
                                                 float* __restrict__ out) {
  const int b = blockIdx.y;
  const int pos = threadIdx.x & 15;
  const int kq = threadIdx.x >> 4;           // 0..15
  const int hw4 = blockIdx.x * 16 + pos;     // float4 index < 2304
  const int mink = *minkp;
  const int qlo = (mink * kq) >> 4, qhi = (mink * (kq + 1)) >> 4;
  const float* base = fp + (size_t)b * CC * PHW;
  float4 acc = make_float4(0.f, 0.f, 0.f, 0.f);
  for (int k = qlo; k < qhi; ++k) {
    int c = svals[b * CC + k];
    float wk = wgt[b * 128 + k];
    float4 v = ((const float4*)(base + (size_t)c * PHW))[hw4];
    acc.x += wk * sigmoidf_(v.x);
    acc.y += wk * sigmoidf_(v.y);
    acc.z += wk * sigmoidf_(v.z);
    acc.w += wk * sigmoidf_(v.w);
  }
  __shared__ __align__(16) float4 sh[16][16];
  __shared__ __align__(16) float4 msh[16];
  sh[kq][pos] = acc;
  __syncthreads();
  if (kq == 0) {
    float4 r = sh[0][pos];
#pragma unroll
    for (int t = 1; t < 16; ++t) {
      float4 a = sh[t][pos];
      r.x += a.x; r.y += a.y; r.z += a.z; r.w += a.w;
    }
    msh[pos] = r;
  }
  __syncthreads();
  const float4 mk = msh[pos];
  float* outb = out + (size_t)b * CC * PHW;
#pragma unroll 4
  for (int it = 0; it < 16; ++it) {
    const int c = it * 16 + kq;
    float4 v = ((const float4*)(base + (size_t)c * PHW))[hw4];
    float4 o;
    o.x = v.x * (1.f + mk.x);
    o.y = v.y * (1.f + mk.y);
    o.z = v.z * (1.f + mk.z);
    o.w = v.w * (1.f + mk.w);
    ((float4*)(outb + (size_t)c * PHW))[hw4] = o;
  }
}

extern "C" void kernel_launch(void* const* d_in, const int* in_sizes, int n_in,
                              void* d_out, int out_size, void* d_ws, size_t ws_size,
                              hipStream_t stream) {
  (void)in_sizes; (void)n_in; (void)out_size;
  const float* fp = (const float*)d_in[0];
  const float* fms = (const float*)d_in[1];
  float* out = (float*)d_out;

  // Big scratch in d_out (dead before k_maskout overwrites it):
  //   padjP: 16*256*3*2304 ushorts = 14,155,776 float-slots
  //   msP  : same, at float-offset 14,155,776
  //   dot  : 16*256*256 floats at float-offset 28,311,552  (ends 29.36M < 37.75M)
  unsigned short* padjP = (unsigned short*)out;
  unsigned short* msP = (unsigned short*)(out + (size_t)14155776);
  float* dotp = out + (size_t)28311552;

  if (ws_size < (size_t)183000 * 4) return;
  float* wsf = (float*)d_ws;
  float* meanp = wsf;               // 4096
  float* pnv = wsf + 4096;          // 4096
  float* meanms = wsf + 8192;       // 4096
  float* msn = wsf + 12288;         // 4096
  float* maxv = wsf + 16384;        // 4096
  float* ssc = wsf + 20480;         // 4096
  float* wgt = wsf + 24576;         // 2048
  int* amax = (int*)(wsf + 174080); // 4096
  int* sv = (int*)(wsf + 178176);   // 4096
  int* cntp = (int*)(wsf + 182272); // 16
  int* minkp = (int*)(wsf + 182288);// 1

  k_stats<<<8192, 256, 0, stream>>>(fp, fms, padjP, msP, meanp, pnv, meanms, msn);
  k_gemm<<<256, 256, 0, stream>>>(msP, padjP, dotp);
  k_rowmax<<<(CB * CC) / 4, 256, 0, stream>>>(dotp, meanp, pnv, meanms, msn, maxv, amax);
  k_group<<<CB, 256, 0, stream>>>(maxv, amax, ssc, sv, cntp);
  k_wsel<<<CB, 128, 0, stream>>>(ssc, cntp, wgt, minkp);
  k_maskout<<<dim3(PHW / 4 / 16, CB), 256, 0, stream>>>(fp, wgt, sv, minkp, out);
}

// Round 13
// 239.108 us; speedup vs baseline: 1.6056x; 1.1332x over previous
//
#include <hip/hip_runtime.h>
#include <hip/hip_bf16.h>
#include <math.h>
#include <float.h>

// Problem constants
constexpr int CB = 16;        // batch
constexpr int CC = 256;       // channels
constexpr int PH = 96, PW = 96, PHW = 9216;
constexpr int MH = 48, MW = 48, MHW = 2304;
constexpr int GSTEPS = MHW / 32;   // 72 mfma k-steps

typedef __bf16 bf16x8 __attribute__((ext_vector_type(8)));
typedef float f32x4 __attribute__((ext_vector_type(4)));

__device__ __forceinline__ float sigmoidf_(float x) { return 1.f / (1.f + __expf(-x)); }

__device__ __forceinline__ unsigned f2ord(float f) {
  unsigned u = __float_as_uint(f);
  return (u & 0x80000000u) ? ~u : (u | 0x80000000u);
}

// Truncation-based 3-term bf16 split: v = b1 + b2 + b3 + err, |err| <= 2^-24 |v|.
__device__ __forceinline__ void split3(float v, unsigned short& h1, unsigned short& h2,
                                       unsigned short& h3) {
  unsigned u1 = __float_as_uint(v) & 0xFFFF0000u;
  float r1 = v - __uint_as_float(u1);
  unsigned u2 = __float_as_uint(r1) & 0xFFFF0000u;
  float r2 = r1 - __uint_as_float(u2);
  h1 = (unsigned short)(u1 >> 16);
  h2 = (unsigned short)(u2 >> 16);
  h3 = (unsigned short)(__float_as_uint(r2) >> 16);
}

__device__ __forceinline__ void taps96(int h, int& i0, int& i1, float& w0, float& w1) {
  if (h == 0) { i0 = 0; i1 = 0; w0 = 1.f; w1 = 0.f; }
  else if (h == 95) { i0 = 47; i1 = 47; w0 = 1.f; w1 = 0.f; }
  else if (h & 1) { int k = h >> 1; i0 = k; i1 = k + 1; w0 = 0.75f; w1 = 0.25f; }
  else { int k = h >> 1; i0 = k - 1; i1 = k; w0 = 0.25f; w1 = 0.75f; }
}

// ---------------- Kernel A+B merged: stats + bf16 planes for both inputs
// blocks [0,4096): f_p path; blocks [4096,8192): f_ms path.
__global__ __launch_bounds__(256) void k_stats(const float* __restrict__ fp,
                                               const float* __restrict__ fms,
                                               unsigned short* __restrict__ padjP,
                                               unsigned short* __restrict__ msP,
                                               float* __restrict__ meanp,
                                               float* __restrict__ pn,
                                               float* __restrict__ meanms,
                                               float* __restrict__ msn) {
  __shared__ __align__(16) float smem[MH * PW];   // 18.4 KB (aliased by both paths)
  __shared__ float rs[4], rss[4];
  __shared__ int2 tIdx[96];
  __shared__ float2 tWt[96];
  const int tid = threadIdx.x;
  if (blockIdx.x < 4096) {
    // ---- f_p path ----
    const int bc = blockIdx.x;
    float (*tmp)[PW] = (float(*)[PW])smem;
    const float* img = fp + (size_t)bc * PHW;
    // Stats with 4-deep ILP: 9 float4/thread = 2 batches of 4 + 1 tail.
    float s4[4] = {0.f, 0.f, 0.f, 0.f}, ss4[4] = {0.f, 0.f, 0.f, 0.f};
#pragma unroll
    for (int base = 0; base < 8; base += 4) {
      float4 v0 = ((const float4*)img)[tid + (base + 0) * 256];
      float4 v1 = ((const float4*)img)[tid + (base + 1) * 256];
      float4 v2 = ((const float4*)img)[tid + (base + 2) * 256];
      float4 v3 = ((const float4*)img)[tid + (base + 3) * 256];
      s4[0] += v0.x + v0.y + v0.z + v0.w;
      ss4[0] += v0.x * v0.x + v0.y * v0.y + v0.z * v0.z + v0.w * v0.w;
      s4[1] += v1.x + v1.y + v1.z + v1.w;
      ss4[1] += v1.x * v1.x + v1.y * v1.y + v1.z * v1.z + v1.w * v1.w;
      s4[2] += v2.x + v2.y + v2.z + v2.w;
      ss4[2] += v2.x * v2.x + v2.y * v2.y + v2.z * v2.z + v2.w * v2.w;
      s4[3] += v3.x + v3.y + v3.z + v3.w;
      ss4[3] += v3.x * v3.x + v3.y * v3.y + v3.z * v3.z + v3.w * v3.w;
    }
    {
      float4 vt = ((const float4*)img)[tid + 8 * 256];
      s4[0] += vt.x + vt.y + vt.z + vt.w;
      ss4[0] += vt.x * vt.x + vt.y * vt.y + vt.z * vt.z + vt.w * vt.w;
    }
    float s = (s4[0] + s4[1]) + (s4[2] + s4[3]);
    float ss = (ss4[0] + ss4[1]) + (ss4[2] + ss4[3]);
    for (int off = 32; off; off >>= 1) { s += __shfl_down(s, off); ss += __shfl_down(ss, off); }
    if ((tid & 63) == 0) { rs[tid >> 6] = s; rss[tid >> 6] = ss; }
    // Row adjoint, float4-wide: tmp[u][w] = sum_h Wrow[h,u] * p[h,w]
    for (int idx4 = tid; idx4 < MH * (PW / 4); idx4 += 256) {   // 1152
      const int u = idx4 / (PW / 4), w4 = (idx4 - u * (PW / 4)) * 4;
      float4 v;
      if (u == 0) {
        float4 a = *(const float4*)&img[w4];
        float4 b = *(const float4*)&img[PW + w4];
        float4 c = *(const float4*)&img[2 * PW + w4];
        v.x = a.x + 0.75f * b.x + 0.25f * c.x;
        v.y = a.y + 0.75f * b.y + 0.25f * c.y;
        v.z = a.z + 0.75f * b.z + 0.25f * c.z;
        v.w = a.w + 0.75f * b.w + 0.25f * c.w;
      } else if (u == MH - 1) {
        float4 a = *(const float4*)&img[(PH - 3) * PW + w4];
        float4 b = *(const float4*)&img[(PH - 2) * PW + w4];
        float4 c = *(const float4*)&img[(PH - 1) * PW + w4];
        v.x = 0.25f * a.x + 0.75f * b.x + c.x;
        v.y = 0.25f * a.y + 0.75f * b.y + c.y;
        v.z = 0.25f * a.z + 0.75f * b.z + c.z;
        v.w = 0.25f * a.w + 0.75f * b.w + c.w;
      } else {
        float4 a = *(const float4*)&img[(2 * u - 1) * PW + w4];
        float4 b = *(const float4*)&img[2 * u * PW + w4];
        float4 c = *(const float4*)&img[(2 * u + 1) * PW + w4];
        float4 d = *(const float4*)&img[(2 * u + 2) * PW + w4];
        v.x = 0.25f * (a.x + d.x) + 0.75f * (b.x + c.x);
        v.y = 0.25f * (a.y + d.y) + 0.75f * (b.y + c.y);
        v.z = 0.25f * (a.z + d.z) + 0.75f * (b.z + c.z);
        v.w = 0.25f * (a.w + d.w) + 0.75f * (b.w + c.w);
      }
      *(float4*)&tmp[u][w4] = v;
    }
    __syncthreads();
    if (tid == 0) {
      float S = rs[0] + rs[1] + rs[2] + rs[3];
      float SS = rss[0] + rss[1] + rss[2] + rss[3];
      meanp[bc] = S / (float)PHW;
      pn[bc] = sqrtf(fmaxf(SS - S * S / (float)PHW, 0.f));
    }
    unsigned short* outp = padjP + (size_t)bc * 3 * MHW;   // [c][plane][k]
    for (int idx = tid; idx < MH * (MW / 2); idx += 256) {
      const int u = idx / (MW / 2), j = idx - u * (MW / 2);
      const float* r = tmp[u];
      const int v0 = 2 * j, v1 = 2 * j + 1;
      float val0, val1;
      if (v0 == 0)
        val0 = r[0] + 0.75f * r[1] + 0.25f * r[2];
      else
        val0 = 0.25f * (r[2 * v0 - 1] + r[2 * v0 + 2]) + 0.75f * (r[2 * v0] + r[2 * v0 + 1]);
      if (v1 == MW - 1)
        val1 = 0.25f * r[PW - 3] + 0.75f * r[PW - 2] + r[PW - 1];
      else
        val1 = 0.25f * (r[2 * v1 - 1] + r[2 * v1 + 2]) + 0.75f * (r[2 * v1] + r[2 * v1 + 1]);
      unsigned short a1, a2, a3, b1, b2, b3;
      split3(val0, a1, a2, a3);
      split3(val1, b1, b2, b3);
      const int k = u * MW + v0;
      ushort2 t;
      t.x = a1; t.y = b1; *(ushort2*)&outp[k] = t;
      t.x = a2; t.y = b2; *(ushort2*)&outp[MHW + k] = t;
      t.x = a3; t.y = b3; *(ushort2*)&outp[2 * MHW + k] = t;
    }
  } else {
    // ---- f_ms path ----
    const int bc = blockIdx.x - 4096;
    float* sm = smem;
    const float* img = fms + (size_t)bc * MHW;
    if (tid < 96) {
      int i0, i1; float w0, w1;
      taps96(tid, i0, i1, w0, w1);
      tIdx[tid] = make_int2(i0, i1);
      tWt[tid] = make_float2(w0, w1);
    }
    float s = 0.f;
    for (int q = tid; q < MHW / 4; q += 256) {
      float4 v = ((const float4*)img)[q];
      ((float4*)sm)[q] = v;
      s += v.x + v.y + v.z + v.w;
    }
    for (int off = 32; off; off >>= 1) s += __shfl_down(s, off);
    if ((tid & 63) == 0) rs[tid >> 6] = s;
    __syncthreads();
    const float mean = (rs[0] + rs[1] + rs[2] + rs[3]) / (float)MHW;
    float ss = 0.f;
    for (int i = tid; i < PHW; i += 256) {
      const int h = i / PW, w = i - h * PW;
      const int2 rI = tIdx[h]; const float2 rW = tWt[h];
      const int2 cI = tIdx[w]; const float2 cW = tWt[w];
      float v = rW.x * (cW.x * sm[rI.x * MW + cI.x] + cW.y * sm[rI.x * MW + cI.y]) +
                rW.y * (cW.x * sm[rI.y * MW + cI.x] + cW.y * sm[rI.y * MW + cI.y]);
      ss += v * v;
    }
    for (int off = 32; off; off >>= 1) ss += __shfl_down(ss, off);
    if ((tid & 63) == 0) rss[tid >> 6] = ss;
    __syncthreads();
    if (tid == 0) {
      float SS = rss[0] + rss[1] + rss[2] + rss[3];
      meanms[bc] = mean;
      msn[bc] = sqrtf(fmaxf(SS - (float)PHW * mean * mean, 0.f));
    }
    unsigned short* outp = msP + (size_t)bc * 3 * MHW;   // [c][plane][k]
    for (int i4 = tid; i4 < MHW / 4; i4 += 256) {
      const int i = 4 * i4;
      float4 v = *(const float4*)&sm[i];
      unsigned short p1[4], p2[4], p3[4];
      split3(v.x, p1[0], p2[0], p3[0]);
      split3(v.y, p1[1], p2[1], p3[1]);
      split3(v.z, p1[2], p2[2], p3[2]);
      split3(v.w, p1[3], p2[3], p3[3]);
      *(ushort4*)&outp[i] = make_ushort4(p1[0], p1[1], p1[2], p1[3]);
      *(ushort4*)&outp[MHW + i] = make_ushort4(p2[0], p2[1], p2[2], p2[3]);
      *(ushort4*)&outp[2 * MHW + i] = make_ushort4(p3[0], p3[1], p3[2], p3[3]);
    }
  }
}

// ---------------- Kernel C: split-bf16 MFMA GEMM, double-buffered (1 barrier/step) ----------------
__global__ __launch_bounds__(256) void k_gemm(const unsigned short* __restrict__ msP,
                                              const unsigned short* __restrict__ padjP,
                                              float* __restrict__ dotp) {
  __shared__ unsigned short As[2][2][3][64][40];   // [buf][mat][plane][row][k] = 122880 B
  const int n = blockIdx.x;                     // 0..255
  const int xcd = n & 7, slot = n >> 3;
  const int b = xcd * 2 + (slot >> 4);          // 2 batches per XCD
  const int xy = slot & 15;
  const int i0 = (xy >> 2) * 64, j0 = (xy & 3) * 64;
  const int tid = threadIdx.x, lane = tid & 63, wid = tid >> 6;
  const int wr = wid >> 1, wc = wid & 1;        // wave quadrant
  const int fr = lane & 15, fq = lane >> 4;

  const unsigned short* mats[2] = {
    msP + (size_t)(b * CC + i0) * 3 * MHW,
    padjP + (size_t)(b * CC + j0) * 3 * MHW
  };
  const unsigned short* gsrc[6];
  int lmat[6], lpl[6], lrow[6], lch[6];
#pragma unroll
  for (int q = 0; q < 6; ++q) {
    int t = tid + q * 256;                      // 1536 tasks: 128 rows x 3 planes x 4 chunks
    int ch = t & 3, pl = (t >> 2) % 3, r128 = t / 12;
    int mat = r128 >> 6, row = r128 & 63;
    gsrc[q] = mats[mat] + ((size_t)row * 3 + pl) * MHW + ch * 8;
    lmat[q] = mat; lpl[q] = pl; lrow[q] = row; lch[q] = ch;
  }
  bf16x8 stg[6];
  f32x4 acc[2][2] = {};

  auto g_load = [&](int kt) {
#pragma unroll
    for (int q = 0; q < 6; ++q) stg[q] = *(const bf16x8*)(gsrc[q] + kt);
  };
  auto l_store = [&](int buf) {
#pragma unroll
    for (int q = 0; q < 6; ++q)
      *(bf16x8*)&As[buf][lmat[q]][lpl[q]][lrow[q]][lch[q] * 8] = stg[q];
  };

  g_load(0);
  l_store(0);
  if (GSTEPS > 1) g_load(32);
  __syncthreads();
  int cur = 0;
  for (int step = 0; step < GSTEPS; ++step) {
    if (step + 1 < GSTEPS) l_store(cur ^ 1);     // store prefetched step+1 into idle buffer
    if (step + 2 < GSTEPS) g_load((step + 2) * 32);
    bf16x8 af[2][3], bfr[2][3];
#pragma unroll
    for (int ti = 0; ti < 2; ++ti)
#pragma unroll
      for (int p = 0; p < 3; ++p) {
        af[ti][p] = *(const bf16x8*)&As[cur][0][p][wr * 32 + ti * 16 + fr][fq * 8];
        bfr[ti][p] = *(const bf16x8*)&As[cur][1][p][wc * 32 + ti * 16 + fr][fq * 8];
      }
#pragma unroll
    for (int ti = 0; ti < 2; ++ti)
#pragma unroll
      for (int tj = 0; tj < 2; ++tj) {
        f32x4 c = acc[ti][tj];
        c = __builtin_amdgcn_mfma_f32_16x16x32_bf16(af[ti][0], bfr[tj][0], c, 0, 0, 0);
        c = __builtin_amdgcn_mfma_f32_16x16x32_bf16(af[ti][0], bfr[tj][1], c, 0, 0, 0);
        c = __builtin_amdgcn_mfma_f32_16x16x32_bf16(af[ti][1], bfr[tj][0], c, 0, 0, 0);
        c = __builtin_amdgcn_mfma_f32_16x16x32_bf16(af[ti][0], bfr[tj][2], c, 0, 0, 0);
        c = __builtin_amdgcn_mfma_f32_16x16x32_bf16(af[ti][1], bfr[tj][1], c, 0, 0, 0);
        c = __builtin_amdgcn_mfma_f32_16x16x32_bf16(af[ti][2], bfr[tj][0], c, 0, 0, 0);
        acc[ti][tj] = c;
      }
    __syncthreads();   // waves done reading As[cur]; stores to As[cur^1] visible
    cur ^= 1;
  }
  // Epilogue: C/D layout col = lane&15, row = (lane>>4)*4 + reg  [m89-verified]
  float* drow = dotp + ((size_t)b * CC + i0) * CC + j0;
#pragma unroll
  for (int ti = 0; ti < 2; ++ti)
#pragma unroll
    for (int tj = 0; tj < 2; ++tj)
#pragma unroll
      for (int j = 0; j < 4; ++j) {
        int row = wr * 32 + ti * 16 + fq * 4 + j;
        int col = wc * 32 + tj * 16 + fr;
        drow[(size_t)row * CC + col] = acc[ti][tj][j];
      }
}

// ---------------- Kernel C2: per-row max/argmax of similarity ----------------
__global__ __launch_bounds__(256) void k_rowmax(const float* __restrict__ dotp,
                                                const float* __restrict__ meanp,
                                                const float* __restrict__ pn,
                                                const float* __restrict__ meanms,
                                                const float* __restrict__ msn,
                                                float* __restrict__ maxv,
                                                int* __restrict__ amax) {
  const int tid = threadIdx.x;
  const int r = blockIdx.x * 4 + (tid >> 6);
  const int lane = tid & 63;
  const int b = r >> 8;
  const float* d0 = dotp + (size_t)r * CC;
  const float mm = meanms[r];
  const float inv = 100.f / msn[r];
  const int j = lane * 4;
  float4 v0 = *(const float4*)(d0 + j);
  float4 mp4 = *(const float4*)(meanp + b * CC + j);
  float4 pn4 = *(const float4*)(pn + b * CC + j);
  float sv[4];
  sv[0] = (v0.x - (float)PHW * mm * mp4.x) * inv / pn4.x;
  sv[1] = (v0.y - (float)PHW * mm * mp4.y) * inv / pn4.y;
  sv[2] = (v0.z - (float)PHW * mm * mp4.z) * inv / pn4.z;
  sv[3] = (v0.w - (float)PHW * mm * mp4.w) * inv / pn4.w;
  float best = sv[0]; int bj = j;
#pragma unroll
  for (int t = 1; t < 4; ++t)
    if (sv[t] > best) { best = sv[t]; bj = j + t; }
  for (int off = 32; off; off >>= 1) {
    float ov = __shfl_down(best, off);
    int oi = __shfl_down(bj, off);
    if (ov > best || (ov == best && oi < bj)) { best = ov; bj = oi; }
  }
  if (lane == 0) { maxv[r] = best; amax[r] = bj; }
}

// ---------------- Kernel D: group select + deterministic bitonic sort ----------------
__global__ __launch_bounds__(256) void k_group(const float* __restrict__ maxv,
                                               const int* __restrict__ amax,
                                               float* __restrict__ sscore,
                                               int* __restrict__ svals,
                                               int* __restrict__ cnt) {
  const int b = blockIdx.x, tid = threadIdx.x;
  __shared__ float mv[CC];
  __shared__ int sidx[CC];
  __shared__ float gsc[CC];
  __shared__ int pres[CC];
  __shared__ unsigned long long keys[CC];
  __shared__ float r1[4], r2[4];
  __shared__ int r3[4];
  float v = maxv[b * CC + tid];
  sidx[tid] = amax[b * CC + tid];
  float m = v;
  for (int off = 32; off; off >>= 1) m = fmaxf(m, __shfl_down(m, off));
  if ((tid & 63) == 0) r1[tid >> 6] = m;
  __syncthreads();
  float mt = fmaxf(fmaxf(r1[0], r1[1]), fmaxf(r1[2], r1[3]));
  float e = __expf(v - mt);
  float s = e;
  for (int off = 32; off; off >>= 1) s += __shfl_down(s, off);
  if ((tid & 63) == 0) r2[tid >> 6] = s;
  __syncthreads();
  float st = r2[0] + r2[1] + r2[2] + r2[3];
  mv[tid] = e / st;
  __syncthreads();
  float g = 0.f; int p = 0;
  for (int i2 = 0; i2 < CC; ++i2)
    if (sidx[i2] == tid) { g += mv[i2]; p = 1; }
  gsc[tid] = g; pres[tid] = p;
  int pc = p;
  for (int off = 32; off; off >>= 1) pc += __shfl_down(pc, off);
  if ((tid & 63) == 0) r3[tid >> 6] = pc;
  __syncthreads();
  if (tid == 0) cnt[b] = r3[0] + r3[1] + r3[2] + r3[3];
  int c = 255 - tid;
  float val = pres[c] ? gsc[c] : -INFINITY;
  keys[tid] = ((unsigned long long)f2ord(val) << 32) | (unsigned)c;
  __syncthreads();
  for (int ksz = 2; ksz <= 256; ksz <<= 1) {
    for (int jj = ksz >> 1; jj > 0; jj >>= 1) {
      int ixj = tid ^ jj;
      if (ixj > tid) {
        unsigned long long a = keys[tid], o = keys[ixj];
        bool descBlock = ((tid & ksz) == 0);
        bool sw = descBlock ? (a < o) : (a > o);
        if (sw) { keys[tid] = o; keys[ixj] = a; }
      }
      __syncthreads();
    }
  }
  unsigned long long kk = keys[tid];
  int cc2 = (int)(kk & 0xFFFFFFFFull);
  float vv = pres[cc2] ? gsc[cc2] : -INFINITY;
  sscore[b * CC + tid] = vv;
  svals[b * CC + tid] = cc2;
}

// ---------------- Kernel E: min_k + softmax weights ----------------
__global__ __launch_bounds__(128) void k_wsel(const float* __restrict__ sscore,
                                              const int* __restrict__ cnt,
                                              float* __restrict__ wgt,
                                              int* __restrict__ minkp) {
  const int b = blockIdx.x, tid = threadIdx.x;
  int mn = 0x7fffffff;
#pragma unroll
  for (int t = 0; t < CB; ++t) mn = min(mn, cnt[t]);
  const int mink = (mn + 1) >> 1;
  if (b == 0 && tid == 0) *minkp = mink;
  __shared__ float sh1[2], sh2[2];
  float v = (tid < mink) ? sscore[b * CC + tid] : -INFINITY;
  float m = v;
  for (int off = 32; off; off >>= 1) m = fmaxf(m, __shfl_down(m, off));
  if ((tid & 63) == 0) sh1[tid >> 6] = m;
  __syncthreads();
  float mt = fmaxf(sh1[0], sh1[1]);
  float e = (tid < mink) ? __expf(v - mt) : 0.f;
  float s = e;
  for (int off = 32; off; off >>= 1) s += __shfl_down(s, off);
  if ((tid & 63) == 0) sh2[tid >> 6] = s;
  __syncthreads();
  float st = sh2[0] + sh2[1];
  if (tid < mink) wgt[b * 128 + tid] = e / st;
}

// ---------------- Kernel F: fused mask + output, fine grid (2304 blocks), deep ILP ----------------
__global__ __launch_bounds__(256) void k_maskout(const float* __restrict__ fp,
                                                 const float* __restrict__ wgt,
                                                 const int* __restrict__ svals,
                                                 const int* __restrict__ minkp,
                                                 float* __restrict__ out) {
  const int b = blockIdx.y;
  const int pos = threadIdx.x & 15;
  const int kq = threadIdx.x >> 4;           // 0..15
  const int hw4 = blockIdx.x * 16 + pos;     // float4 index < 2304
  const int mink = *minkp;
  const int qlo = (mink * kq) >> 4, qhi = (mink * (kq + 1)) >> 4;
  const float* base = fp + (size_t)b * CC * PHW;
  float4 acc = make_float4(0.f, 0.f, 0.f, 0.f);
  // Phase 1: gather with 4-deep load batches; accumulation stays in ascending-k order.
  int k = qlo;
  for (; k + 4 <= qhi; k += 4) {
    float4 vv[4]; float wk[4];
#pragma unroll
    for (int t = 0; t < 4; ++t) {
      int c = svals[b * CC + k + t];
      wk[t] = wgt[b * 128 + k + t];
      vv[t] = ((const float4*)(base + (size_t)c * PHW))[hw4];
    }
#pragma unroll
    for (int t = 0; t < 4; ++t) {
      acc.x += wk[t] * sigmoidf_(vv[t].x);
      acc.y += wk[t] * sigmoidf_(vv[t].y);
      acc.z += wk[t] * sigmoidf_(vv[t].z);
      acc.w += wk[t] * sigmoidf_(vv[t].w);
    }
  }
  for (; k < qhi; ++k) {
    int c = svals[b * CC + k];
    float wk = wgt[b * 128 + k];
    float4 v = ((const float4*)(base + (size_t)c * PHW))[hw4];
    acc.x += wk * sigmoidf_(v.x);
    acc.y += wk * sigmoidf_(v.y);
    acc.z += wk * sigmoidf_(v.z);
    acc.w += wk * sigmoidf_(v.w);
  }
  __shared__ __align__(16) float4 sh[16][16];
  __shared__ __align__(16) float4 msh[16];
  sh[kq][pos] = acc;
  __syncthreads();
  if (kq == 0) {
    float4 r = sh[0][pos];
#pragma unroll
    for (int t = 1; t < 16; ++t) {
      float4 a = sh[t][pos];
      r.x += a.x; r.y += a.y; r.z += a.z; r.w += a.w;
    }
    msh[pos] = r;
  }
  __syncthreads();
  const float4 mk = msh[pos];
  float* outb = out + (size_t)b * CC * PHW;
  // Phase 2: 8-deep load batches (8 channels in flight), 2 halves.
#pragma unroll
  for (int half = 0; half < 2; ++half) {
    float4 v[8];
#pragma unroll
    for (int j = 0; j < 8; ++j) {
      const int c = (half * 8 + j) * 16 + kq;
      v[j] = ((const float4*)(base + (size_t)c * PHW))[hw4];
    }
#pragma unroll
    for (int j = 0; j < 8; ++j) {
      const int c = (half * 8 + j) * 16 + kq;
      float4 o;
      o.x = v[j].x * (1.f + mk.x);
      o.y = v[j].y * (1.f + mk.y);
      o.z = v[j].z * (1.f + mk.z);
      o.w = v[j].w * (1.f + mk.w);
      ((float4*)(outb + (size_t)c * PHW))[hw4] = o;
    }
  }
}

extern "C" void kernel_launch(void* const* d_in, const int* in_sizes, int n_in,
                              void* d_out, int out_size, void* d_ws, size_t ws_size,
                              hipStream_t stream) {
  (void)in_sizes; (void)n_in; (void)out_size;
  const float* fp = (const float*)d_in[0];
  const float* fms = (const float*)d_in[1];
  float* out = (float*)d_out;

  // Big scratch in d_out (dead before k_maskout overwrites it):
  //   padjP: 16*256*3*2304 ushorts = 14,155,776 float-slots
  //   msP  : same, at float-offset 14,155,776
  //   dot  : 16*256*256 floats at float-offset 28,311,552  (ends 29.36M < 37.75M)
  unsigned short* padjP = (unsigned short*)out;
  unsigned short* msP = (unsigned short*)(out + (size_t)14155776);
  float* dotp = out + (size_t)28311552;

  if (ws_size < (size_t)183000 * 4) return;
  float* wsf = (float*)d_ws;
  float* meanp = wsf;               // 4096
  float* pnv = wsf + 4096;          // 4096
  float* meanms = wsf + 8192;       // 4096
  float* msn = wsf + 12288;         // 4096
  float* maxv = wsf + 16384;        // 4096
  float* ssc = wsf + 20480;         // 4096
  float* wgt = wsf + 24576;         // 2048
  int* amax = (int*)(wsf + 174080); // 4096
  int* sv = (int*)(wsf + 178176);   // 4096
  int* cntp = (int*)(wsf + 182272); // 16
  int* minkp = (int*)(wsf + 182288);// 1

  k_stats<<<8192, 256, 0, stream>>>(fp, fms, padjP, msP, meanp, pnv, meanms, msn);
  k_gemm<<<256, 256, 0, stream>>>(msP, padjP, dotp);
  k_rowmax<<<(CB * CC) / 4, 256, 0, stream>>>(dotp, meanp, pnv, meanms, msn, maxv, amax);
  k_group<<<CB, 256, 0, stream>>>(maxv, amax, ssc, sv, cntp);
  k_wsel<<<CB, 128, 0, stream>>>(ssc, cntp, wgt, minkp);
  k_maskout<<<dim3(PHW / 4 / 16, CB), 256, 0, stream>>>(fp, wgt, sv, minkp, out);
}

// Round 14
// 225.090 us; speedup vs baseline: 1.7056x; 1.0623x over previous
//
#include <hip/hip_runtime.h>
#include <hip/hip_bf16.h>
#include <math.h>
#include <float.h>

// Problem constants
constexpr int CB = 16;        // batch
constexpr int CC = 256;       // channels
constexpr int PH = 96, PW = 96, PHW = 9216;
constexpr int MH = 48, MW = 48, MHW = 2304;
constexpr int GSTEPS = MHW / 32;   // 72 mfma k-steps

typedef __bf16 bf16x8 __attribute__((ext_vector_type(8)));
typedef float f32x4 __attribute__((ext_vector_type(4)));

__device__ __forceinline__ float sigmoidf_(float x) { return 1.f / (1.f + __expf(-x)); }

__device__ __forceinline__ unsigned f2ord(float f) {
  unsigned u = __float_as_uint(f);
  return (u & 0x80000000u) ? ~u : (u | 0x80000000u);
}

// Truncation-based 3-term bf16 split: v = b1 + b2 + b3 + err, |err| <= 2^-24 |v|.
__device__ __forceinline__ void split3(float v, unsigned short& h1, unsigned short& h2,
                                       unsigned short& h3) {
  unsigned u1 = __float_as_uint(v) & 0xFFFF0000u;
  float r1 = v - __uint_as_float(u1);
  unsigned u2 = __float_as_uint(r1) & 0xFFFF0000u;
  float r2 = r1 - __uint_as_float(u2);
  h1 = (unsigned short)(u1 >> 16);
  h2 = (unsigned short)(u2 >> 16);
  h3 = (unsigned short)(__float_as_uint(r2) >> 16);
}

// ---------------- Kernel A+B merged: stats + bf16 planes for both inputs
// blocks [0,4096): f_p path; blocks [4096,8192): f_ms path.
// ms-path SS uses the Gram identity: SS(up(m)) = sum m .* (G m G^T), G = W^T W tridiagonal
// with diag {1.625 edges, 1.25 inner}, offdiag 0.375 (column sums of W are 2 -> mean exact).
__global__ __launch_bounds__(256) void k_stats(const float* __restrict__ fp,
                                               const float* __restrict__ fms,
                                               unsigned short* __restrict__ padjP,
                                               unsigned short* __restrict__ msP,
                                               float* __restrict__ meanp,
                                               float* __restrict__ pn,
                                               float* __restrict__ meanms,
                                               float* __restrict__ msn) {
  __shared__ __align__(16) float smem[MH * PW];   // 18.4 KB (aliased by both paths)
  __shared__ float rs[4], rss[4];
  const int tid = threadIdx.x;
  if (blockIdx.x < 4096) {
    // ---- f_p path ----
    const int bc = blockIdx.x;
    float (*tmp)[PW] = (float(*)[PW])smem;
    const float* img = fp + (size_t)bc * PHW;
    // Stats: all 9 float4 loads issued upfront; accumulation order identical to round 13.
    float4 v9[9];
#pragma unroll
    for (int t = 0; t < 9; ++t) v9[t] = ((const float4*)img)[tid + t * 256];
    float s4[4] = {0.f, 0.f, 0.f, 0.f}, ss4[4] = {0.f, 0.f, 0.f, 0.f};
#pragma unroll
    for (int t = 0; t < 8; ++t) {
      const float4 v = v9[t];
      s4[t & 3] += v.x + v.y + v.z + v.w;
      ss4[t & 3] += v.x * v.x + v.y * v.y + v.z * v.z + v.w * v.w;
    }
    {
      const float4 v = v9[8];
      s4[0] += v.x + v.y + v.z + v.w;
      ss4[0] += v.x * v.x + v.y * v.y + v.z * v.z + v.w * v.w;
    }
    float s = (s4[0] + s4[1]) + (s4[2] + s4[3]);
    float ss = (ss4[0] + ss4[1]) + (ss4[2] + ss4[3]);
    for (int off = 32; off; off >>= 1) { s += __shfl_down(s, off); ss += __shfl_down(ss, off); }
    if ((tid & 63) == 0) { rs[tid >> 6] = s; rss[tid >> 6] = ss; }
    // Row adjoint, float4-wide: tmp[u][w] = sum_h Wrow[h,u] * p[h,w]
    for (int idx4 = tid; idx4 < MH * (PW / 4); idx4 += 256) {   // 1152
      const int u = idx4 / (PW / 4), w4 = (idx4 - u * (PW / 4)) * 4;
      float4 v;
      if (u == 0) {
        float4 a = *(const float4*)&img[w4];
        float4 b = *(const float4*)&img[PW + w4];
        float4 c = *(const float4*)&img[2 * PW + w4];
        v.x = a.x + 0.75f * b.x + 0.25f * c.x;
        v.y = a.y + 0.75f * b.y + 0.25f * c.y;
        v.z = a.z + 0.75f * b.z + 0.25f * c.z;
        v.w = a.w + 0.75f * b.w + 0.25f * c.w;
      } else if (u == MH - 1) {
        float4 a = *(const float4*)&img[(PH - 3) * PW + w4];
        float4 b = *(const float4*)&img[(PH - 2) * PW + w4];
        float4 c = *(const float4*)&img[(PH - 1) * PW + w4];
        v.x = 0.25f * a.x + 0.75f * b.x + c.x;
        v.y = 0.25f * a.y + 0.75f * b.y + c.y;
        v.z = 0.25f * a.z + 0.75f * b.z + c.z;
        v.w = 0.25f * a.w + 0.75f * b.w + c.w;
      } else {
        float4 a = *(const float4*)&img[(2 * u - 1) * PW + w4];
        float4 b = *(const float4*)&img[2 * u * PW + w4];
        float4 c = *(const float4*)&img[(2 * u + 1) * PW + w4];
        float4 d = *(const float4*)&img[(2 * u + 2) * PW + w4];
        v.x = 0.25f * (a.x + d.x) + 0.75f * (b.x + c.x);
        v.y = 0.25f * (a.y + d.y) + 0.75f * (b.y + c.y);
        v.z = 0.25f * (a.z + d.z) + 0.75f * (b.z + c.z);
        v.w = 0.25f * (a.w + d.w) + 0.75f * (b.w + c.w);
      }
      *(float4*)&tmp[u][w4] = v;
    }
    __syncthreads();
    if (tid == 0) {
      float S = rs[0] + rs[1] + rs[2] + rs[3];
      float SS = rss[0] + rss[1] + rss[2] + rss[3];
      meanp[bc] = S / (float)PHW;
      pn[bc] = sqrtf(fmaxf(SS - S * S / (float)PHW, 0.f));
    }
    unsigned short* outp = padjP + (size_t)bc * 3 * MHW;   // [c][plane][k]
    for (int idx = tid; idx < MH * (MW / 2); idx += 256) {
      const int u = idx / (MW / 2), j = idx - u * (MW / 2);
      const float* r = tmp[u];
      const int v0 = 2 * j, v1 = 2 * j + 1;
      float val0, val1;
      if (v0 == 0)
        val0 = r[0] + 0.75f * r[1] + 0.25f * r[2];
      else
        val0 = 0.25f * (r[2 * v0 - 1] + r[2 * v0 + 2]) + 0.75f * (r[2 * v0] + r[2 * v0 + 1]);
      if (v1 == MW - 1)
        val1 = 0.25f * r[PW - 3] + 0.75f * r[PW - 2] + r[PW - 1];
      else
        val1 = 0.25f * (r[2 * v1 - 1] + r[2 * v1 + 2]) + 0.75f * (r[2 * v1] + r[2 * v1 + 1]);
      unsigned short a1, a2, a3, b1, b2, b3;
      split3(val0, a1, a2, a3);
      split3(val1, b1, b2, b3);
      const int k = u * MW + v0;
      ushort2 t;
      t.x = a1; t.y = b1; *(ushort2*)&outp[k] = t;
      t.x = a2; t.y = b2; *(ushort2*)&outp[MHW + k] = t;
      t.x = a3; t.y = b3; *(ushort2*)&outp[2 * MHW + k] = t;
    }
  } else {
    // ---- f_ms path ----
    const int bc = blockIdx.x - 4096;
    float* m = smem;            // 2304 floats
    float* t = smem + MHW;      // 2304 floats (fits: MH*PW = 4608)
    const float* img = fms + (size_t)bc * MHW;
    float s = 0.f;
    for (int q = tid; q < MHW / 4; q += 256) {
      float4 v = ((const float4*)img)[q];
      ((float4*)m)[q] = v;
      s += v.x + v.y + v.z + v.w;
    }
    for (int off = 32; off; off >>= 1) s += __shfl_down(s, off);
    if ((tid & 63) == 0) rs[tid >> 6] = s;
    __syncthreads();
    const float mean = (rs[0] + rs[1] + rs[2] + rs[3]) / (float)MHW;
    // Col apply: t[i][j] = d_j*m[i][j] + 0.375*(m[i][j-1] + m[i][j+1])
    for (int idx = tid; idx < MHW; idx += 256) {
      const int i = idx / MW, j = idx - i * MW;
      const float c = m[idx];
      const float l = (j > 0) ? m[idx - 1] : 0.f;
      const float r = (j < MW - 1) ? m[idx + 1] : 0.f;
      const float dj = (j == 0 || j == MW - 1) ? 1.625f : 1.25f;
      t[idx] = dj * c + 0.375f * (l + r);
    }
    __syncthreads();
    // Row apply + dot: ss = sum m[i][j] * (d_i*t[i][j] + 0.375*(t[i-1][j] + t[i+1][j]))
    float ss = 0.f;
    for (int idx = tid; idx < MHW; idx += 256) {
      const int i = idx / MW;
      const float c = t[idx];
      const float up = (i > 0) ? t[idx - MW] : 0.f;
      const float dn = (i < MH - 1) ? t[idx + MW] : 0.f;
      const float di = (i == 0 || i == MH - 1) ? 1.625f : 1.25f;
      ss += m[idx] * (di * c + 0.375f * (up + dn));
    }
    for (int off = 32; off; off >>= 1) ss += __shfl_down(ss, off);
    if ((tid & 63) == 0) rss[tid >> 6] = ss;
    __syncthreads();
    if (tid == 0) {
      float SS = rss[0] + rss[1] + rss[2] + rss[3];
      meanms[bc] = mean;
      msn[bc] = sqrtf(fmaxf(SS - (float)PHW * mean * mean, 0.f));
    }
    unsigned short* outp = msP + (size_t)bc * 3 * MHW;   // [c][plane][k]
    for (int i4 = tid; i4 < MHW / 4; i4 += 256) {
      const int i = 4 * i4;
      float4 v = *(const float4*)&m[i];
      unsigned short p1[4], p2[4], p3[4];
      split3(v.x, p1[0], p2[0], p3[0]);
      split3(v.y, p1[1], p2[1], p3[1]);
      split3(v.z, p1[2], p2[2], p3[2]);
      split3(v.w, p1[3], p2[3], p3[3]);
      *(ushort4*)&outp[i] = make_ushort4(p1[0], p1[1], p1[2], p1[3]);
      *(ushort4*)&outp[MHW + i] = make_ushort4(p2[0], p2[1], p2[2], p2[3]);
      *(ushort4*)&outp[2 * MHW + i] = make_ushort4(p3[0], p3[1], p3[2], p3[3]);
    }
  }
}

// ---------------- Kernel C: split-bf16 MFMA GEMM, double-buffered (1 barrier/step) ----------------
__global__ __launch_bounds__(256) void k_gemm(const unsigned short* __restrict__ msP,
                                              const unsigned short* __restrict__ padjP,
                                              float* __restrict__ dotp) {
  __shared__ unsigned short As[2][2][3][64][40];   // [buf][mat][plane][row][k] = 122880 B
  const int n = blockIdx.x;                     // 0..255
  const int xcd = n & 7, slot = n >> 3;
  const int b = xcd * 2 + (slot >> 4);          // 2 batches per XCD
  const int xy = slot & 15;
  const int i0 = (xy >> 2) * 64, j0 = (xy & 3) * 64;
  const int tid = threadIdx.x, lane = tid & 63, wid = tid >> 6;
  const int wr = wid >> 1, wc = wid & 1;        // wave quadrant
  const int fr = lane & 15, fq = lane >> 4;

  const unsigned short* mats[2] = {
    msP + (size_t)(b * CC + i0) * 3 * MHW,
    padjP + (size_t)(b * CC + j0) * 3 * MHW
  };
  const unsigned short* gsrc[6];
  int lmat[6], lpl[6], lrow[6], lch[6];
#pragma unroll
  for (int q = 0; q < 6; ++q) {
    int t = tid + q * 256;                      // 1536 tasks: 128 rows x 3 planes x 4 chunks
    int ch = t & 3, pl = (t >> 2) % 3, r128 = t / 12;
    int mat = r128 >> 6, row = r128 & 63;
    gsrc[q] = mats[mat] + ((size_t)row * 3 + pl) * MHW + ch * 8;
    lmat[q] = mat; lpl[q] = pl; lrow[q] = row; lch[q] = ch;
  }
  bf16x8 stg[6];
  f32x4 acc[2][2] = {};

  auto g_load = [&](int kt) {
#pragma unroll
    for (int q = 0; q < 6; ++q) stg[q] = *(const bf16x8*)(gsrc[q] + kt);
  };
  auto l_store = [&](int buf) {
#pragma unroll
    for (int q = 0; q < 6; ++q)
      *(bf16x8*)&As[buf][lmat[q]][lpl[q]][lrow[q]][lch[q] * 8] = stg[q];
  };

  g_load(0);
  l_store(0);
  if (GSTEPS > 1) g_load(32);
  __syncthreads();
  int cur = 0;
  for (int step = 0; step < GSTEPS; ++step) {
    if (step + 1 < GSTEPS) l_store(cur ^ 1);     // store prefetched step+1 into idle buffer
    if (step + 2 < GSTEPS) g_load((step + 2) * 32);
    bf16x8 af[2][3], bfr[2][3];
#pragma unroll
    for (int ti = 0; ti < 2; ++ti)
#pragma unroll
      for (int p = 0; p < 3; ++p) {
        af[ti][p] = *(const bf16x8*)&As[cur][0][p][wr * 32 + ti * 16 + fr][fq * 8];
        bfr[ti][p] = *(const bf16x8*)&As[cur][1][p][wc * 32 + ti * 16 + fr][fq * 8];
      }
#pragma unroll
    for (int ti = 0; ti < 2; ++ti)
#pragma unroll
      for (int tj = 0; tj < 2; ++tj) {
        f32x4 c = acc[ti][tj];
        c = __builtin_amdgcn_mfma_f32_16x16x32_bf16(af[ti][0], bfr[tj][0], c, 0, 0, 0);
        c = __builtin_amdgcn_mfma_f32_16x16x32_bf16(af[ti][0], bfr[tj][1], c, 0, 0, 0);
        c = __builtin_amdgcn_mfma_f32_16x16x32_bf16(af[ti][1], bfr[tj][0], c, 0, 0, 0);
        c = __builtin_amdgcn_mfma_f32_16x16x32_bf16(af[ti][0], bfr[tj][2], c, 0, 0, 0);
        c = __builtin_amdgcn_mfma_f32_16x16x32_bf16(af[ti][1], bfr[tj][1], c, 0, 0, 0);
        c = __builtin_amdgcn_mfma_f32_16x16x32_bf16(af[ti][2], bfr[tj][0], c, 0, 0, 0);
        acc[ti][tj] = c;
      }
    __syncthreads();   // waves done reading As[cur]; stores to As[cur^1] visible
    cur ^= 1;
  }
  // Epilogue: C/D layout col = lane&15, row = (lane>>4)*4 + reg  [m89-verified]
  float* drow = dotp + ((size_t)b * CC + i0) * CC + j0;
#pragma unroll
  for (int ti = 0; ti < 2; ++ti)
#pragma unroll
    for (int tj = 0; tj < 2; ++tj)
#pragma unroll
      for (int j = 0; j < 4; ++j) {
        int row = wr * 32 + ti * 16 + fq * 4 + j;
        int col = wc * 32 + tj * 16 + fr;
        drow[(size_t)row * CC + col] = acc[ti][tj][j];
      }
}

// ---------------- Kernel C2: per-row max/argmax of similarity ----------------
__global__ __launch_bounds__(256) void k_rowmax(const float* __restrict__ dotp,
                                                const float* __restrict__ meanp,
                                                const float* __restrict__ pn,
                                                const float* __restrict__ meanms,
                                                const float* __restrict__ msn,
                                                float* __restrict__ maxv,
                                                int* __restrict__ amax) {
  const int tid = threadIdx.x;
  const int r = blockIdx.x * 4 + (tid >> 6);
  const int lane = tid & 63;
  const int b = r >> 8;
  const float* d0 = dotp + (size_t)r * CC;
  const float mm = meanms[r];
  const float inv = 100.f / msn[r];
  const int j = lane * 4;
  float4 v0 = *(const float4*)(d0 + j);
  float4 mp4 = *(const float4*)(meanp + b * CC + j);
  float4 pn4 = *(const float4*)(pn + b * CC + j);
  float sv[4];
  sv[0] = (v0.x - (float)PHW * mm * mp4.x) * inv / pn4.x;
  sv[1] = (v0.y - (float)PHW * mm * mp4.y) * inv / pn4.y;
  sv[2] = (v0.z - (float)PHW * mm * mp4.z) * inv / pn4.z;
  sv[3] = (v0.w - (float)PHW * mm * mp4.w) * inv / pn4.w;
  float best = sv[0]; int bj = j;
#pragma unroll
  for (int t = 1; t < 4; ++t)
    if (sv[t] > best) { best = sv[t]; bj = j + t; }
  for (int off = 32; off; off >>= 1) {
    float ov = __shfl_down(best, off);
    int oi = __shfl_down(bj, off);
    if (ov > best || (ov == best && oi < bj)) { best = ov; bj = oi; }
  }
  if (lane == 0) { maxv[r] = best; amax[r] = bj; }
}

// ---------------- Kernel D: group select + deterministic bitonic sort ----------------
__global__ __launch_bounds__(256) void k_group(const float* __restrict__ maxv,
                                               const int* __restrict__ amax,
                                               float* __restrict__ sscore,
                                               int* __restrict__ svals,
                                               int* __restrict__ cnt) {
  const int b = blockIdx.x, tid = threadIdx.x;
  __shared__ float mv[CC];
  __shared__ int sidx[CC];
  __shared__ float gsc[CC];
  __shared__ int pres[CC];
  __shared__ unsigned long long keys[CC];
  __shared__ float r1[4], r2[4];
  __shared__ int r3[4];
  float v = maxv[b * CC + tid];
  sidx[tid] = amax[b * CC + tid];
  float m = v;
  for (int off = 32; off; off >>= 1) m = fmaxf(m, __shfl_down(m, off));
  if ((tid & 63) == 0) r1[tid >> 6] = m;
  __syncthreads();
  float mt = fmaxf(fmaxf(r1[0], r1[1]), fmaxf(r1[2], r1[3]));
  float e = __expf(v - mt);
  float s = e;
  for (int off = 32; off; off >>= 1) s += __shfl_down(s, off);
  if ((tid & 63) == 0) r2[tid >> 6] = s;
  __syncthreads();
  float st = r2[0] + r2[1] + r2[2] + r2[3];
  mv[tid] = e / st;
  __syncthreads();
  float g = 0.f; int p = 0;
  for (int i2 = 0; i2 < CC; ++i2)
    if (sidx[i2] == tid) { g += mv[i2]; p = 1; }
  gsc[tid] = g; pres[tid] = p;
  int pc = p;
  for (int off = 32; off; off >>= 1) pc += __shfl_down(pc, off);
  if ((tid & 63) == 0) r3[tid >> 6] = pc;
  __syncthreads();
  if (tid == 0) cnt[b] = r3[0] + r3[1] + r3[2] + r3[3];
  int c = 255 - tid;
  float val = pres[c] ? gsc[c] : -INFINITY;
  keys[tid] = ((unsigned long long)f2ord(val) << 32) | (unsigned)c;
  __syncthreads();
  for (int ksz = 2; ksz <= 256; ksz <<= 1) {
    for (int jj = ksz >> 1; jj > 0; jj >>= 1) {
      int ixj = tid ^ jj;
      if (ixj > tid) {
        unsigned long long a = keys[tid], o = keys[ixj];
        bool descBlock = ((tid & ksz) == 0);
        bool sw = descBlock ? (a < o) : (a > o);
        if (sw) { keys[tid] = o; keys[ixj] = a; }
      }
      __syncthreads();
    }
  }
  unsigned long long kk = keys[tid];
  int cc2 = (int)(kk & 0xFFFFFFFFull);
  float vv = pres[cc2] ? gsc[cc2] : -INFINITY;
  sscore[b * CC + tid] = vv;
  svals[b * CC + tid] = cc2;
}

// ---------------- Kernel E: min_k + softmax weights ----------------
__global__ __launch_bounds__(128) void k_wsel(const float* __restrict__ sscore,
                                              const int* __restrict__ cnt,
                                              float* __restrict__ wgt,
                                              int* __restrict__ minkp) {
  const int b = blockIdx.x, tid = threadIdx.x;
  int mn = 0x7fffffff;
#pragma unroll
  for (int t = 0; t < CB; ++t) mn = min(mn, cnt[t]);
  const int mink = (mn + 1) >> 1;
  if (b == 0 && tid == 0) *minkp = mink;
  __shared__ float sh1[2], sh2[2];
  float v = (tid < mink) ? sscore[b * CC + tid] : -INFINITY;
  float m = v;
  for (int off = 32; off; off >>= 1) m = fmaxf(m, __shfl_down(m, off));
  if ((tid & 63) == 0) sh1[tid >> 6] = m;
  __syncthreads();
  float mt = fmaxf(sh1[0], sh1[1]);
  float e = (tid < mink) ? __expf(v - mt) : 0.f;
  float s = e;
  for (int off = 32; off; off >>= 1) s += __shfl_down(s, off);
  if ((tid & 63) == 0) sh2[tid >> 6] = s;
  __syncthreads();
  float st = sh2[0] + sh2[1];
  if (tid < mink) wgt[b * 128 + tid] = e / st;
}

// ---------------- Kernel F: fused mask + output, fine grid (2304 blocks), deep ILP ----------------
__global__ __launch_bounds__(256) void k_maskout(const float* __restrict__ fp,
                                                 const float* __restrict__ wgt,
                                                 const int* __restrict__ svals,
                                                 const int* __restrict__ minkp,
                                                 float* __restrict__ out) {
  const int b = blockIdx.y;
  const int pos = threadIdx.x & 15;
  const int kq = threadIdx.x >> 4;           // 0..15
  const int hw4 = blockIdx.x * 16 + pos;     // float4 index < 2304
  const int mink = *minkp;
  const int qlo = (mink * kq) >> 4, qhi = (mink * (kq + 1)) >> 4;
  const float* base = fp + (size_t)b * CC * PHW;
  float4 acc = make_float4(0.f, 0.f, 0.f, 0.f);
  // Phase 1: gather with 4-deep load batches; accumulation stays in ascending-k order.
  int k = qlo;
  for (; k + 4 <= qhi; k += 4) {
    float4 vv[4]; float wk[4];
#pragma unroll
    for (int t = 0; t < 4; ++t) {
      int c = svals[b * CC + k + t];
      wk[t] = wgt[b * 128 + k + t];
      vv[t] = ((const float4*)(base + (size_t)c * PHW))[hw4];
    }
#pragma unroll
    for (int t = 0; t < 4; ++t) {
      acc.x += wk[t] * sigmoidf_(vv[t].x);
      acc.y += wk[t] * sigmoidf_(vv[t].y);
      acc.z += wk[t] * sigmoidf_(vv[t].z);
      acc.w += wk[t] * sigmoidf_(vv[t].w);
    }
  }
  for (; k < qhi; ++k) {
    int c = svals[b * CC + k];
    float wk = wgt[b * 128 + k];
    float4 v = ((const float4*)(base + (size_t)c * PHW))[hw4];
    acc.x += wk * sigmoidf_(v.x);
    acc.y += wk * sigmoidf_(v.y);
    acc.z += wk * sigmoidf_(v.z);
    acc.w += wk * sigmoidf_(v.w);
  }
  __shared__ __align__(16) float4 sh[16][16];
  __shared__ __align__(16) float4 msh[16];
  sh[kq][pos] = acc;
  __syncthreads();
  if (kq == 0) {
    float4 r = sh[0][pos];
#pragma unroll
    for (int t = 1; t < 16; ++t) {
      float4 a = sh[t][pos];
      r.x += a.x; r.y += a.y; r.z += a.z; r.w += a.w;
    }
    msh[pos] = r;
  }
  __syncthreads();
  const float4 mk = msh[pos];
  float* outb = out + (size_t)b * CC * PHW;
  // Phase 2: 8-deep load batches (8 channels in flight), 2 halves.
#pragma unroll
  for (int half = 0; half < 2; ++half) {
    float4 v[8];
#pragma unroll
    for (int j = 0; j < 8; ++j) {
      const int c = (half * 8 + j) * 16 + kq;
      v[j] = ((const float4*)(base + (size_t)c * PHW))[hw4];
    }
#pragma unroll
    for (int j = 0; j < 8; ++j) {
      const int c = (half * 8 + j) * 16 + kq;
      float4 o;
      o.x = v[j].x * (1.f + mk.x);
      o.y = v[j].y * (1.f + mk.y);
      o.z = v[j].z * (1.f + mk.z);
      o.w = v[j].w * (1.f + mk.w);
      ((float4*)(outb + (size_t)c * PHW))[hw4] = o;
    }
  }
}

extern "C" void kernel_launch(void* const* d_in, const int* in_sizes, int n_in,
                              void* d_out, int out_size, void* d_ws, size_t ws_size,
                              hipStream_t stream) {
  (void)in_sizes; (void)n_in; (void)out_size;
  const float* fp = (const float*)d_in[0];
  const float* fms = (const float*)d_in[1];
  float* out = (float*)d_out;

  // Big scratch in d_out (dead before k_maskout overwrites it):
  //   padjP: 16*256*3*2304 ushorts = 14,155,776 float-slots
  //   msP  : same, at float-offset 14,155,776
  //   dot  : 16*256*256 floats at float-offset 28,311,552  (ends 29.36M < 37.75M)
  unsigned short* padjP = (unsigned short*)out;
  unsigned short* msP = (unsigned short*)(out + (size_t)14155776);
  float* dotp = out + (size_t)28311552;

  if (ws_size < (size_t)183000 * 4) return;
  float* wsf = (float*)d_ws;
  float* meanp = wsf;               // 4096
  float* pnv = wsf + 4096;          // 4096
  float* meanms = wsf + 8192;       // 4096
  float* msn = wsf + 12288;         // 4096
  float* maxv = wsf + 16384;        // 4096
  float* ssc = wsf + 20480;         // 4096
  float* wgt = wsf + 24576;         // 2048
  int* amax = (int*)(wsf + 174080); // 4096
  int* sv = (int*)(wsf + 178176);   // 4096
  int* cntp = (int*)(wsf + 182272); // 16
  int* minkp = (int*)(wsf + 182288);// 1

  k_stats<<<8192, 256, 0, stream>>>(fp, fms, padjP, msP, meanp, pnv, meanms, msn);
  k_gemm<<<256, 256, 0, stream>>>(msP, padjP, dotp);
  k_rowmax<<<(CB * CC) / 4, 256, 0, stream>>>(dotp, meanp, pnv, meanms, msn, maxv, amax);
  k_group<<<CB, 256, 0, stream>>>(maxv, amax, ssc, sv, cntp);
  k_wsel<<<CB, 128, 0, stream>>>(ssc, cntp, wgt, minkp);
  k_maskout<<<dim3(PHW / 4 / 16, CB), 256, 0, stream>>>(fp, wgt, sv, minkp, out);
}

// Round 15
// 219.171 us; speedup vs baseline: 1.7517x; 1.0270x over previous
//
#include <hip/hip_runtime.h>
#include <hip/hip_bf16.h>
#include <math.h>
#include <float.h>

// Problem constants
constexpr int CB = 16;        // batch
constexpr int CC = 256;       // channels
constexpr int PH = 96, PW = 96, PHW = 9216;
constexpr int MH = 48, MW = 48, MHW = 2304;
constexpr int GSTEPS = MHW / 32;   // 72 mfma k-steps

typedef __bf16 bf16x8 __attribute__((ext_vector_type(8)));
typedef float f32x4 __attribute__((ext_vector_type(4)));

__device__ __forceinline__ float sigmoidf_(float x) { return 1.f / (1.f + __expf(-x)); }

__device__ __forceinline__ unsigned f2ord(float f) {
  unsigned u = __float_as_uint(f);
  return (u & 0x80000000u) ? ~u : (u | 0x80000000u);
}

// Truncation-based 3-term bf16 split: v = b1 + b2 + b3 + err, |err| <= 2^-24 |v|.
__device__ __forceinline__ void split3(float v, unsigned short& h1, unsigned short& h2,
                                       unsigned short& h3) {
  unsigned u1 = __float_as_uint(v) & 0xFFFF0000u;
  float r1 = v - __uint_as_float(u1);
  unsigned u2 = __float_as_uint(r1) & 0xFFFF0000u;
  float r2 = r1 - __uint_as_float(u2);
  h1 = (unsigned short)(u1 >> 16);
  h2 = (unsigned short)(u2 >> 16);
  h3 = (unsigned short)(__float_as_uint(r2) >> 16);
}

// ---------------- Kernel A+B merged: stats + bf16 planes for both inputs
// blocks [0,4096): f_p path (stats fused into adjoint loop -> single HBM pass);
// blocks [4096,8192): f_ms path (Gram-identity SS).
__global__ __launch_bounds__(256) void k_stats(const float* __restrict__ fp,
                                               const float* __restrict__ fms,
                                               unsigned short* __restrict__ padjP,
                                               unsigned short* __restrict__ msP,
                                               float* __restrict__ meanp,
                                               float* __restrict__ pn,
                                               float* __restrict__ meanms,
                                               float* __restrict__ msn) {
  __shared__ __align__(16) float smem[MH * PW];   // 18.4 KB (aliased by both paths)
  __shared__ float rs[4], rss[4];
  const int tid = threadIdx.x;
  if (blockIdx.x < 4096) {
    // ---- f_p path ----
    const int bc = blockIdx.x;
    float (*tmp)[PW] = (float(*)[PW])smem;
    const float* img = fp + (size_t)bc * PHW;
    // Row adjoint with fused stats: task (u,w4) accumulates s/ss from rows 2u,2u+1
    // (u=0 -> rows 0,1; u=47 -> rows 94,95) -> every element counted exactly once.
    float s = 0.f, ss = 0.f;
    for (int idx4 = tid; idx4 < MH * (PW / 4); idx4 += 256) {   // 1152
      const int u = idx4 / (PW / 4), w4 = (idx4 - u * (PW / 4)) * 4;
      float4 v, p0, p1;
      if (u == 0) {
        float4 a = *(const float4*)&img[w4];
        float4 b = *(const float4*)&img[PW + w4];
        float4 c = *(const float4*)&img[2 * PW + w4];
        v.x = a.x + 0.75f * b.x + 0.25f * c.x;
        v.y = a.y + 0.75f * b.y + 0.25f * c.y;
        v.z = a.z + 0.75f * b.z + 0.25f * c.z;
        v.w = a.w + 0.75f * b.w + 0.25f * c.w;
        p0 = a; p1 = b;
      } else if (u == MH - 1) {
        float4 a = *(const float4*)&img[(PH - 3) * PW + w4];
        float4 b = *(const float4*)&img[(PH - 2) * PW + w4];
        float4 c = *(const float4*)&img[(PH - 1) * PW + w4];
        v.x = 0.25f * a.x + 0.75f * b.x + c.x;
        v.y = 0.25f * a.y + 0.75f * b.y + c.y;
        v.z = 0.25f * a.z + 0.75f * b.z + c.z;
        v.w = 0.25f * a.w + 0.75f * b.w + c.w;
        p0 = b; p1 = c;
      } else {
        float4 a = *(const float4*)&img[(2 * u - 1) * PW + w4];
        float4 b = *(const float4*)&img[2 * u * PW + w4];
        float4 c = *(const float4*)&img[(2 * u + 1) * PW + w4];
        float4 d = *(const float4*)&img[(2 * u + 2) * PW + w4];
        v.x = 0.25f * (a.x + d.x) + 0.75f * (b.x + c.x);
        v.y = 0.25f * (a.y + d.y) + 0.75f * (b.y + c.y);
        v.z = 0.25f * (a.z + d.z) + 0.75f * (b.z + c.z);
        v.w = 0.25f * (a.w + d.w) + 0.75f * (b.w + c.w);
        p0 = b; p1 = c;
      }
      s += (p0.x + p0.y + p0.z + p0.w) + (p1.x + p1.y + p1.z + p1.w);
      ss += (p0.x * p0.x + p0.y * p0.y + p0.z * p0.z + p0.w * p0.w) +
            (p1.x * p1.x + p1.y * p1.y + p1.z * p1.z + p1.w * p1.w);
      *(float4*)&tmp[u][w4] = v;
    }
    for (int off = 32; off; off >>= 1) { s += __shfl_down(s, off); ss += __shfl_down(ss, off); }
    if ((tid & 63) == 0) { rs[tid >> 6] = s; rss[tid >> 6] = ss; }
    __syncthreads();
    if (tid == 0) {
      float S = rs[0] + rs[1] + rs[2] + rs[3];
      float SS = rss[0] + rss[1] + rss[2] + rss[3];
      meanp[bc] = S / (float)PHW;
      pn[bc] = sqrtf(fmaxf(SS - S * S / (float)PHW, 0.f));
    }
    unsigned short* outp = padjP + (size_t)bc * 3 * MHW;   // [c][plane][k]
    for (int idx = tid; idx < MH * (MW / 2); idx += 256) {
      const int u = idx / (MW / 2), j = idx - u * (MW / 2);
      const float* r = tmp[u];
      const int v0 = 2 * j, v1 = 2 * j + 1;
      float val0, val1;
      if (v0 == 0)
        val0 = r[0] + 0.75f * r[1] + 0.25f * r[2];
      else
        val0 = 0.25f * (r[2 * v0 - 1] + r[2 * v0 + 2]) + 0.75f * (r[2 * v0] + r[2 * v0 + 1]);
      if (v1 == MW - 1)
        val1 = 0.25f * r[PW - 3] + 0.75f * r[PW - 2] + r[PW - 1];
      else
        val1 = 0.25f * (r[2 * v1 - 1] + r[2 * v1 + 2]) + 0.75f * (r[2 * v1] + r[2 * v1 + 1]);
      unsigned short a1, a2, a3, b1, b2, b3;
      split3(val0, a1, a2, a3);
      split3(val1, b1, b2, b3);
      const int k = u * MW + v0;
      ushort2 t;
      t.x = a1; t.y = b1; *(ushort2*)&outp[k] = t;
      t.x = a2; t.y = b2; *(ushort2*)&outp[MHW + k] = t;
      t.x = a3; t.y = b3; *(ushort2*)&outp[2 * MHW + k] = t;
    }
  } else {
    // ---- f_ms path ----
    const int bc = blockIdx.x - 4096;
    float* m = smem;            // 2304 floats
    float* t = smem + MHW;      // 2304 floats
    const float* img = fms + (size_t)bc * MHW;
    float s = 0.f;
    for (int q = tid; q < MHW / 4; q += 256) {
      float4 v = ((const float4*)img)[q];
      ((float4*)m)[q] = v;
      s += v.x + v.y + v.z + v.w;
    }
    for (int off = 32; off; off >>= 1) s += __shfl_down(s, off);
    if ((tid & 63) == 0) rs[tid >> 6] = s;
    __syncthreads();
    const float mean = (rs[0] + rs[1] + rs[2] + rs[3]) / (float)MHW;
    for (int idx = tid; idx < MHW; idx += 256) {
      const int i = idx / MW, j = idx - i * MW;
      const float c = m[idx];
      const float l = (j > 0) ? m[idx - 1] : 0.f;
      const float r = (j < MW - 1) ? m[idx + 1] : 0.f;
      const float dj = (j == 0 || j == MW - 1) ? 1.625f : 1.25f;
      t[idx] = dj * c + 0.375f * (l + r);
    }
    __syncthreads();
    float ss = 0.f;
    for (int idx = tid; idx < MHW; idx += 256) {
      const int i = idx / MW;
      const float c = t[idx];
      const float up = (i > 0) ? t[idx - MW] : 0.f;
      const float dn = (i < MH - 1) ? t[idx + MW] : 0.f;
      const float di = (i == 0 || i == MH - 1) ? 1.625f : 1.25f;
      ss += m[idx] * (di * c + 0.375f * (up + dn));
    }
    for (int off = 32; off; off >>= 1) ss += __shfl_down(ss, off);
    if ((tid & 63) == 0) rss[tid >> 6] = ss;
    __syncthreads();
    if (tid == 0) {
      float SS = rss[0] + rss[1] + rss[2] + rss[3];
      meanms[bc] = mean;
      msn[bc] = sqrtf(fmaxf(SS - (float)PHW * mean * mean, 0.f));
    }
    unsigned short* outp = msP + (size_t)bc * 3 * MHW;   // [c][plane][k]
    for (int i4 = tid; i4 < MHW / 4; i4 += 256) {
      const int i = 4 * i4;
      float4 v = *(const float4*)&m[i];
      unsigned short p1[4], p2[4], p3[4];
      split3(v.x, p1[0], p2[0], p3[0]);
      split3(v.y, p1[1], p2[1], p3[1]);
      split3(v.z, p1[2], p2[2], p3[2]);
      split3(v.w, p1[3], p2[3], p3[3]);
      *(ushort4*)&outp[i] = make_ushort4(p1[0], p1[1], p1[2], p1[3]);
      *(ushort4*)&outp[MHW + i] = make_ushort4(p2[0], p2[1], p2[2], p2[3]);
      *(ushort4*)&outp[2 * MHW + i] = make_ushort4(p3[0], p3[1], p3[2], p3[3]);
    }
  }
}

// ---------------- Kernel C: split-bf16 MFMA GEMM, double-buffered (1 barrier/step) ----------------
__global__ __launch_bounds__(256) void k_gemm(const unsigned short* __restrict__ msP,
                                              const unsigned short* __restrict__ padjP,
                                              float* __restrict__ dotp) {
  __shared__ unsigned short As[2][2][3][64][40];   // [buf][mat][plane][row][k] = 122880 B
  const int n = blockIdx.x;                     // 0..255
  const int xcd = n & 7, slot = n >> 3;
  const int b = xcd * 2 + (slot >> 4);          // 2 batches per XCD
  const int xy = slot & 15;
  const int i0 = (xy >> 2) * 64, j0 = (xy & 3) * 64;
  const int tid = threadIdx.x, lane = tid & 63, wid = tid >> 6;
  const int wr = wid >> 1, wc = wid & 1;        // wave quadrant
  const int fr = lane & 15, fq = lane >> 4;

  const unsigned short* mats[2] = {
    msP + (size_t)(b * CC + i0) * 3 * MHW,
    padjP + (size_t)(b * CC + j0) * 3 * MHW
  };
  const unsigned short* gsrc[6];
  int lmat[6], lpl[6], lrow[6], lch[6];
#pragma unroll
  for (int q = 0; q < 6; ++q) {
    int t = tid + q * 256;                      // 1536 tasks: 128 rows x 3 planes x 4 chunks
    int ch = t & 3, pl = (t >> 2) % 3, r128 = t / 12;
    int mat = r128 >> 6, row = r128 & 63;
    gsrc[q] = mats[mat] + ((size_t)row * 3 + pl) * MHW + ch * 8;
    lmat[q] = mat; lpl[q] = pl; lrow[q] = row; lch[q] = ch;
  }
  bf16x8 stg[6];
  f32x4 acc[2][2] = {};

  auto g_load = [&](int kt) {
#pragma unroll
    for (int q = 0; q < 6; ++q) stg[q] = *(const bf16x8*)(gsrc[q] + kt);
  };
  auto l_store = [&](int buf) {
#pragma unroll
    for (int q = 0; q < 6; ++q)
      *(bf16x8*)&As[buf][lmat[q]][lpl[q]][lrow[q]][lch[q] * 8] = stg[q];
  };

  g_load(0);
  l_store(0);
  if (GSTEPS > 1) g_load(32);
  __syncthreads();
  int cur = 0;
  for (int step = 0; step < GSTEPS; ++step) {
    if (step + 1 < GSTEPS) l_store(cur ^ 1);     // store prefetched step+1 into idle buffer
    if (step + 2 < GSTEPS) g_load((step + 2) * 32);
    bf16x8 af[2][3], bfr[2][3];
#pragma unroll
    for (int ti = 0; ti < 2; ++ti)
#pragma unroll
      for (int p = 0; p < 3; ++p) {
        af[ti][p] = *(const bf16x8*)&As[cur][0][p][wr * 32 + ti * 16 + fr][fq * 8];
        bfr[ti][p] = *(const bf16x8*)&As[cur][1][p][wc * 32 + ti * 16 + fr][fq * 8];
      }
#pragma unroll
    for (int ti = 0; ti < 2; ++ti)
#pragma unroll
      for (int tj = 0; tj < 2; ++tj) {
        f32x4 c = acc[ti][tj];
        c = __builtin_amdgcn_mfma_f32_16x16x32_bf16(af[ti][0], bfr[tj][0], c, 0, 0, 0);
        c = __builtin_amdgcn_mfma_f32_16x16x32_bf16(af[ti][0], bfr[tj][1], c, 0, 0, 0);
        c = __builtin_amdgcn_mfma_f32_16x16x32_bf16(af[ti][1], bfr[tj][0], c, 0, 0, 0);
        c = __builtin_amdgcn_mfma_f32_16x16x32_bf16(af[ti][0], bfr[tj][2], c, 0, 0, 0);
        c = __builtin_amdgcn_mfma_f32_16x16x32_bf16(af[ti][1], bfr[tj][1], c, 0, 0, 0);
        c = __builtin_amdgcn_mfma_f32_16x16x32_bf16(af[ti][2], bfr[tj][0], c, 0, 0, 0);
        acc[ti][tj] = c;
      }
    __syncthreads();   // waves done reading As[cur]; stores to As[cur^1] visible
    cur ^= 1;
  }
  // Epilogue: C/D layout col = lane&15, row = (lane>>4)*4 + reg  [m89-verified]
  float* drow = dotp + ((size_t)b * CC + i0) * CC + j0;
#pragma unroll
  for (int ti = 0; ti < 2; ++ti)
#pragma unroll
    for (int tj = 0; tj < 2; ++tj)
#pragma unroll
      for (int j = 0; j < 4; ++j) {
        int row = wr * 32 + ti * 16 + fq * 4 + j;
        int col = wc * 32 + tj * 16 + fr;
        drow[(size_t)row * CC + col] = acc[ti][tj][j];
      }
}

// ---------------- Kernel D: merged rowmax + group select + bitonic sort (per batch)
// Thread tid scans row tid sequentially (strictly-greater -> first-occurrence argmax,
// bitwise-identical to the old shuffle-reduce tie-break). Then group logic verbatim.
__global__ __launch_bounds__(256) void k_select(const float* __restrict__ dotp,
                                                const float* __restrict__ meanp,
                                                const float* __restrict__ pn,
                                                const float* __restrict__ meanms,
                                                const float* __restrict__ msn,
                                                float* __restrict__ sscore,
                                                int* __restrict__ svals,
                                                int* __restrict__ cnt) {
  const int b = blockIdx.x, tid = threadIdx.x;
  __shared__ float mv[CC];
  __shared__ int sidx[CC];
  __shared__ float gsc[CC];
  __shared__ int pres[CC];
  __shared__ unsigned long long keys[CC];
  __shared__ float r1[4], r2[4];
  __shared__ int r3[4];
  // Row-scan max/argmax for row r = b*CC + tid
  const int r = b * CC + tid;
  const float* d0 = dotp + (size_t)r * CC;
  const float mm = meanms[r];
  const float inv = 100.f / msn[r];
  const float* mpb = meanp + b * CC;
  const float* pnb = pn + b * CC;
  float best = -INFINITY; int bj = 0;
  for (int j4 = 0; j4 < CC / 4; ++j4) {
    float4 v0 = ((const float4*)d0)[j4];
    float4 mp4 = ((const float4*)mpb)[j4];
    float4 pn4 = ((const float4*)pnb)[j4];
    float sv[4];
    sv[0] = (v0.x - (float)PHW * mm * mp4.x) * inv / pn4.x;
    sv[1] = (v0.y - (float)PHW * mm * mp4.y) * inv / pn4.y;
    sv[2] = (v0.z - (float)PHW * mm * mp4.z) * inv / pn4.z;
    sv[3] = (v0.w - (float)PHW * mm * mp4.w) * inv / pn4.w;
#pragma unroll
    for (int t = 0; t < 4; ++t)
      if (sv[t] > best) { best = sv[t]; bj = j4 * 4 + t; }
  }
  const float v = best;
  sidx[tid] = bj;
  // ---- group logic (verbatim) ----
  float m = v;
  for (int off = 32; off; off >>= 1) m = fmaxf(m, __shfl_down(m, off));
  if ((tid & 63) == 0) r1[tid >> 6] = m;
  __syncthreads();
  float mt = fmaxf(fmaxf(r1[0], r1[1]), fmaxf(r1[2], r1[3]));
  float e = __expf(v - mt);
  float s = e;
  for (int off = 32; off; off >>= 1) s += __shfl_down(s, off);
  if ((tid & 63) == 0) r2[tid >> 6] = s;
  __syncthreads();
  float st = r2[0] + r2[1] + r2[2] + r2[3];
  mv[tid] = e / st;
  __syncthreads();
  float g = 0.f; int p = 0;
  for (int i2 = 0; i2 < CC; ++i2)
    if (sidx[i2] == tid) { g += mv[i2]; p = 1; }
  gsc[tid] = g; pres[tid] = p;
  int pc = p;
  for (int off = 32; off; off >>= 1) pc += __shfl_down(pc, off);
  if ((tid & 63) == 0) r3[tid >> 6] = pc;
  __syncthreads();
  if (tid == 0) cnt[b] = r3[0] + r3[1] + r3[2] + r3[3];
  int c = 255 - tid;
  float val = pres[c] ? gsc[c] : -INFINITY;
  keys[tid] = ((unsigned long long)f2ord(val) << 32) | (unsigned)c;
  __syncthreads();
  for (int ksz = 2; ksz <= 256; ksz <<= 1) {
    for (int jj = ksz >> 1; jj > 0; jj >>= 1) {
      int ixj = tid ^ jj;
      if (ixj > tid) {
        unsigned long long a = keys[tid], o = keys[ixj];
        bool descBlock = ((tid & ksz) == 0);
        bool sw = descBlock ? (a < o) : (a > o);
        if (sw) { keys[tid] = o; keys[ixj] = a; }
      }
      __syncthreads();
    }
  }
  unsigned long long kk = keys[tid];
  int cc2 = (int)(kk & 0xFFFFFFFFull);
  float vv = pres[cc2] ? gsc[cc2] : -INFINITY;
  sscore[b * CC + tid] = vv;
  svals[b * CC + tid] = cc2;
}

// ---------------- Kernel E: min_k + softmax weights ----------------
__global__ __launch_bounds__(128) void k_wsel(const float* __restrict__ sscore,
                                              const int* __restrict__ cnt,
                                              float* __restrict__ wgt,
                                              int* __restrict__ minkp) {
  const int b = blockIdx.x, tid = threadIdx.x;
  int mn = 0x7fffffff;
#pragma unroll
  for (int t = 0; t < CB; ++t) mn = min(mn, cnt[t]);
  const int mink = (mn + 1) >> 1;
  if (b == 0 && tid == 0) *minkp = mink;
  __shared__ float sh1[2], sh2[2];
  float v = (tid < mink) ? sscore[b * CC + tid] : -INFINITY;
  float m = v;
  for (int off = 32; off; off >>= 1) m = fmaxf(m, __shfl_down(m, off));
  if ((tid & 63) == 0) sh1[tid >> 6] = m;
  __syncthreads();
  float mt = fmaxf(sh1[0], sh1[1]);
  float e = (tid < mink) ? __expf(v - mt) : 0.f;
  float s = e;
  for (int off = 32; off; off >>= 1) s += __shfl_down(s, off);
  if ((tid & 63) == 0) sh2[tid >> 6] = s;
  __syncthreads();
  float st = sh2[0] + sh2[1];
  if (tid < mink) wgt[b * 128 + tid] = e / st;
}

// ---------------- Kernel F: fused mask + output, fine grid (2304 blocks), deep ILP ----------------
__global__ __launch_bounds__(256) void k_maskout(const float* __restrict__ fp,
                                                 const float* __restrict__ wgt,
                                                 const int* __restrict__ svals,
                                                 const int* __restrict__ minkp,
                                                 float* __restrict__ out) {
  const int b = blockIdx.y;
  const int pos = threadIdx.x & 15;
  const int kq = threadIdx.x >> 4;           // 0..15
  const int hw4 = blockIdx.x * 16 + pos;     // float4 index < 2304
  const int mink = *minkp;
  const int qlo = (mink * kq) >> 4, qhi = (mink * (kq + 1)) >> 4;
  const float* base = fp + (size_t)b * CC * PHW;
  float4 acc = make_float4(0.f, 0.f, 0.f, 0.f);
  int k = qlo;
  for (; k + 4 <= qhi; k += 4) {
    float4 vv[4]; float wk[4];
#pragma unroll
    for (int t = 0; t < 4; ++t) {
      int c = svals[b * CC + k + t];
      wk[t] = wgt[b * 128 + k + t];
      vv[t] = ((const float4*)(base + (size_t)c * PHW))[hw4];
    }
#pragma unroll
    for (int t = 0; t < 4; ++t) {
      acc.x += wk[t] * sigmoidf_(vv[t].x);
      acc.y += wk[t] * sigmoidf_(vv[t].y);
      acc.z += wk[t] * sigmoidf_(vv[t].z);
      acc.w += wk[t] * sigmoidf_(vv[t].w);
    }
  }
  for (; k < qhi; ++k) {
    int c = svals[b * CC + k];
    float wk = wgt[b * 128 + k];
    float4 v = ((const float4*)(base + (size_t)c * PHW))[hw4];
    acc.x += wk * sigmoidf_(v.x);
    acc.y += wk * sigmoidf_(v.y);
    acc.z += wk * sigmoidf_(v.z);
    acc.w += wk * sigmoidf_(v.w);
  }
  __shared__ __align__(16) float4 sh[16][16];
  __shared__ __align__(16) float4 msh[16];
  sh[kq][pos] = acc;
  __syncthreads();
  if (kq == 0) {
    float4 r = sh[0][pos];
#pragma unroll
    for (int t = 1; t < 16; ++t) {
      float4 a = sh[t][pos];
      r.x += a.x; r.y += a.y; r.z += a.z; r.w += a.w;
    }
    msh[pos] = r;
  }
  __syncthreads();
  const float4 mk = msh[pos];
  float* outb = out + (size_t)b * CC * PHW;
#pragma unroll
  for (int half = 0; half < 2; ++half) {
    float4 v[8];
#pragma unroll
    for (int j = 0; j < 8; ++j) {
      const int c = (half * 8 + j) * 16 + kq;
      v[j] = ((const float4*)(base + (size_t)c * PHW))[hw4];
    }
#pragma unroll
    for (int j = 0; j < 8; ++j) {
      const int c = (half * 8 + j) * 16 + kq;
      float4 o;
      o.x = v[j].x * (1.f + mk.x);
      o.y = v[j].y * (1.f + mk.y);
      o.z = v[j].z * (1.f + mk.z);
      o.w = v[j].w * (1.f + mk.w);
      ((float4*)(outb + (size_t)c * PHW))[hw4] = o;
    }
  }
}

extern "C" void kernel_launch(void* const* d_in, const int* in_sizes, int n_in,
                              void* d_out, int out_size, void* d_ws, size_t ws_size,
                              hipStream_t stream) {
  (void)in_sizes; (void)n_in; (void)out_size;
  const float* fp = (const float*)d_in[0];
  const float* fms = (const float*)d_in[1];
  float* out = (float*)d_out;

  // Big scratch in d_out (dead before k_maskout overwrites it):
  //   padjP: 16*256*3*2304 ushorts = 14,155,776 float-slots
  //   msP  : same, at float-offset 14,155,776
  //   dot  : 16*256*256 floats at float-offset 28,311,552  (ends 29.36M < 37.75M)
  unsigned short* padjP = (unsigned short*)out;
  unsigned short* msP = (unsigned short*)(out + (size_t)14155776);
  float* dotp = out + (size_t)28311552;

  if (ws_size < (size_t)183000 * 4) return;
  float* wsf = (float*)d_ws;
  float* meanp = wsf;               // 4096
  float* pnv = wsf + 4096;          // 4096
  float* meanms = wsf + 8192;       // 4096
  float* msn = wsf + 12288;         // 4096
  float* ssc = wsf + 20480;         // 4096
  float* wgt = wsf + 24576;         // 2048
  int* sv = (int*)(wsf + 178176);   // 4096
  int* cntp = (int*)(wsf + 182272); // 16
  int* minkp = (int*)(wsf + 182288);// 1

  k_stats<<<8192, 256, 0, stream>>>(fp, fms, padjP, msP, meanp, pnv, meanms, msn);
  k_gemm<<<256, 256, 0, stream>>>(msP, padjP, dotp);
  k_select<<<CB, 256, 0, stream>>>(dotp, meanp, pnv, meanms, msn, ssc, sv, cntp);
  k_wsel<<<CB, 128, 0, stream>>>(ssc, cntp, wgt, minkp);
  k_maskout<<<dim3(PHW / 4 / 16, CB), 256, 0, stream>>>(fp, wgt, sv, minkp, out);
}